// Round 15
// baseline (719.322 us; speedup 1.0000x reference)
//
#include <hip/hip_runtime.h>

#define NN 50000
#define EE 800000
#define GG 512
#define LL 3

typedef short bf16x8 __attribute__((ext_vector_type(8)));
typedef float f32x4  __attribute__((ext_vector_type(4)));

__device__ __forceinline__ float silu_f(float x) {
    return x * __builtin_amdgcn_rcpf(1.0f + __expf(-x));
}
__device__ __forceinline__ unsigned short bf16_rne(float x) {
    unsigned u = __float_as_uint(x);
    u += 0x7fffu + ((u >> 16) & 1u);
    return (unsigned short)(u >> 16);
}
__device__ __forceinline__ float bflo(unsigned u) { return __uint_as_float(u << 16); }
__device__ __forceinline__ float bfhi(unsigned u) { return __uint_as_float(u & 0xffff0000u); }
__device__ __forceinline__ f32x4 mfma16(bf16x8 a, bf16x8 b, f32x4 c) {
    return __builtin_amdgcn_mfma_f32_16x16x32_bf16(a, b, c, 0, 0, 0);
}
// lgkm-only barrier: drains LDS ops, leaves global loads/stores in flight.
__device__ __forceinline__ void barrier_lgkm() {
    asm volatile("s_waitcnt lgkmcnt(0)" ::: "memory");
    __builtin_amdgcn_s_barrier();
}

// ===========================================================================
// CSR build: histogram -> hierarchical scan (3 small kernels) -> scatter
// ===========================================================================
__global__ __launch_bounds__(256) void hist_kernel(const int* __restrict__ ei,
                                                   int* __restrict__ deg) {
    int e = blockIdx.x * 256 + threadIdx.x;
    if (e < EE) atomicAdd(&deg[ei[EE + e]], 1);
}

__global__ __launch_bounds__(512) void scanA_kernel(const int* __restrict__ deg,
                                                    int* __restrict__ rowptr,
                                                    int* __restrict__ bsum) {
    __shared__ int wsum[8];
    const int tid = threadIdx.x, b = blockIdx.x;
    int i = b * 512 + tid;
    int v = (i < NN) ? deg[i] : 0;
    int lane = tid & 63, wid = tid >> 6;
    int x = v;
#pragma unroll
    for (int s = 1; s < 64; s <<= 1) {
        int u = __shfl_up(x, s, 64);
        if (lane >= s) x += u;
    }
    if (lane == 63) wsum[wid] = x;
    __syncthreads();
    int woff = 0;
    for (int w = 0; w < wid; ++w) woff += wsum[w];
    if (i < NN) rowptr[i] = woff + x - v;
    if (tid == 511) bsum[b] = woff + x;
}

__global__ __launch_bounds__(128) void scanB_kernel(int* __restrict__ bsum, int nb) {
    __shared__ int wsum[2];
    const int tid = threadIdx.x;
    int v = (tid < nb) ? bsum[tid] : 0;
    int lane = tid & 63, wid = tid >> 6;
    int x = v;
#pragma unroll
    for (int s = 1; s < 64; s <<= 1) {
        int u = __shfl_up(x, s, 64);
        if (lane >= s) x += u;
    }
    if (lane == 63) wsum[wid] = x;
    __syncthreads();
    int woff = (wid == 1) ? wsum[0] : 0;
    if (tid < nb) bsum[tid] = woff + x - v;
}

__global__ __launch_bounds__(512) void scanC_kernel(int* __restrict__ rowptr,
                                                    int* __restrict__ cursor,
                                                    const int* __restrict__ bsum) {
    const int tid = threadIdx.x, b = blockIdx.x;
    int i = b * 512 + tid;
    if (i < NN) {
        int r = rowptr[i] + bsum[b];
        rowptr[i] = r;
        cursor[i] = r;
    }
    if (i == 0) rowptr[NN] = EE;
}

__global__ __launch_bounds__(256) void scatter_kernel(const int* __restrict__ ei,
                                                      int* __restrict__ cursor,
                                                      int* __restrict__ srcsS,
                                                      int* __restrict__ dstsS) {
    int e = blockIdx.x * 256 + threadIdx.x;
    if (e < EE) {
        int d = ei[EE + e];
        int pos = atomicAdd(&cursor[d], 1);
        srcsS[pos] = ei[e];
        dstsS[pos] = d;
    }
}

// ===========================================================================
// pk_kernel: Pt = h @ W1[0:64] (f32), Pb = h @ W1[64:128] (bf16 packed)
// ===========================================================================
__global__ __launch_bounds__(512, 4) void pk_kernel(
    const float* __restrict__ h, const float* __restrict__ w1g,
    float* __restrict__ Pt, unsigned short* __restrict__ Pbu, int ntiles)
{
    extern __shared__ float lds[];
    float* ws = lds;            // [128][64] f32 = 32 KB
    float* hs = ws + 8192;      // [128][68] f32 = 34.8 KB
    const int tid = threadIdx.x;
    const int tr  = tid & 31;
    const int tc  = tid >> 5;

    for (int i = tid; i < 2048; i += 512)
        *(float4*)&ws[4 * i] = *(const float4*)&w1g[4 * i];

    for (int tile = blockIdx.x; tile < ntiles; tile += gridDim.x) {
        const int base = tile * 128;
        __syncthreads();
#pragma unroll
        for (int rep = 0; rep < 4; ++rep) {
            int idx = rep * 512 + tid;
            int r = idx >> 4, q = idx & 15;
            int n = base + r;
            float4 v = make_float4(0.f, 0.f, 0.f, 0.f);
            if (n < NN) v = *(const float4*)(h + 64 * n + 4 * q);
            *(float4*)&hs[r * 68 + 4 * q] = v;
        }
        __syncthreads();
#pragma unroll
        for (int p = 0; p < 2; ++p) {
            float acc[4][4];
#pragma unroll
            for (int jj = 0; jj < 4; ++jj)
#pragma unroll
                for (int ii = 0; ii < 4; ++ii) acc[jj][ii] = 0.f;
#pragma unroll 4
            for (int k16 = 0; k16 < 16; ++k16) {
                float4 bv0 = *(const float4*)&ws[(p * 64 + 4 * k16 + 0) * 64 + 4 * tc];
                float4 bv1 = *(const float4*)&ws[(p * 64 + 4 * k16 + 1) * 64 + 4 * tc];
                float4 bv2 = *(const float4*)&ws[(p * 64 + 4 * k16 + 2) * 64 + 4 * tc];
                float4 bv3 = *(const float4*)&ws[(p * 64 + 4 * k16 + 3) * 64 + 4 * tc];
#pragma unroll
                for (int jj = 0; jj < 4; ++jj) {
                    float4 av = *(const float4*)&hs[(tr + 32 * jj) * 68 + 4 * k16];
                    acc[jj][0] = fmaf(av.x, bv0.x, fmaf(av.y, bv1.x, fmaf(av.z, bv2.x, fmaf(av.w, bv3.x, acc[jj][0]))));
                    acc[jj][1] = fmaf(av.x, bv0.y, fmaf(av.y, bv1.y, fmaf(av.z, bv2.y, fmaf(av.w, bv3.y, acc[jj][1]))));
                    acc[jj][2] = fmaf(av.x, bv0.z, fmaf(av.y, bv1.z, fmaf(av.z, bv2.z, fmaf(av.w, bv3.z, acc[jj][2]))));
                    acc[jj][3] = fmaf(av.x, bv0.w, fmaf(av.y, bv1.w, fmaf(av.z, bv2.w, fmaf(av.w, bv3.w, acc[jj][3]))));
                }
            }
#pragma unroll
            for (int jj = 0; jj < 4; ++jj) {
                int n = base + tr + 32 * jj;
                if (n < NN) {
                    if (p == 0) {
                        *(float4*)(Pt + (size_t)64 * n + 4 * tc) =
                            make_float4(acc[jj][0], acc[jj][1], acc[jj][2], acc[jj][3]);
                    } else {
                        uint2 o;
                        o.x = ((unsigned)bf16_rne(acc[jj][1]) << 16) | bf16_rne(acc[jj][0]);
                        o.y = ((unsigned)bf16_rne(acc[jj][3]) << 16) | bf16_rne(acc[jj][2]);
                        *(uint2*)(Pbu + (size_t)64 * n + 4 * tc) = o;
                    }
                }
            }
        }
    }
}

// ===========================================================================
// Fused edge+agg kernel: per 128-edge dst-sorted tile
//   m1 = silu(Pt[dst]+Pb[src]+b1) -> bf16 swizzled LDS
//   m2 = silu(m1@W2+b2)           -> bf16 LDS [128][136B]
//   in-LDS segment walk over sorted dst runs:
//     interior segment (r>0 && rr<128 => provably the node's whole edge list)
//       -> plain f32 store to agg
//     tile-boundary segments (~2/tile) -> scalar atomicAdd (agg pre-zeroed)
// No m2g stream (kills 204 MB/layer of HBM traffic). LDS 43.5KB -> 3 blk/CU.
// ===========================================================================
__global__ __launch_bounds__(512, 4) void edge_kernel(
    const float* __restrict__ Pt, const unsigned short* __restrict__ Pbu,
    const int* __restrict__ srcsS, const int* __restrict__ dstsS,
    const float* __restrict__ b1g,
    const float* __restrict__ w2g, const float* __restrict__ b2g,
    float* __restrict__ agg, int ntiles)
{
    extern __shared__ __align__(16) char smem[];
    char*  wt2s  = smem;                          // [64c][128B] swz    8192
    char*  m1s   = wt2s + 8192;                   // [128r][128B] swz  16384
    char*  m2h   = m1s + 16384;                   // [128r][136B] bf16 17408
    float* b1s   = (float*)(m2h + 17408);         // 64 f32
    float* b2s   = b1s + 64;                      // 64 f32
    int*   dstsL = (int*)(b2s + 64);              // 2 x 128 int
    // total 43520 B -> 3 blocks/CU

    const int tid = threadIdx.x;
    const int l   = tid & 63;
    const int w   = tid >> 6;
    const int mi  = w >> 1;
    const int ni  = w & 1;
    const int l15 = l & 15;
    const int l4  = l >> 4;
    const int g7  = tid & 7;

    {
        int c = tid >> 3, kc = tid & 7;
        const float* wp = w2g + (kc * 8) * 64 + c;
        bf16x8 bv;
#pragma unroll
        for (int j = 0; j < 8; ++j) bv[j] = (short)bf16_rne(wp[j * 64]);
        *(bf16x8*)(wt2s + c * 128 + ((kc * 16) ^ ((c & 7) << 4))) = bv;
    }
    if (tid < 64) { b1s[tid] = b1g[tid]; b2s[tid] = b2g[tid]; }

    int    ix_d[2], ix_s[2], ix_pd = 0;
    float4 pf_a0[2], pf_a1[2];
    uint4  pf_pb[2];
    int    pf_d = 0;

    auto IDX = [&](int tt) {
        int eb = tt * 128;
#pragma unroll
        for (int it = 0; it < 2; ++it) {
            int e = (it * 512 + tid) >> 3;
            ix_d[it] = dstsS[eb + e];
            ix_s[it] = srcsS[eb + e];
        }
        ix_pd = (tid < 128) ? dstsS[eb + tid] : 0;
    };
    auto DATA = [&]() {
#pragma unroll
        for (int it = 0; it < 2; ++it) {
            const float* pt = Pt + (size_t)64 * ix_d[it] + 8 * g7;
            pf_a0[it] = *(const float4*)pt;
            pf_a1[it] = *(const float4*)(pt + 4);
            pf_pb[it] = *(const uint4*)(Pbu + (size_t)64 * ix_s[it] + 8 * g7);
        }
        pf_d = ix_pd;
    };

    int tile = blockIdx.x;
    int buf  = 0;
    if (tile < ntiles) { IDX(tile); DATA(); }
    if (tile + gridDim.x < ntiles) IDX(tile + gridDim.x);
    barrier_lgkm();                               // staging visible

    for (; tile < ntiles; tile += gridDim.x) {
        if (tid < 128) dstsL[buf * 128 + tid] = pf_d;
#pragma unroll
        for (int it = 0; it < 2; ++it) {
            int e = (it * 512 + tid) >> 3;
            float4 b0  = *(const float4*)(b1s + 8 * g7);
            float4 b1v = *(const float4*)(b1s + 8 * g7 + 4);
            float v0 = silu_f(pf_a0[it].x + bflo(pf_pb[it].x) + b0.x);
            float v1 = silu_f(pf_a0[it].y + bfhi(pf_pb[it].x) + b0.y);
            float v2 = silu_f(pf_a0[it].z + bflo(pf_pb[it].y) + b0.z);
            float v3 = silu_f(pf_a0[it].w + bfhi(pf_pb[it].y) + b0.w);
            float v4 = silu_f(pf_a1[it].x + bflo(pf_pb[it].z) + b1v.x);
            float v5 = silu_f(pf_a1[it].y + bfhi(pf_pb[it].z) + b1v.y);
            float v6 = silu_f(pf_a1[it].z + bflo(pf_pb[it].w) + b1v.z);
            float v7 = silu_f(pf_a1[it].w + bfhi(pf_pb[it].w) + b1v.w);
            uint4 o;
            o.x = ((unsigned)bf16_rne(v1) << 16) | bf16_rne(v0);
            o.y = ((unsigned)bf16_rne(v3) << 16) | bf16_rne(v2);
            o.z = ((unsigned)bf16_rne(v5) << 16) | bf16_rne(v4);
            o.w = ((unsigned)bf16_rne(v7) << 16) | bf16_rne(v6);
            *(uint4*)(m1s + e * 128 + ((g7 * 16) ^ ((e & 7) << 4))) = o;
        }
        barrier_lgkm();                           // B1: m1s + dstsL ready
        int nxt = tile + gridDim.x;
        if (nxt < ntiles) {
            DATA();                               // idx regs completed 1 iter ago
            if (nxt + gridDim.x < ntiles) IDX(nxt + gridDim.x);
        }
        // ---- stage 2: m1[128x64] @ W2[64x64] ----
        f32x4 acc2[2][2];
#pragma unroll
        for (int m = 0; m < 2; ++m)
#pragma unroll
            for (int n = 0; n < 2; ++n) {
                float b = b2s[32 * ni + 16 * n + l15];
                acc2[m][n] = (f32x4){b, b, b, b};
            }
        const int sw = (l15 & 7) << 4;
#pragma unroll
        for (int ks = 0; ks < 2; ++ks) {
            int kb = ks * 64 + l4 * 16;
            bf16x8 af[2], bfr[2];
#pragma unroll
            for (int m = 0; m < 2; ++m)
                af[m] = *(const bf16x8*)(m1s + (32 * mi + 16 * m + l15) * 128 + (kb ^ sw));
#pragma unroll
            for (int n = 0; n < 2; ++n)
                bfr[n] = *(const bf16x8*)(wt2s + (32 * ni + 16 * n + l15) * 128 + (kb ^ sw));
#pragma unroll
            for (int m = 0; m < 2; ++m)
#pragma unroll
                for (int n = 0; n < 2; ++n)
                    acc2[m][n] = mfma16(af[m], bfr[n], acc2[m][n]);
        }
        // m2 = silu -> bf16 LDS [row][col], row stride 136B (round-10 proven)
#pragma unroll
        for (int m = 0; m < 2; ++m)
#pragma unroll
            for (int n = 0; n < 2; ++n)
#pragma unroll
                for (int r = 0; r < 4; ++r) {
                    int row = 32 * mi + 16 * m + l4 * 4 + r;
                    int col = 32 * ni + 16 * n + l15;
                    *(unsigned short*)(m2h + row * 136 + col * 2) =
                        bf16_rne(silu_f(acc2[m][n][r]));
                }
        barrier_lgkm();                           // B2: m2h complete
        // ---- in-LDS segment walk; thread = (row, 16-col group) ----
        {
            const int* dL = dstsL + buf * 128;
            int r  = tid & 127;
            int cg = tid >> 7;                    // 0..3
            int d  = dL[r];
            bool head = (r == 0) || (dL[r - 1] != d);
            if (head) {
                float s[16];
#pragma unroll
                for (int j = 0; j < 16; ++j) s[j] = 0.f;
                int rr = r;
                do {
                    const char* p = m2h + rr * 136 + cg * 32;
                    uint2 u0 = *(const uint2*)(p);
                    uint2 u1 = *(const uint2*)(p + 8);
                    uint2 u2 = *(const uint2*)(p + 16);
                    uint2 u3 = *(const uint2*)(p + 24);
                    s[0]  += bflo(u0.x); s[1]  += bfhi(u0.x);
                    s[2]  += bflo(u0.y); s[3]  += bfhi(u0.y);
                    s[4]  += bflo(u1.x); s[5]  += bfhi(u1.x);
                    s[6]  += bflo(u1.y); s[7]  += bfhi(u1.y);
                    s[8]  += bflo(u2.x); s[9]  += bfhi(u2.x);
                    s[10] += bflo(u2.y); s[11] += bfhi(u2.y);
                    s[12] += bflo(u3.x); s[13] += bfhi(u3.x);
                    s[14] += bflo(u3.y); s[15] += bfhi(u3.y);
                    ++rr;
                } while (rr < 128 && dL[rr] == d);
                float* ap = agg + (size_t)64 * d + cg * 16;
                if (r > 0 && rr < 128) {
                    // interior: this tile holds ALL of node d's edges
                    *(float4*)(ap + 0)  = make_float4(s[0], s[1], s[2], s[3]);
                    *(float4*)(ap + 4)  = make_float4(s[4], s[5], s[6], s[7]);
                    *(float4*)(ap + 8)  = make_float4(s[8], s[9], s[10], s[11]);
                    *(float4*)(ap + 12) = make_float4(s[12], s[13], s[14], s[15]);
                } else {
#pragma unroll
                    for (int j = 0; j < 16; ++j) atomicAdd(ap + j, s[j]);
                }
            }
        }
        buf ^= 1;
    }
}

// ===========================================================================
// Node row-MLP: cats=[h|agg], u=silu(cats@W1+b1), h = u@W2 + b2 + h.
// ===========================================================================
__global__ __launch_bounds__(512, 1) void node_mlp_kernel(
    const float* __restrict__ A, const float* __restrict__ A2,
    const float* __restrict__ w1g, const float* __restrict__ b1g,
    const float* __restrict__ w2g, const float* __restrict__ b2g,
    float* __restrict__ outp, int nrows, int ntiles)
{
    extern __shared__ float lds[];
    float* ws1  = lds;
    float* ws2  = ws1 + 8192;
    float* wb1  = ws2 + 4096;
    float* wb2  = wb1 + 64;
    float* cats = wb2 + 64;
    float* m1s  = cats + 128 * 132;

    const int tid = threadIdx.x;
    const int tr  = tid & 31;
    const int tc  = tid >> 5;

    for (int i = tid; i < 2048; i += 512)
        *(float4*)&ws1[4 * i] = *(const float4*)&w1g[4 * i];
    for (int i = tid; i < 1024; i += 512)
        *(float4*)&ws2[4 * i] = *(const float4*)&w2g[4 * i];
    if (tid < 64) { wb1[tid] = b1g[tid]; wb2[tid] = b2g[tid]; }

    for (int tile = blockIdx.x; tile < ntiles; tile += gridDim.x) {
        const int base = tile * 128;
        __syncthreads();
#pragma unroll
        for (int rep = 0; rep < 8; ++rep) {
            int idx = rep * 512 + tid;
            int r = idx >> 5, q = idx & 31;
            int n = base + r;
            float4 v = make_float4(0.f, 0.f, 0.f, 0.f);
            if (n < nrows)
                v = (q < 16) ? *(const float4*)(A + 64 * n + 4 * q)
                             : *(const float4*)(A2 + 64 * n + 4 * (q - 16));
            *(float4*)&cats[r * 132 + 4 * q] = v;
        }
        __syncthreads();
        float acc[4][4];
#pragma unroll
        for (int jj = 0; jj < 4; ++jj)
#pragma unroll
            for (int ii = 0; ii < 4; ++ii) acc[jj][ii] = wb1[4 * tc + ii];
#pragma unroll 4
        for (int k16 = 0; k16 < 32; ++k16) {
            float4 bv0 = *(const float4*)&ws1[(4 * k16 + 0) * 64 + 4 * tc];
            float4 bv1 = *(const float4*)&ws1[(4 * k16 + 1) * 64 + 4 * tc];
            float4 bv2 = *(const float4*)&ws1[(4 * k16 + 2) * 64 + 4 * tc];
            float4 bv3 = *(const float4*)&ws1[(4 * k16 + 3) * 64 + 4 * tc];
#pragma unroll
            for (int jj = 0; jj < 4; ++jj) {
                float4 av = *(const float4*)&cats[(tr + 32 * jj) * 132 + 4 * k16];
                acc[jj][0] = fmaf(av.x, bv0.x, fmaf(av.y, bv1.x, fmaf(av.z, bv2.x, fmaf(av.w, bv3.x, acc[jj][0]))));
                acc[jj][1] = fmaf(av.x, bv0.y, fmaf(av.y, bv1.y, fmaf(av.z, bv2.y, fmaf(av.w, bv3.y, acc[jj][1]))));
                acc[jj][2] = fmaf(av.x, bv0.z, fmaf(av.y, bv1.z, fmaf(av.z, bv2.z, fmaf(av.w, bv3.z, acc[jj][2]))));
                acc[jj][3] = fmaf(av.x, bv0.w, fmaf(av.y, bv1.w, fmaf(av.z, bv2.w, fmaf(av.w, bv3.w, acc[jj][3]))));
            }
        }
#pragma unroll
        for (int jj = 0; jj < 4; ++jj) {
            float4 v;
            v.x = silu_f(acc[jj][0]); v.y = silu_f(acc[jj][1]);
            v.z = silu_f(acc[jj][2]); v.w = silu_f(acc[jj][3]);
            *(float4*)&m1s[(tr + 32 * jj) * 68 + 4 * tc] = v;
        }
        __syncthreads();
        float acc2[4][4];
#pragma unroll
        for (int jj = 0; jj < 4; ++jj)
#pragma unroll
            for (int ii = 0; ii < 4; ++ii) acc2[jj][ii] = wb2[4 * tc + ii];
#pragma unroll 4
        for (int k16 = 0; k16 < 16; ++k16) {
            float4 bv0 = *(const float4*)&ws2[(4 * k16 + 0) * 64 + 4 * tc];
            float4 bv1 = *(const float4*)&ws2[(4 * k16 + 1) * 64 + 4 * tc];
            float4 bv2 = *(const float4*)&ws2[(4 * k16 + 2) * 64 + 4 * tc];
            float4 bv3 = *(const float4*)&ws2[(4 * k16 + 3) * 64 + 4 * tc];
#pragma unroll
            for (int jj = 0; jj < 4; ++jj) {
                float4 av = *(const float4*)&m1s[(tr + 32 * jj) * 68 + 4 * k16];
                acc2[jj][0] = fmaf(av.x, bv0.x, fmaf(av.y, bv1.x, fmaf(av.z, bv2.x, fmaf(av.w, bv3.x, acc2[jj][0]))));
                acc2[jj][1] = fmaf(av.x, bv0.y, fmaf(av.y, bv1.y, fmaf(av.z, bv2.y, fmaf(av.w, bv3.y, acc2[jj][1]))));
                acc2[jj][2] = fmaf(av.x, bv0.z, fmaf(av.y, bv1.z, fmaf(av.z, bv2.z, fmaf(av.w, bv3.z, acc2[jj][2]))));
                acc2[jj][3] = fmaf(av.x, bv0.w, fmaf(av.y, bv1.w, fmaf(av.z, bv2.w, fmaf(av.w, bv3.w, acc2[jj][3]))));
            }
        }
#pragma unroll
        for (int jj = 0; jj < 4; ++jj) {
            int r = tr + 32 * jj;
            int n = base + r;
            if (n < nrows) {
                float4 hold = *(const float4*)&cats[r * 132 + 4 * tc];
                *(float4*)&outp[64 * n + 4 * tc] = make_float4(
                    acc2[jj][0] + hold.x, acc2[jj][1] + hold.y,
                    acc2[jj][2] + hold.z, acc2[jj][3] + hold.w);
            }
        }
    }
}

// ===========================================================================
// Readout row-MLP (K1=64, segmented scatter into gsum)
// ===========================================================================
__global__ __launch_bounds__(512, 1) void rowmlp_ro_kernel(
    const float* __restrict__ A,
    const float* __restrict__ w1g, const float* __restrict__ b1g,
    const float* __restrict__ w2g, const float* __restrict__ b2g,
    const int* __restrict__ seg, float* __restrict__ outp,
    int nrows, int ntiles)
{
    extern __shared__ float lds[];
    float* ws1  = lds;
    float* ws2  = ws1 + 4096;
    float* wb1  = ws2 + 4096;
    float* wb2  = wb1 + 64;
    float* cats = wb2 + 64;
    float* m1s  = cats + 128 * 68;
    int*   segs = (int*)(m1s + 128 * 68);

    const int tid = threadIdx.x;
    const int tr  = tid & 31;
    const int tc  = tid >> 5;

    for (int i = tid; i < 1024; i += 512) {
        *(float4*)&ws1[4 * i] = *(const float4*)&w1g[4 * i];
        *(float4*)&ws2[4 * i] = *(const float4*)&w2g[4 * i];
    }
    if (tid < 64) { wb1[tid] = b1g[tid]; wb2[tid] = b2g[tid]; }

    for (int tile = blockIdx.x; tile < ntiles; tile += gridDim.x) {
        const int base = tile * 128;
        __syncthreads();
        if (tid < 128) segs[tid] = (base + tid < nrows) ? seg[base + tid] : -1;
#pragma unroll
        for (int rep = 0; rep < 4; ++rep) {
            int idx = rep * 512 + tid;
            int r = idx >> 4, q = idx & 15;
            int n = base + r;
            float4 v = make_float4(0.f, 0.f, 0.f, 0.f);
            if (n < nrows) v = *(const float4*)(A + 64 * n + 4 * q);
            *(float4*)&cats[r * 68 + 4 * q] = v;
        }
        __syncthreads();
        float acc[4][4];
#pragma unroll
        for (int jj = 0; jj < 4; ++jj)
#pragma unroll
            for (int ii = 0; ii < 4; ++ii) acc[jj][ii] = wb1[4 * tc + ii];
#pragma unroll 4
        for (int k16 = 0; k16 < 16; ++k16) {
            float4 bv0 = *(const float4*)&ws1[(4 * k16 + 0) * 64 + 4 * tc];
            float4 bv1 = *(const float4*)&ws1[(4 * k16 + 1) * 64 + 4 * tc];
            float4 bv2 = *(const float4*)&ws1[(4 * k16 + 2) * 64 + 4 * tc];
            float4 bv3 = *(const float4*)&ws1[(4 * k16 + 3) * 64 + 4 * tc];
#pragma unroll
            for (int jj = 0; jj < 4; ++jj) {
                float4 av = *(const float4*)&cats[(tr + 32 * jj) * 68 + 4 * k16];
                acc[jj][0] = fmaf(av.x, bv0.x, fmaf(av.y, bv1.x, fmaf(av.z, bv2.x, fmaf(av.w, bv3.x, acc[jj][0]))));
                acc[jj][1] = fmaf(av.x, bv0.y, fmaf(av.y, bv1.y, fmaf(av.z, bv2.y, fmaf(av.w, bv3.y, acc[jj][1]))));
                acc[jj][2] = fmaf(av.x, bv0.z, fmaf(av.y, bv1.z, fmaf(av.z, bv2.z, fmaf(av.w, bv3.z, acc[jj][2]))));
                acc[jj][3] = fmaf(av.x, bv0.w, fmaf(av.y, bv1.w, fmaf(av.z, bv2.w, fmaf(av.w, bv3.w, acc[jj][3]))));
            }
        }
#pragma unroll
        for (int jj = 0; jj < 4; ++jj) {
            float4 v;
            v.x = silu_f(acc[jj][0]); v.y = silu_f(acc[jj][1]);
            v.z = silu_f(acc[jj][2]); v.w = silu_f(acc[jj][3]);
            *(float4*)&m1s[(tr + 32 * jj) * 68 + 4 * tc] = v;
        }
        __syncthreads();
        float acc2[4][4];
#pragma unroll
        for (int jj = 0; jj < 4; ++jj)
#pragma unroll
            for (int ii = 0; ii < 4; ++ii) acc2[jj][ii] = wb2[4 * tc + ii];
#pragma unroll 4
        for (int k16 = 0; k16 < 16; ++k16) {
            float4 bv0 = *(const float4*)&ws2[(4 * k16 + 0) * 64 + 4 * tc];
            float4 bv1 = *(const float4*)&ws2[(4 * k16 + 1) * 64 + 4 * tc];
            float4 bv2 = *(const float4*)&ws2[(4 * k16 + 2) * 64 + 4 * tc];
            float4 bv3 = *(const float4*)&ws2[(4 * k16 + 3) * 64 + 4 * tc];
#pragma unroll
            for (int jj = 0; jj < 4; ++jj) {
                float4 av = *(const float4*)&m1s[(tr + 32 * jj) * 68 + 4 * k16];
                acc2[jj][0] = fmaf(av.x, bv0.x, fmaf(av.y, bv1.x, fmaf(av.z, bv2.x, fmaf(av.w, bv3.x, acc2[jj][0]))));
                acc2[jj][1] = fmaf(av.x, bv0.y, fmaf(av.y, bv1.y, fmaf(av.z, bv2.y, fmaf(av.w, bv3.y, acc2[jj][1]))));
                acc2[jj][2] = fmaf(av.x, bv0.z, fmaf(av.y, bv1.z, fmaf(av.z, bv2.z, fmaf(av.w, bv3.z, acc2[jj][2]))));
                acc2[jj][3] = fmaf(av.x, bv0.w, fmaf(av.y, bv1.w, fmaf(av.z, bv2.w, fmaf(av.w, bv3.w, acc2[jj][3]))));
            }
        }
#pragma unroll
        for (int jj = 0; jj < 4; ++jj) {
            int r = tr + 32 * jj;
            int n = base + r;
            int gid = segs[r];
            float4 vv = (n < nrows) ? make_float4(acc2[jj][0], acc2[jj][1], acc2[jj][2], acc2[jj][3])
                                    : make_float4(0.f, 0.f, 0.f, 0.f);
            unsigned f = (tr == 0 || segs[(r > 0) ? r - 1 : 0] != gid) ? 1u : 0u;
#pragma unroll
            for (int s = 1; s < 32; s <<= 1) {
                float ux = __shfl_up(vv.x, s, 32);
                float uy = __shfl_up(vv.y, s, 32);
                float uz = __shfl_up(vv.z, s, 32);
                float uw = __shfl_up(vv.w, s, 32);
                unsigned uf = __shfl_up(f, s, 32);
                if (tr >= s) {
                    if (!f) { vv.x += ux; vv.y += uy; vv.z += uz; vv.w += uw; }
                    f |= uf;
                }
            }
            bool tail = (tr == 31) || (segs[r + 1] != gid);
            if (tail && gid >= 0) {
                float* bp = outp + 64 * gid + 4 * tc;
                atomicAdd(bp + 0, vv.x); atomicAdd(bp + 1, vv.y);
                atomicAdd(bp + 2, vv.z); atomicAdd(bp + 3, vv.w);
            }
        }
    }
}

__global__ __launch_bounds__(256) void proj_kernel(
    const float* __restrict__ x, const float* __restrict__ w,
    const float* __restrict__ b, float* __restrict__ h, int n)
{
    int i = blockIdx.x * 256 + threadIdx.x;
    if (i >= n * 64) return;
    int node = i >> 6, j = i & 63;
    const float* xr = x + node * 14;
    float acc = b[j];
#pragma unroll
    for (int k = 0; k < 14; ++k) acc = fmaf(xr[k], w[k * 64 + j], acc);
    h[i] = acc;
}

__global__ __launch_bounds__(256) void head_kernel(
    const float* __restrict__ gsum,
    const float* __restrict__ w3, const float* __restrict__ b3,
    const float* __restrict__ w4, const float* __restrict__ b4,
    float* __restrict__ out, int g_count)
{
    int wid  = (blockIdx.x * 256 + threadIdx.x) >> 6;
    int lane = threadIdx.x & 63;
    if (wid >= g_count) return;
    float v = gsum[wid * 64 + lane];
    float t = b3[lane];
#pragma unroll
    for (int k = 0; k < 64; ++k) {
        float a = __shfl(v, k, 64);
        t = fmaf(a, w3[k * 64 + lane], t);
    }
    t = silu_f(t);
    float r = t * w4[lane];
#pragma unroll
    for (int off = 32; off; off >>= 1) r += __shfl_down(r, off, 64);
    if (lane == 0) out[wid] = r + b4[0];
}

extern "C" void kernel_launch(void* const* d_in, const int* in_sizes, int n_in,
                              void* d_out, int out_size, void* d_ws, size_t ws_size,
                              hipStream_t stream)
{
    const float* x      = (const float*)d_in[0];
    const int*   ei     = (const int*)d_in[2];
    const int*   batch  = (const int*)d_in[3];
    const float* proj_w = (const float*)d_in[4];
    const float* proj_b = (const float*)d_in[5];
    const float* ew1 = (const float*)d_in[6];
    const float* eb1 = (const float*)d_in[7];
    const float* ew2 = (const float*)d_in[8];
    const float* eb2 = (const float*)d_in[9];
    const float* nw1 = (const float*)d_in[10];
    const float* nb1 = (const float*)d_in[11];
    const float* nw2 = (const float*)d_in[12];
    const float* nb2 = (const float*)d_in[13];
    const float* l1w = (const float*)d_in[14]; const float* l1b = (const float*)d_in[15];
    const float* l2w = (const float*)d_in[16]; const float* l2b = (const float*)d_in[17];
    const float* l3w = (const float*)d_in[18]; const float* l3b = (const float*)d_in[19];
    const float* l4w = (const float*)d_in[20]; const float* l4b = (const float*)d_in[21];

    float* out  = (float*)d_out;
    float* h    = out + GG;                      // per_atom_out doubles as h

    float* agg  = (float*)d_ws;                              // [N,64] f32
    float* gsum = agg + (size_t)NN * 64;                     // [G,64]
    float* Pt   = gsum + (size_t)GG * 64;                    // [N,64] f32
    unsigned short* Pbu = (unsigned short*)(Pt + (size_t)NN * 64);  // [N,64] bf16
    int* deg    = (int*)(Pbu + (size_t)NN * 64);
    int* rowptr = deg + NN;                                  // N+1
    int* cursor = rowptr + NN + 1;
    int* srcsS  = cursor + NN;                               // [E]
    int* dstsS  = srcsS + EE;                                // [E]
    int* bsum   = dstsS + EE;                                // [98]

    const size_t edge_lds = 8192 + 16384 + 17408 + 256 + 256 + 1024;  // 43520
    const size_t pk_lds   = (size_t)(8192 + 8704) * 4;                // 67584
    const size_t node_lds = (size_t)(8192 + 4096 + 128 + 128 * 132 + 128 * 68) * 4;
    const size_t ro_lds   = (size_t)(4096 + 4096 + 128 + 128 * 68 + 128 * 68) * 4 + 128 * 4;

    (void)hipFuncSetAttribute((const void*)edge_kernel,
                              hipFuncAttributeMaxDynamicSharedMemorySize, (int)edge_lds);
    (void)hipFuncSetAttribute((const void*)pk_kernel,
                              hipFuncAttributeMaxDynamicSharedMemorySize, (int)pk_lds);
    (void)hipFuncSetAttribute((const void*)node_mlp_kernel,
                              hipFuncAttributeMaxDynamicSharedMemorySize, (int)node_lds);
    (void)hipFuncSetAttribute((const void*)rowmlp_ro_kernel,
                              hipFuncAttributeMaxDynamicSharedMemorySize, (int)ro_lds);

    // --- CSR build (dst-sorted edge arrays) ---
    const int nb = (NN + 511) / 512;           // 98
    hipMemsetAsync(deg, 0, (size_t)NN * sizeof(int), stream);
    hipMemsetAsync(gsum, 0, (size_t)GG * 64 * sizeof(float), stream);
    hist_kernel<<<(EE + 255) / 256, 256, 0, stream>>>(ei, deg);
    scanA_kernel<<<nb, 512, 0, stream>>>(deg, rowptr, bsum);
    scanB_kernel<<<1, 128, 0, stream>>>(bsum, nb);
    scanC_kernel<<<nb, 512, 0, stream>>>(rowptr, cursor, bsum);
    scatter_kernel<<<(EE + 255) / 256, 256, 0, stream>>>(ei, cursor, srcsS, dstsS);

    proj_kernel<<<(NN * 64 + 255) / 256, 256, 0, stream>>>(x, proj_w, proj_b, h, NN);

    const int etiles = EE / 128;               // 6250 (exact)
    const int ntiles = (NN + 127) / 128;       // 391
    for (int l = 0; l < LL; ++l) {
        pk_kernel<<<ntiles, 512, pk_lds, stream>>>(h, ew1 + l * 8192, Pt, Pbu, ntiles);
        hipMemsetAsync(agg, 0, (size_t)NN * 64 * sizeof(float), stream);
        edge_kernel<<<768, 512, edge_lds, stream>>>(
            Pt, Pbu, srcsS, dstsS, eb1 + l * 64, ew2 + l * 4096, eb2 + l * 64,
            agg, etiles);
        node_mlp_kernel<<<196, 512, node_lds, stream>>>(
            h, agg, nw1 + l * 8192, nb1 + l * 64, nw2 + l * 4096, nb2 + l * 64,
            h, NN, ntiles);
    }
    rowmlp_ro_kernel<<<196, 512, ro_lds, stream>>>(
        h, l1w, l1b, l2w, l2b, batch, gsum, NN, ntiles);
    head_kernel<<<GG / 4, 256, 0, stream>>>(gsum, l3w, l3b, l4w, l4b, out, GG);
}

// Round 16
// 702.776 us; speedup vs baseline: 1.0235x; 1.0235x over previous
//
#include <hip/hip_runtime.h>

#define NN 50000
#define EE 800000
#define GG 512
#define LL 3

typedef short bf16x8 __attribute__((ext_vector_type(8)));
typedef float f32x4  __attribute__((ext_vector_type(4)));

__device__ __forceinline__ float silu_f(float x) {
    return x * __builtin_amdgcn_rcpf(1.0f + __expf(-x));
}
__device__ __forceinline__ unsigned short bf16_rne(float x) {
    unsigned u = __float_as_uint(x);
    u += 0x7fffu + ((u >> 16) & 1u);
    return (unsigned short)(u >> 16);
}
__device__ __forceinline__ float bflo(unsigned u) { return __uint_as_float(u << 16); }
__device__ __forceinline__ float bfhi(unsigned u) { return __uint_as_float(u & 0xffff0000u); }
__device__ __forceinline__ f32x4 mfma16(bf16x8 a, bf16x8 b, f32x4 c) {
    return __builtin_amdgcn_mfma_f32_16x16x32_bf16(a, b, c, 0, 0, 0);
}
// lgkm-only barrier: drains LDS ops, leaves global loads/stores in flight.
__device__ __forceinline__ void barrier_lgkm() {
    asm volatile("s_waitcnt lgkmcnt(0)" ::: "memory");
    __builtin_amdgcn_s_barrier();
}

// ===========================================================================
// CSR build: histogram -> hierarchical scan (3 small kernels) -> scatter
// ===========================================================================
__global__ __launch_bounds__(256) void hist_kernel(const int* __restrict__ ei,
                                                   int* __restrict__ deg) {
    int e = blockIdx.x * 256 + threadIdx.x;
    if (e < EE) atomicAdd(&deg[ei[EE + e]], 1);
}

__global__ __launch_bounds__(512) void scanA_kernel(const int* __restrict__ deg,
                                                    int* __restrict__ rowptr,
                                                    int* __restrict__ bsum) {
    __shared__ int wsum[8];
    const int tid = threadIdx.x, b = blockIdx.x;
    int i = b * 512 + tid;
    int v = (i < NN) ? deg[i] : 0;
    int lane = tid & 63, wid = tid >> 6;
    int x = v;
#pragma unroll
    for (int s = 1; s < 64; s <<= 1) {
        int u = __shfl_up(x, s, 64);
        if (lane >= s) x += u;
    }
    if (lane == 63) wsum[wid] = x;
    __syncthreads();
    int woff = 0;
    for (int w = 0; w < wid; ++w) woff += wsum[w];
    if (i < NN) rowptr[i] = woff + x - v;
    if (tid == 511) bsum[b] = woff + x;
}

__global__ __launch_bounds__(128) void scanB_kernel(int* __restrict__ bsum, int nb) {
    __shared__ int wsum[2];
    const int tid = threadIdx.x;
    int v = (tid < nb) ? bsum[tid] : 0;
    int lane = tid & 63, wid = tid >> 6;
    int x = v;
#pragma unroll
    for (int s = 1; s < 64; s <<= 1) {
        int u = __shfl_up(x, s, 64);
        if (lane >= s) x += u;
    }
    if (lane == 63) wsum[wid] = x;
    __syncthreads();
    int woff = (wid == 1) ? wsum[0] : 0;
    if (tid < nb) bsum[tid] = woff + x - v;
}

__global__ __launch_bounds__(512) void scanC_kernel(int* __restrict__ rowptr,
                                                    int* __restrict__ cursor,
                                                    const int* __restrict__ bsum) {
    const int tid = threadIdx.x, b = blockIdx.x;
    int i = b * 512 + tid;
    if (i < NN) {
        int r = rowptr[i] + bsum[b];
        rowptr[i] = r;
        cursor[i] = r;
    }
    if (i == 0) rowptr[NN] = EE;
}

__global__ __launch_bounds__(256) void scatter_kernel(const int* __restrict__ ei,
                                                      int* __restrict__ cursor,
                                                      int* __restrict__ srcsS,
                                                      int* __restrict__ dstsS) {
    int e = blockIdx.x * 256 + threadIdx.x;
    if (e < EE) {
        int d = ei[EE + e];
        int pos = atomicAdd(&cursor[d], 1);
        srcsS[pos] = ei[e];
        dstsS[pos] = d;
    }
}

// ===========================================================================
// pk_kernel: Pt = h @ W1[0:64] (f32), Pb = h @ W1[64:128] (bf16 packed).
// Fused p=0/1 passes: 32 accumulators, hs read once (halved LDS reads).
// ===========================================================================
__global__ __launch_bounds__(512, 4) void pk_kernel(
    const float* __restrict__ h, const float* __restrict__ w1g,
    float* __restrict__ Pt, unsigned short* __restrict__ Pbu, int ntiles)
{
    extern __shared__ float lds[];
    float* ws = lds;            // [128][64] f32 = 32 KB
    float* hs = ws + 8192;      // [128][68] f32 = 34.8 KB
    const int tid = threadIdx.x;
    const int tr  = tid & 31;
    const int tc  = tid >> 5;

    for (int i = tid; i < 2048; i += 512)
        *(float4*)&ws[4 * i] = *(const float4*)&w1g[4 * i];

    for (int tile = blockIdx.x; tile < ntiles; tile += gridDim.x) {
        const int base = tile * 128;
        __syncthreads();
#pragma unroll
        for (int rep = 0; rep < 4; ++rep) {
            int idx = rep * 512 + tid;
            int r = idx >> 4, q = idx & 15;
            int n = base + r;
            float4 v = make_float4(0.f, 0.f, 0.f, 0.f);
            if (n < NN) v = *(const float4*)(h + 64 * n + 4 * q);
            *(float4*)&hs[r * 68 + 4 * q] = v;
        }
        __syncthreads();
        float acc[2][4][4];
#pragma unroll
        for (int p = 0; p < 2; ++p)
#pragma unroll
            for (int jj = 0; jj < 4; ++jj)
#pragma unroll
                for (int ii = 0; ii < 4; ++ii) acc[p][jj][ii] = 0.f;
#pragma unroll 2
        for (int k16 = 0; k16 < 16; ++k16) {
            float4 b00 = *(const float4*)&ws[(4 * k16 + 0) * 64 + 4 * tc];
            float4 b01 = *(const float4*)&ws[(4 * k16 + 1) * 64 + 4 * tc];
            float4 b02 = *(const float4*)&ws[(4 * k16 + 2) * 64 + 4 * tc];
            float4 b03 = *(const float4*)&ws[(4 * k16 + 3) * 64 + 4 * tc];
            float4 b10 = *(const float4*)&ws[(64 + 4 * k16 + 0) * 64 + 4 * tc];
            float4 b11 = *(const float4*)&ws[(64 + 4 * k16 + 1) * 64 + 4 * tc];
            float4 b12 = *(const float4*)&ws[(64 + 4 * k16 + 2) * 64 + 4 * tc];
            float4 b13 = *(const float4*)&ws[(64 + 4 * k16 + 3) * 64 + 4 * tc];
#pragma unroll
            for (int jj = 0; jj < 4; ++jj) {
                float4 av = *(const float4*)&hs[(tr + 32 * jj) * 68 + 4 * k16];
                acc[0][jj][0] = fmaf(av.x, b00.x, fmaf(av.y, b01.x, fmaf(av.z, b02.x, fmaf(av.w, b03.x, acc[0][jj][0]))));
                acc[0][jj][1] = fmaf(av.x, b00.y, fmaf(av.y, b01.y, fmaf(av.z, b02.y, fmaf(av.w, b03.y, acc[0][jj][1]))));
                acc[0][jj][2] = fmaf(av.x, b00.z, fmaf(av.y, b01.z, fmaf(av.z, b02.z, fmaf(av.w, b03.z, acc[0][jj][2]))));
                acc[0][jj][3] = fmaf(av.x, b00.w, fmaf(av.y, b01.w, fmaf(av.z, b02.w, fmaf(av.w, b03.w, acc[0][jj][3]))));
                acc[1][jj][0] = fmaf(av.x, b10.x, fmaf(av.y, b11.x, fmaf(av.z, b12.x, fmaf(av.w, b13.x, acc[1][jj][0]))));
                acc[1][jj][1] = fmaf(av.x, b10.y, fmaf(av.y, b11.y, fmaf(av.z, b12.y, fmaf(av.w, b13.y, acc[1][jj][1]))));
                acc[1][jj][2] = fmaf(av.x, b10.z, fmaf(av.y, b11.z, fmaf(av.z, b12.z, fmaf(av.w, b13.z, acc[1][jj][2]))));
                acc[1][jj][3] = fmaf(av.x, b10.w, fmaf(av.y, b11.w, fmaf(av.z, b12.w, fmaf(av.w, b13.w, acc[1][jj][3]))));
            }
        }
#pragma unroll
        for (int jj = 0; jj < 4; ++jj) {
            int n = base + tr + 32 * jj;
            if (n < NN) {
                *(float4*)(Pt + (size_t)64 * n + 4 * tc) =
                    make_float4(acc[0][jj][0], acc[0][jj][1], acc[0][jj][2], acc[0][jj][3]);
                uint2 o;
                o.x = ((unsigned)bf16_rne(acc[1][jj][1]) << 16) | bf16_rne(acc[1][jj][0]);
                o.y = ((unsigned)bf16_rne(acc[1][jj][3]) << 16) | bf16_rne(acc[1][jj][2]);
                *(uint2*)(Pbu + (size_t)64 * n + 4 * tc) = o;
            }
        }
    }
}

// ===========================================================================
// Edge kernel — round-14 proven structure (direct 2B fragment stores, 60 us)
// + biases hoisted to registers (tile-invariant; removes 6 lgkm-waited LDS
// reads/thread/tile from the hot loop).
// ===========================================================================
__global__ __launch_bounds__(512, 6) void edge_kernel(
    const float* __restrict__ Pt, const unsigned short* __restrict__ Pbu,
    const int* __restrict__ srcsS, const int* __restrict__ dstsS,
    const float* __restrict__ b1g,
    const float* __restrict__ w2g, const float* __restrict__ b2g,
    unsigned short* __restrict__ m2g, int ntiles)
{
    extern __shared__ __align__(16) char smem[];
    char*  wt2s = smem;                       // [64c][128B] swz   8192
    char*  m1s  = wt2s + 8192;                // [128r][128B] swz 16384
    float* b1s  = (float*)(m1s + 16384);      // 64 f32
    float* b2s  = b1s + 64;                   // 64 f32
    // total 25088 B

    const int tid = threadIdx.x;
    const int l   = tid & 63;
    const int w   = tid >> 6;
    const int mi  = w >> 1;
    const int ni  = w & 1;
    const int l15 = l & 15;
    const int l4  = l >> 4;
    const int g7  = tid & 7;

    {
        int c = tid >> 3, kc = tid & 7;
        const float* wp = w2g + (kc * 8) * 64 + c;
        bf16x8 bv;
#pragma unroll
        for (int j = 0; j < 8; ++j) bv[j] = (short)bf16_rne(wp[j * 64]);
        *(bf16x8*)(wt2s + c * 128 + ((kc * 16) ^ ((c & 7) << 4))) = bv;
    }
    if (tid < 64) { b1s[tid] = b1g[tid]; b2s[tid] = b2g[tid]; }

    int    ix_d[2], ix_s[2];
    float4 pf_a0[2], pf_a1[2];
    uint4  pf_pb[2];

    auto IDX = [&](int tt) {
        int eb = tt * 128;
#pragma unroll
        for (int it = 0; it < 2; ++it) {
            int e = (it * 512 + tid) >> 3;
            ix_d[it] = dstsS[eb + e];
            ix_s[it] = srcsS[eb + e];
        }
    };
    auto DATA = [&]() {
#pragma unroll
        for (int it = 0; it < 2; ++it) {
            const float* pt = Pt + (size_t)64 * ix_d[it] + 8 * g7;
            pf_a0[it] = *(const float4*)pt;
            pf_a1[it] = *(const float4*)(pt + 4);
            pf_pb[it] = *(const uint4*)(Pbu + (size_t)64 * ix_s[it] + 8 * g7);
        }
    };

    int tile = blockIdx.x;
    if (tile < ntiles) { IDX(tile); DATA(); }
    if (tile + gridDim.x < ntiles) IDX(tile + gridDim.x);
    barrier_lgkm();                               // staging visible

    // Hoist tile-invariant biases into registers.
    const float4 rb0  = *(const float4*)(b1s + 8 * g7);
    const float4 rb1  = *(const float4*)(b1s + 8 * g7 + 4);
    float bb2[2][2];
#pragma unroll
    for (int n = 0; n < 2; ++n)
#pragma unroll
        for (int m = 0; m < 1; ++m) { }
    bb2[0][0] = b2s[32 * ni + l15];
    bb2[0][1] = b2s[32 * ni + 16 + l15];

    for (; tile < ntiles; tile += gridDim.x) {
#pragma unroll
        for (int it = 0; it < 2; ++it) {
            int e = (it * 512 + tid) >> 3;
            float v0 = silu_f(pf_a0[it].x + bflo(pf_pb[it].x) + rb0.x);
            float v1 = silu_f(pf_a0[it].y + bfhi(pf_pb[it].x) + rb0.y);
            float v2 = silu_f(pf_a0[it].z + bflo(pf_pb[it].y) + rb0.z);
            float v3 = silu_f(pf_a0[it].w + bfhi(pf_pb[it].y) + rb0.w);
            float v4 = silu_f(pf_a1[it].x + bflo(pf_pb[it].z) + rb1.x);
            float v5 = silu_f(pf_a1[it].y + bfhi(pf_pb[it].z) + rb1.y);
            float v6 = silu_f(pf_a1[it].z + bflo(pf_pb[it].w) + rb1.z);
            float v7 = silu_f(pf_a1[it].w + bfhi(pf_pb[it].w) + rb1.w);
            uint4 o;
            o.x = ((unsigned)bf16_rne(v1) << 16) | bf16_rne(v0);
            o.y = ((unsigned)bf16_rne(v3) << 16) | bf16_rne(v2);
            o.z = ((unsigned)bf16_rne(v5) << 16) | bf16_rne(v4);
            o.w = ((unsigned)bf16_rne(v7) << 16) | bf16_rne(v6);
            *(uint4*)(m1s + e * 128 + ((g7 * 16) ^ ((e & 7) << 4))) = o;
        }
        barrier_lgkm();                           // B1: m1s ready
        int nxt = tile + gridDim.x;
        if (nxt < ntiles) {
            DATA();                               // idx regs completed 1 iter ago
            if (nxt + gridDim.x < ntiles) IDX(nxt + gridDim.x);
        }
        f32x4 acc2[2][2];
#pragma unroll
        for (int m = 0; m < 2; ++m)
#pragma unroll
            for (int n = 0; n < 2; ++n) {
                float b = bb2[0][n];
                acc2[m][n] = (f32x4){b, b, b, b};
            }
        const int sw = (l15 & 7) << 4;
#pragma unroll
        for (int ks = 0; ks < 2; ++ks) {
            int kb = ks * 64 + l4 * 16;
            bf16x8 af[2], bfr[2];
#pragma unroll
            for (int m = 0; m < 2; ++m)
                af[m] = *(const bf16x8*)(m1s + (32 * mi + 16 * m + l15) * 128 + (kb ^ sw));
#pragma unroll
            for (int n = 0; n < 2; ++n)
                bfr[n] = *(const bf16x8*)(wt2s + (32 * ni + 16 * n + l15) * 128 + (kb ^ sw));
#pragma unroll
            for (int m = 0; m < 2; ++m)
#pragma unroll
                for (int n = 0; n < 2; ++n)
                    acc2[m][n] = mfma16(af[m], bfr[n], acc2[m][n]);
        }
        // m2 = silu -> direct bf16 global store (proven 60us path)
        unsigned short* mg = m2g + (size_t)(tile * 128) * 64;
#pragma unroll
        for (int m = 0; m < 2; ++m)
#pragma unroll
            for (int n = 0; n < 2; ++n)
#pragma unroll
                for (int r = 0; r < 4; ++r) {
                    int row = 32 * mi + 16 * m + l4 * 4 + r;
                    int col = 32 * ni + 16 * n + l15;
                    mg[row * 64 + col] = bf16_rne(silu_f(acc2[m][n][r]));
                }
        barrier_lgkm();                           // B2: m1s reads done before next write
    }
}

// ===========================================================================
// agg_kernel: agg[n] = sum of contiguous m2g rows (CSR). Thread = (node, 4 cols).
// ===========================================================================
__global__ __launch_bounds__(256) void agg_kernel(
    const unsigned short* __restrict__ m2g, const int* __restrict__ rowptr,
    float* __restrict__ agg)
{
    int idx = blockIdx.x * 256 + threadIdx.x;
    if (idx >= NN * 16) return;
    int n = idx >> 4, c = idx & 15;
    int e0 = rowptr[n], e1 = rowptr[n + 1];
    float a0 = 0.f, a1 = 0.f, a2 = 0.f, a3 = 0.f;
    int e = e0;
    for (; e + 4 <= e1; e += 4) {
        uint2 u0 = *(const uint2*)(m2g + (size_t)(e + 0) * 64 + 4 * c);
        uint2 u1 = *(const uint2*)(m2g + (size_t)(e + 1) * 64 + 4 * c);
        uint2 u2 = *(const uint2*)(m2g + (size_t)(e + 2) * 64 + 4 * c);
        uint2 u3 = *(const uint2*)(m2g + (size_t)(e + 3) * 64 + 4 * c);
        a0 += (bflo(u0.x) + bflo(u1.x)) + (bflo(u2.x) + bflo(u3.x));
        a1 += (bfhi(u0.x) + bfhi(u1.x)) + (bfhi(u2.x) + bfhi(u3.x));
        a2 += (bflo(u0.y) + bflo(u1.y)) + (bflo(u2.y) + bflo(u3.y));
        a3 += (bfhi(u0.y) + bfhi(u1.y)) + (bfhi(u2.y) + bfhi(u3.y));
    }
    for (; e < e1; ++e) {
        uint2 u = *(const uint2*)(m2g + (size_t)e * 64 + 4 * c);
        a0 += bflo(u.x); a1 += bfhi(u.x);
        a2 += bflo(u.y); a3 += bfhi(u.y);
    }
    *(float4*)(agg + (size_t)64 * n + 4 * c) = make_float4(a0, a1, a2, a3);
}

// ===========================================================================
// Node row-MLP: cats=[h|agg], u=silu(cats@W1+b1), h = u@W2 + b2 + h.
// ===========================================================================
__global__ __launch_bounds__(512, 1) void node_mlp_kernel(
    const float* __restrict__ A, const float* __restrict__ A2,
    const float* __restrict__ w1g, const float* __restrict__ b1g,
    const float* __restrict__ w2g, const float* __restrict__ b2g,
    float* __restrict__ outp, int nrows, int ntiles)
{
    extern __shared__ float lds[];
    float* ws1  = lds;
    float* ws2  = ws1 + 8192;
    float* wb1  = ws2 + 4096;
    float* wb2  = wb1 + 64;
    float* cats = wb2 + 64;
    float* m1s  = cats + 128 * 132;

    const int tid = threadIdx.x;
    const int tr  = tid & 31;
    const int tc  = tid >> 5;

    for (int i = tid; i < 2048; i += 512)
        *(float4*)&ws1[4 * i] = *(const float4*)&w1g[4 * i];
    for (int i = tid; i < 1024; i += 512)
        *(float4*)&ws2[4 * i] = *(const float4*)&w2g[4 * i];
    if (tid < 64) { wb1[tid] = b1g[tid]; wb2[tid] = b2g[tid]; }

    for (int tile = blockIdx.x; tile < ntiles; tile += gridDim.x) {
        const int base = tile * 128;
        __syncthreads();
#pragma unroll
        for (int rep = 0; rep < 8; ++rep) {
            int idx = rep * 512 + tid;
            int r = idx >> 5, q = idx & 31;
            int n = base + r;
            float4 v = make_float4(0.f, 0.f, 0.f, 0.f);
            if (n < nrows)
                v = (q < 16) ? *(const float4*)(A + 64 * n + 4 * q)
                             : *(const float4*)(A2 + 64 * n + 4 * (q - 16));
            *(float4*)&cats[r * 132 + 4 * q] = v;
        }
        __syncthreads();
        float acc[4][4];
#pragma unroll
        for (int jj = 0; jj < 4; ++jj)
#pragma unroll
            for (int ii = 0; ii < 4; ++ii) acc[jj][ii] = wb1[4 * tc + ii];
#pragma unroll 4
        for (int k16 = 0; k16 < 32; ++k16) {
            float4 bv0 = *(const float4*)&ws1[(4 * k16 + 0) * 64 + 4 * tc];
            float4 bv1 = *(const float4*)&ws1[(4 * k16 + 1) * 64 + 4 * tc];
            float4 bv2 = *(const float4*)&ws1[(4 * k16 + 2) * 64 + 4 * tc];
            float4 bv3 = *(const float4*)&ws1[(4 * k16 + 3) * 64 + 4 * tc];
#pragma unroll
            for (int jj = 0; jj < 4; ++jj) {
                float4 av = *(const float4*)&cats[(tr + 32 * jj) * 132 + 4 * k16];
                acc[jj][0] = fmaf(av.x, bv0.x, fmaf(av.y, bv1.x, fmaf(av.z, bv2.x, fmaf(av.w, bv3.x, acc[jj][0]))));
                acc[jj][1] = fmaf(av.x, bv0.y, fmaf(av.y, bv1.y, fmaf(av.z, bv2.y, fmaf(av.w, bv3.y, acc[jj][1]))));
                acc[jj][2] = fmaf(av.x, bv0.z, fmaf(av.y, bv1.z, fmaf(av.z, bv2.z, fmaf(av.w, bv3.z, acc[jj][2]))));
                acc[jj][3] = fmaf(av.x, bv0.w, fmaf(av.y, bv1.w, fmaf(av.z, bv2.w, fmaf(av.w, bv3.w, acc[jj][3]))));
            }
        }
#pragma unroll
        for (int jj = 0; jj < 4; ++jj) {
            float4 v;
            v.x = silu_f(acc[jj][0]); v.y = silu_f(acc[jj][1]);
            v.z = silu_f(acc[jj][2]); v.w = silu_f(acc[jj][3]);
            *(float4*)&m1s[(tr + 32 * jj) * 68 + 4 * tc] = v;
        }
        __syncthreads();
        float acc2[4][4];
#pragma unroll
        for (int jj = 0; jj < 4; ++jj)
#pragma unroll
            for (int ii = 0; ii < 4; ++ii) acc2[jj][ii] = wb2[4 * tc + ii];
#pragma unroll 4
        for (int k16 = 0; k16 < 16; ++k16) {
            float4 bv0 = *(const float4*)&ws2[(4 * k16 + 0) * 64 + 4 * tc];
            float4 bv1 = *(const float4*)&ws2[(4 * k16 + 1) * 64 + 4 * tc];
            float4 bv2 = *(const float4*)&ws2[(4 * k16 + 2) * 64 + 4 * tc];
            float4 bv3 = *(const float4*)&ws2[(4 * k16 + 3) * 64 + 4 * tc];
#pragma unroll
            for (int jj = 0; jj < 4; ++jj) {
                float4 av = *(const float4*)&m1s[(tr + 32 * jj) * 68 + 4 * k16];
                acc2[jj][0] = fmaf(av.x, bv0.x, fmaf(av.y, bv1.x, fmaf(av.z, bv2.x, fmaf(av.w, bv3.x, acc2[jj][0]))));
                acc2[jj][1] = fmaf(av.x, bv0.y, fmaf(av.y, bv1.y, fmaf(av.z, bv2.y, fmaf(av.w, bv3.y, acc2[jj][1]))));
                acc2[jj][2] = fmaf(av.x, bv0.z, fmaf(av.y, bv1.z, fmaf(av.z, bv2.z, fmaf(av.w, bv3.z, acc2[jj][2]))));
                acc2[jj][3] = fmaf(av.x, bv0.w, fmaf(av.y, bv1.w, fmaf(av.z, bv2.w, fmaf(av.w, bv3.w, acc2[jj][3]))));
            }
        }
#pragma unroll
        for (int jj = 0; jj < 4; ++jj) {
            int r = tr + 32 * jj;
            int n = base + r;
            if (n < nrows) {
                float4 hold = *(const float4*)&cats[r * 132 + 4 * tc];
                *(float4*)&outp[64 * n + 4 * tc] = make_float4(
                    acc2[jj][0] + hold.x, acc2[jj][1] + hold.y,
                    acc2[jj][2] + hold.z, acc2[jj][3] + hold.w);
            }
        }
    }
}

// ===========================================================================
// Readout row-MLP (K1=64, segmented scatter into gsum)
// ===========================================================================
__global__ __launch_bounds__(512, 1) void rowmlp_ro_kernel(
    const float* __restrict__ A,
    const float* __restrict__ w1g, const float* __restrict__ b1g,
    const float* __restrict__ w2g, const float* __restrict__ b2g,
    const int* __restrict__ seg, float* __restrict__ outp,
    int nrows, int ntiles)
{
    extern __shared__ float lds[];
    float* ws1  = lds;
    float* ws2  = ws1 + 4096;
    float* wb1  = ws2 + 4096;
    float* wb2  = wb1 + 64;
    float* cats = wb2 + 64;
    float* m1s  = cats + 128 * 68;
    int*   segs = (int*)(m1s + 128 * 68);

    const int tid = threadIdx.x;
    const int tr  = tid & 31;
    const int tc  = tid >> 5;

    for (int i = tid; i < 1024; i += 512) {
        *(float4*)&ws1[4 * i] = *(const float4*)&w1g[4 * i];
        *(float4*)&ws2[4 * i] = *(const float4*)&w2g[4 * i];
    }
    if (tid < 64) { wb1[tid] = b1g[tid]; wb2[tid] = b2g[tid]; }

    for (int tile = blockIdx.x; tile < ntiles; tile += gridDim.x) {
        const int base = tile * 128;
        __syncthreads();
        if (tid < 128) segs[tid] = (base + tid < nrows) ? seg[base + tid] : -1;
#pragma unroll
        for (int rep = 0; rep < 4; ++rep) {
            int idx = rep * 512 + tid;
            int r = idx >> 4, q = idx & 15;
            int n = base + r;
            float4 v = make_float4(0.f, 0.f, 0.f, 0.f);
            if (n < nrows) v = *(const float4*)(A + 64 * n + 4 * q);
            *(float4*)&cats[r * 68 + 4 * q] = v;
        }
        __syncthreads();
        float acc[4][4];
#pragma unroll
        for (int jj = 0; jj < 4; ++jj)
#pragma unroll
            for (int ii = 0; ii < 4; ++ii) acc[jj][ii] = wb1[4 * tc + ii];
#pragma unroll 4
        for (int k16 = 0; k16 < 16; ++k16) {
            float4 bv0 = *(const float4*)&ws1[(4 * k16 + 0) * 64 + 4 * tc];
            float4 bv1 = *(const float4*)&ws1[(4 * k16 + 1) * 64 + 4 * tc];
            float4 bv2 = *(const float4*)&ws1[(4 * k16 + 2) * 64 + 4 * tc];
            float4 bv3 = *(const float4*)&ws1[(4 * k16 + 3) * 64 + 4 * tc];
#pragma unroll
            for (int jj = 0; jj < 4; ++jj) {
                float4 av = *(const float4*)&cats[(tr + 32 * jj) * 68 + 4 * k16];
                acc[jj][0] = fmaf(av.x, bv0.x, fmaf(av.y, bv1.x, fmaf(av.z, bv2.x, fmaf(av.w, bv3.x, acc[jj][0]))));
                acc[jj][1] = fmaf(av.x, bv0.y, fmaf(av.y, bv1.y, fmaf(av.z, bv2.y, fmaf(av.w, bv3.y, acc[jj][1]))));
                acc[jj][2] = fmaf(av.x, bv0.z, fmaf(av.y, bv1.z, fmaf(av.z, bv2.z, fmaf(av.w, bv3.z, acc[jj][2]))));
                acc[jj][3] = fmaf(av.x, bv0.w, fmaf(av.y, bv1.w, fmaf(av.z, bv2.w, fmaf(av.w, bv3.w, acc[jj][3]))));
            }
        }
#pragma unroll
        for (int jj = 0; jj < 4; ++jj) {
            float4 v;
            v.x = silu_f(acc[jj][0]); v.y = silu_f(acc[jj][1]);
            v.z = silu_f(acc[jj][2]); v.w = silu_f(acc[jj][3]);
            *(float4*)&m1s[(tr + 32 * jj) * 68 + 4 * tc] = v;
        }
        __syncthreads();
        float acc2[4][4];
#pragma unroll
        for (int jj = 0; jj < 4; ++jj)
#pragma unroll
            for (int ii = 0; ii < 4; ++ii) acc2[jj][ii] = wb2[4 * tc + ii];
#pragma unroll 4
        for (int k16 = 0; k16 < 16; ++k16) {
            float4 bv0 = *(const float4*)&ws2[(4 * k16 + 0) * 64 + 4 * tc];
            float4 bv1 = *(const float4*)&ws2[(4 * k16 + 1) * 64 + 4 * tc];
            float4 bv2 = *(const float4*)&ws2[(4 * k16 + 2) * 64 + 4 * tc];
            float4 bv3 = *(const float4*)&ws2[(4 * k16 + 3) * 64 + 4 * tc];
#pragma unroll
            for (int jj = 0; jj < 4; ++jj) {
                float4 av = *(const float4*)&m1s[(tr + 32 * jj) * 68 + 4 * k16];
                acc2[jj][0] = fmaf(av.x, bv0.x, fmaf(av.y, bv1.x, fmaf(av.z, bv2.x, fmaf(av.w, bv3.x, acc2[jj][0]))));
                acc2[jj][1] = fmaf(av.x, bv0.y, fmaf(av.y, bv1.y, fmaf(av.z, bv2.y, fmaf(av.w, bv3.y, acc2[jj][1]))));
                acc2[jj][2] = fmaf(av.x, bv0.z, fmaf(av.y, bv1.z, fmaf(av.z, bv2.z, fmaf(av.w, bv3.z, acc2[jj][2]))));
                acc2[jj][3] = fmaf(av.x, bv0.w, fmaf(av.y, bv1.w, fmaf(av.z, bv2.w, fmaf(av.w, bv3.w, acc2[jj][3]))));
            }
        }
#pragma unroll
        for (int jj = 0; jj < 4; ++jj) {
            int r = tr + 32 * jj;
            int n = base + r;
            int gid = segs[r];
            float4 vv = (n < nrows) ? make_float4(acc2[jj][0], acc2[jj][1], acc2[jj][2], acc2[jj][3])
                                    : make_float4(0.f, 0.f, 0.f, 0.f);
            unsigned f = (tr == 0 || segs[(r > 0) ? r - 1 : 0] != gid) ? 1u : 0u;
#pragma unroll
            for (int s = 1; s < 32; s <<= 1) {
                float ux = __shfl_up(vv.x, s, 32);
                float uy = __shfl_up(vv.y, s, 32);
                float uz = __shfl_up(vv.z, s, 32);
                float uw = __shfl_up(vv.w, s, 32);
                unsigned uf = __shfl_up(f, s, 32);
                if (tr >= s) {
                    if (!f) { vv.x += ux; vv.y += uy; vv.z += uz; vv.w += uw; }
                    f |= uf;
                }
            }
            bool tail = (tr == 31) || (segs[r + 1] != gid);
            if (tail && gid >= 0) {
                float* bp = outp + 64 * gid + 4 * tc;
                atomicAdd(bp + 0, vv.x); atomicAdd(bp + 1, vv.y);
                atomicAdd(bp + 2, vv.z); atomicAdd(bp + 3, vv.w);
            }
        }
    }
}

__global__ __launch_bounds__(256) void proj_kernel(
    const float* __restrict__ x, const float* __restrict__ w,
    const float* __restrict__ b, float* __restrict__ h, int n)
{
    int i = blockIdx.x * 256 + threadIdx.x;
    if (i >= n * 64) return;
    int node = i >> 6, j = i & 63;
    const float* xr = x + node * 14;
    float acc = b[j];
#pragma unroll
    for (int k = 0; k < 14; ++k) acc = fmaf(xr[k], w[k * 64 + j], acc);
    h[i] = acc;
}

__global__ __launch_bounds__(256) void head_kernel(
    const float* __restrict__ gsum,
    const float* __restrict__ w3, const float* __restrict__ b3,
    const float* __restrict__ w4, const float* __restrict__ b4,
    float* __restrict__ out, int g_count)
{
    int wid  = (blockIdx.x * 256 + threadIdx.x) >> 6;
    int lane = threadIdx.x & 63;
    if (wid >= g_count) return;
    float v = gsum[wid * 64 + lane];
    float t = b3[lane];
#pragma unroll
    for (int k = 0; k < 64; ++k) {
        float a = __shfl(v, k, 64);
        t = fmaf(a, w3[k * 64 + lane], t);
    }
    t = silu_f(t);
    float r = t * w4[lane];
#pragma unroll
    for (int off = 32; off; off >>= 1) r += __shfl_down(r, off, 64);
    if (lane == 0) out[wid] = r + b4[0];
}

extern "C" void kernel_launch(void* const* d_in, const int* in_sizes, int n_in,
                              void* d_out, int out_size, void* d_ws, size_t ws_size,
                              hipStream_t stream)
{
    const float* x      = (const float*)d_in[0];
    const int*   ei     = (const int*)d_in[2];
    const int*   batch  = (const int*)d_in[3];
    const float* proj_w = (const float*)d_in[4];
    const float* proj_b = (const float*)d_in[5];
    const float* ew1 = (const float*)d_in[6];
    const float* eb1 = (const float*)d_in[7];
    const float* ew2 = (const float*)d_in[8];
    const float* eb2 = (const float*)d_in[9];
    const float* nw1 = (const float*)d_in[10];
    const float* nb1 = (const float*)d_in[11];
    const float* nw2 = (const float*)d_in[12];
    const float* nb2 = (const float*)d_in[13];
    const float* l1w = (const float*)d_in[14]; const float* l1b = (const float*)d_in[15];
    const float* l2w = (const float*)d_in[16]; const float* l2b = (const float*)d_in[17];
    const float* l3w = (const float*)d_in[18]; const float* l3b = (const float*)d_in[19];
    const float* l4w = (const float*)d_in[20]; const float* l4b = (const float*)d_in[21];

    float* out  = (float*)d_out;
    float* h    = out + GG;                      // per_atom_out doubles as h

    unsigned short* m2g = (unsigned short*)d_ws;             // [E,64] bf16 = 102.4MB
    float* gsum = (float*)(m2g + (size_t)EE * 64);           // [G,64]
    float* Pt   = gsum + (size_t)GG * 64;                    // [N,64] f32
    unsigned short* Pbu = (unsigned short*)(Pt + (size_t)NN * 64);  // [N,64] bf16
    int* deg    = (int*)(Pbu + (size_t)NN * 64);
    int* rowptr = deg + NN;                                  // N+1
    int* cursor = rowptr + NN + 1;
    int* srcsS  = cursor + NN;                               // [E]
    int* dstsS  = srcsS + EE;                                // [E]
    int* bsum   = dstsS + EE;                                // [98]
    float* agg  = Pt;   // alias: Pt dead after edge_kernel, rebuilt next layer

    const size_t edge_lds = 8192 + 16384 + 256 + 256;                 // 25088
    const size_t pk_lds   = (size_t)(8192 + 8704) * 4;                // 67584
    const size_t node_lds = (size_t)(8192 + 4096 + 128 + 128 * 132 + 128 * 68) * 4;
    const size_t ro_lds   = (size_t)(4096 + 4096 + 128 + 128 * 68 + 128 * 68) * 4 + 128 * 4;

    (void)hipFuncSetAttribute((const void*)edge_kernel,
                              hipFuncAttributeMaxDynamicSharedMemorySize, (int)edge_lds);
    (void)hipFuncSetAttribute((const void*)pk_kernel,
                              hipFuncAttributeMaxDynamicSharedMemorySize, (int)pk_lds);
    (void)hipFuncSetAttribute((const void*)node_mlp_kernel,
                              hipFuncAttributeMaxDynamicSharedMemorySize, (int)node_lds);
    (void)hipFuncSetAttribute((const void*)rowmlp_ro_kernel,
                              hipFuncAttributeMaxDynamicSharedMemorySize, (int)ro_lds);

    // --- CSR build (dst-sorted edge arrays) ---
    const int nb = (NN + 511) / 512;           // 98
    hipMemsetAsync(deg, 0, (size_t)NN * sizeof(int), stream);
    hipMemsetAsync(gsum, 0, (size_t)GG * 64 * sizeof(float), stream);
    hist_kernel<<<(EE + 255) / 256, 256, 0, stream>>>(ei, deg);
    scanA_kernel<<<nb, 512, 0, stream>>>(deg, rowptr, bsum);
    scanB_kernel<<<1, 128, 0, stream>>>(bsum, nb);
    scanC_kernel<<<nb, 512, 0, stream>>>(rowptr, cursor, bsum);
    scatter_kernel<<<(EE + 255) / 256, 256, 0, stream>>>(ei, cursor, srcsS, dstsS);

    proj_kernel<<<(NN * 64 + 255) / 256, 256, 0, stream>>>(x, proj_w, proj_b, h, NN);

    const int etiles = EE / 128;               // 6250 (exact)
    const int ntiles = (NN + 127) / 128;       // 391
    for (int l = 0; l < LL; ++l) {
        pk_kernel<<<ntiles, 512, pk_lds, stream>>>(h, ew1 + l * 8192, Pt, Pbu, ntiles);
        edge_kernel<<<1024, 512, edge_lds, stream>>>(
            Pt, Pbu, srcsS, dstsS, eb1 + l * 64, ew2 + l * 4096, eb2 + l * 64,
            m2g, etiles);
        agg_kernel<<<(NN * 16 + 255) / 256, 256, 0, stream>>>(m2g, rowptr, agg);
        node_mlp_kernel<<<196, 512, node_lds, stream>>>(
            h, agg, nw1 + l * 8192, nb1 + l * 64, nw2 + l * 4096, nb2 + l * 64,
            h, NN, ntiles);
    }
    rowmlp_ro_kernel<<<196, 512, ro_lds, stream>>>(
        h, l1w, l1b, l2w, l2b, batch, gsum, NN, ntiles);
    head_kernel<<<GG / 4, 256, 0, stream>>>(gsum, l3w, l3b, l4w, l4b, out, GG);
}

// Round 17
// 506.080 us; speedup vs baseline: 1.4214x; 1.3887x over previous
//
#include <hip/hip_runtime.h>

#define NN 50000
#define EE 800000
#define GG 512
#define LL 3

typedef short bf16x8 __attribute__((ext_vector_type(8)));
typedef float f32x4  __attribute__((ext_vector_type(4)));

__device__ __forceinline__ float silu_f(float x) {
    return x * __builtin_amdgcn_rcpf(1.0f + __expf(-x));
}
__device__ __forceinline__ unsigned short bf16_rne(float x) {
    unsigned u = __float_as_uint(x);
    u += 0x7fffu + ((u >> 16) & 1u);
    return (unsigned short)(u >> 16);
}
__device__ __forceinline__ float bflo(unsigned u) { return __uint_as_float(u << 16); }
__device__ __forceinline__ float bfhi(unsigned u) { return __uint_as_float(u & 0xffff0000u); }
__device__ __forceinline__ f32x4 mfma16(bf16x8 a, bf16x8 b, f32x4 c) {
    return __builtin_amdgcn_mfma_f32_16x16x32_bf16(a, b, c, 0, 0, 0);
}
// lgkm-only barrier: drains LDS ops, leaves global loads/stores in flight.
__device__ __forceinline__ void barrier_lgkm() {
    asm volatile("s_waitcnt lgkmcnt(0)" ::: "memory");
    __builtin_amdgcn_s_barrier();
}

// ===========================================================================
// CSR build: histogram -> hierarchical scan (3 small kernels) -> scatter
// ===========================================================================
__global__ __launch_bounds__(256) void hist_kernel(const int* __restrict__ ei,
                                                   int* __restrict__ deg) {
    int e = blockIdx.x * 256 + threadIdx.x;
    if (e < EE) atomicAdd(&deg[ei[EE + e]], 1);
}

__global__ __launch_bounds__(512) void scanA_kernel(const int* __restrict__ deg,
                                                    int* __restrict__ rowptr,
                                                    int* __restrict__ bsum) {
    __shared__ int wsum[8];
    const int tid = threadIdx.x, b = blockIdx.x;
    int i = b * 512 + tid;
    int v = (i < NN) ? deg[i] : 0;
    int lane = tid & 63, wid = tid >> 6;
    int x = v;
#pragma unroll
    for (int s = 1; s < 64; s <<= 1) {
        int u = __shfl_up(x, s, 64);
        if (lane >= s) x += u;
    }
    if (lane == 63) wsum[wid] = x;
    __syncthreads();
    int woff = 0;
    for (int w = 0; w < wid; ++w) woff += wsum[w];
    if (i < NN) rowptr[i] = woff + x - v;
    if (tid == 511) bsum[b] = woff + x;
}

__global__ __launch_bounds__(128) void scanB_kernel(int* __restrict__ bsum, int nb) {
    __shared__ int wsum[2];
    const int tid = threadIdx.x;
    int v = (tid < nb) ? bsum[tid] : 0;
    int lane = tid & 63, wid = tid >> 6;
    int x = v;
#pragma unroll
    for (int s = 1; s < 64; s <<= 1) {
        int u = __shfl_up(x, s, 64);
        if (lane >= s) x += u;
    }
    if (lane == 63) wsum[wid] = x;
    __syncthreads();
    int woff = (wid == 1) ? wsum[0] : 0;
    if (tid < nb) bsum[tid] = woff + x - v;
}

__global__ __launch_bounds__(512) void scanC_kernel(int* __restrict__ rowptr,
                                                    int* __restrict__ cursor,
                                                    const int* __restrict__ bsum) {
    const int tid = threadIdx.x, b = blockIdx.x;
    int i = b * 512 + tid;
    if (i < NN) {
        int r = rowptr[i] + bsum[b];
        rowptr[i] = r;
        cursor[i] = r;
    }
    if (i == 0) rowptr[NN] = EE;
}

__global__ __launch_bounds__(256) void scatter_kernel(const int* __restrict__ ei,
                                                      int* __restrict__ cursor,
                                                      int* __restrict__ srcsS,
                                                      int* __restrict__ dstsS) {
    int e = blockIdx.x * 256 + threadIdx.x;
    if (e < EE) {
        int d = ei[EE + e];
        int pos = atomicAdd(&cursor[d], 1);
        srcsS[pos] = ei[e];
        dstsS[pos] = d;
    }
}

// ===========================================================================
// pk_kernel: Pt = h @ W1[0:64] (f32), Pb = h @ W1[64:128] (bf16 packed).
// Fused p=0/1 passes: 32 accumulators, hs read once (halved LDS reads).
// ===========================================================================
__global__ __launch_bounds__(512, 4) void pk_kernel(
    const float* __restrict__ h, const float* __restrict__ w1g,
    float* __restrict__ Pt, unsigned short* __restrict__ Pbu, int ntiles)
{
    extern __shared__ float lds[];
    float* ws = lds;            // [128][64] f32 = 32 KB
    float* hs = ws + 8192;      // [128][68] f32 = 34.8 KB
    const int tid = threadIdx.x;
    const int tr  = tid & 31;
    const int tc  = tid >> 5;

    for (int i = tid; i < 2048; i += 512)
        *(float4*)&ws[4 * i] = *(const float4*)&w1g[4 * i];

    for (int tile = blockIdx.x; tile < ntiles; tile += gridDim.x) {
        const int base = tile * 128;
        __syncthreads();
#pragma unroll
        for (int rep = 0; rep < 4; ++rep) {
            int idx = rep * 512 + tid;
            int r = idx >> 4, q = idx & 15;
            int n = base + r;
            float4 v = make_float4(0.f, 0.f, 0.f, 0.f);
            if (n < NN) v = *(const float4*)(h + 64 * n + 4 * q);
            *(float4*)&hs[r * 68 + 4 * q] = v;
        }
        __syncthreads();
        float acc[2][4][4];
#pragma unroll
        for (int p = 0; p < 2; ++p)
#pragma unroll
            for (int jj = 0; jj < 4; ++jj)
#pragma unroll
                for (int ii = 0; ii < 4; ++ii) acc[p][jj][ii] = 0.f;
#pragma unroll 2
        for (int k16 = 0; k16 < 16; ++k16) {
            float4 b00 = *(const float4*)&ws[(4 * k16 + 0) * 64 + 4 * tc];
            float4 b01 = *(const float4*)&ws[(4 * k16 + 1) * 64 + 4 * tc];
            float4 b02 = *(const float4*)&ws[(4 * k16 + 2) * 64 + 4 * tc];
            float4 b03 = *(const float4*)&ws[(4 * k16 + 3) * 64 + 4 * tc];
            float4 b10 = *(const float4*)&ws[(64 + 4 * k16 + 0) * 64 + 4 * tc];
            float4 b11 = *(const float4*)&ws[(64 + 4 * k16 + 1) * 64 + 4 * tc];
            float4 b12 = *(const float4*)&ws[(64 + 4 * k16 + 2) * 64 + 4 * tc];
            float4 b13 = *(const float4*)&ws[(64 + 4 * k16 + 3) * 64 + 4 * tc];
#pragma unroll
            for (int jj = 0; jj < 4; ++jj) {
                float4 av = *(const float4*)&hs[(tr + 32 * jj) * 68 + 4 * k16];
                acc[0][jj][0] = fmaf(av.x, b00.x, fmaf(av.y, b01.x, fmaf(av.z, b02.x, fmaf(av.w, b03.x, acc[0][jj][0]))));
                acc[0][jj][1] = fmaf(av.x, b00.y, fmaf(av.y, b01.y, fmaf(av.z, b02.y, fmaf(av.w, b03.y, acc[0][jj][1]))));
                acc[0][jj][2] = fmaf(av.x, b00.z, fmaf(av.y, b01.z, fmaf(av.z, b02.z, fmaf(av.w, b03.z, acc[0][jj][2]))));
                acc[0][jj][3] = fmaf(av.x, b00.w, fmaf(av.y, b01.w, fmaf(av.z, b02.w, fmaf(av.w, b03.w, acc[0][jj][3]))));
                acc[1][jj][0] = fmaf(av.x, b10.x, fmaf(av.y, b11.x, fmaf(av.z, b12.x, fmaf(av.w, b13.x, acc[1][jj][0]))));
                acc[1][jj][1] = fmaf(av.x, b10.y, fmaf(av.y, b11.y, fmaf(av.z, b12.y, fmaf(av.w, b13.y, acc[1][jj][1]))));
                acc[1][jj][2] = fmaf(av.x, b10.z, fmaf(av.y, b11.z, fmaf(av.z, b12.z, fmaf(av.w, b13.z, acc[1][jj][2]))));
                acc[1][jj][3] = fmaf(av.x, b10.w, fmaf(av.y, b11.w, fmaf(av.z, b12.w, fmaf(av.w, b13.w, acc[1][jj][3]))));
            }
        }
#pragma unroll
        for (int jj = 0; jj < 4; ++jj) {
            int n = base + tr + 32 * jj;
            if (n < NN) {
                *(float4*)(Pt + (size_t)64 * n + 4 * tc) =
                    make_float4(acc[0][jj][0], acc[0][jj][1], acc[0][jj][2], acc[0][jj][3]);
                uint2 o;
                o.x = ((unsigned)bf16_rne(acc[1][jj][1]) << 16) | bf16_rne(acc[1][jj][0]);
                o.y = ((unsigned)bf16_rne(acc[1][jj][3]) << 16) | bf16_rne(acc[1][jj][2]);
                *(uint2*)(Pbu + (size_t)64 * n + 4 * tc) = o;
            }
        }
    }
}

// ===========================================================================
// Edge kernel — BYTE-EXACT round-14 version (61 us, FETCH 66 / WRITE 112 MB).
// Round 16's bias-hoist re-phased the scattered 2B stores and doubled L2
// RMW traffic (WRITE 246 MB) — do NOT perturb this kernel's store timing.
// ===========================================================================
__global__ __launch_bounds__(512, 6) void edge_kernel(
    const float* __restrict__ Pt, const unsigned short* __restrict__ Pbu,
    const int* __restrict__ srcsS, const int* __restrict__ dstsS,
    const float* __restrict__ b1g,
    const float* __restrict__ w2g, const float* __restrict__ b2g,
    unsigned short* __restrict__ m2g, int ntiles)
{
    extern __shared__ __align__(16) char smem[];
    char*  wt2s = smem;                       // [64c][128B] swz   8192
    char*  m1s  = wt2s + 8192;                // [128r][128B] swz 16384
    float* b1s  = (float*)(m1s + 16384);      // 64 f32
    float* b2s  = b1s + 64;                   // 64 f32
    // total 25088 B

    const int tid = threadIdx.x;
    const int l   = tid & 63;
    const int w   = tid >> 6;
    const int mi  = w >> 1;
    const int ni  = w & 1;
    const int l15 = l & 15;
    const int l4  = l >> 4;
    const int g7  = tid & 7;

    {
        int c = tid >> 3, kc = tid & 7;
        const float* wp = w2g + (kc * 8) * 64 + c;
        bf16x8 bv;
#pragma unroll
        for (int j = 0; j < 8; ++j) bv[j] = (short)bf16_rne(wp[j * 64]);
        *(bf16x8*)(wt2s + c * 128 + ((kc * 16) ^ ((c & 7) << 4))) = bv;
    }
    if (tid < 64) { b1s[tid] = b1g[tid]; b2s[tid] = b2g[tid]; }

    int    ix_d[2], ix_s[2];
    float4 pf_a0[2], pf_a1[2];
    uint4  pf_pb[2];

    auto IDX = [&](int tt) {
        int eb = tt * 128;
#pragma unroll
        for (int it = 0; it < 2; ++it) {
            int e = (it * 512 + tid) >> 3;
            ix_d[it] = dstsS[eb + e];
            ix_s[it] = srcsS[eb + e];
        }
    };
    auto DATA = [&]() {
#pragma unroll
        for (int it = 0; it < 2; ++it) {
            const float* pt = Pt + (size_t)64 * ix_d[it] + 8 * g7;
            pf_a0[it] = *(const float4*)pt;
            pf_a1[it] = *(const float4*)(pt + 4);
            pf_pb[it] = *(const uint4*)(Pbu + (size_t)64 * ix_s[it] + 8 * g7);
        }
    };

    int tile = blockIdx.x;
    if (tile < ntiles) { IDX(tile); DATA(); }
    if (tile + gridDim.x < ntiles) IDX(tile + gridDim.x);
    barrier_lgkm();

    for (; tile < ntiles; tile += gridDim.x) {
#pragma unroll
        for (int it = 0; it < 2; ++it) {
            int e = (it * 512 + tid) >> 3;
            float4 b0  = *(const float4*)(b1s + 8 * g7);
            float4 b1v = *(const float4*)(b1s + 8 * g7 + 4);
            float v0 = silu_f(pf_a0[it].x + bflo(pf_pb[it].x) + b0.x);
            float v1 = silu_f(pf_a0[it].y + bfhi(pf_pb[it].x) + b0.y);
            float v2 = silu_f(pf_a0[it].z + bflo(pf_pb[it].y) + b0.z);
            float v3 = silu_f(pf_a0[it].w + bfhi(pf_pb[it].y) + b0.w);
            float v4 = silu_f(pf_a1[it].x + bflo(pf_pb[it].z) + b1v.x);
            float v5 = silu_f(pf_a1[it].y + bfhi(pf_pb[it].z) + b1v.y);
            float v6 = silu_f(pf_a1[it].z + bflo(pf_pb[it].w) + b1v.z);
            float v7 = silu_f(pf_a1[it].w + bfhi(pf_pb[it].w) + b1v.w);
            uint4 o;
            o.x = ((unsigned)bf16_rne(v1) << 16) | bf16_rne(v0);
            o.y = ((unsigned)bf16_rne(v3) << 16) | bf16_rne(v2);
            o.z = ((unsigned)bf16_rne(v5) << 16) | bf16_rne(v4);
            o.w = ((unsigned)bf16_rne(v7) << 16) | bf16_rne(v6);
            *(uint4*)(m1s + e * 128 + ((g7 * 16) ^ ((e & 7) << 4))) = o;
        }
        barrier_lgkm();                           // B1: m1s ready
        int nxt = tile + gridDim.x;
        if (nxt < ntiles) {
            DATA();                               // idx regs completed 1 iter ago
            if (nxt + gridDim.x < ntiles) IDX(nxt + gridDim.x);
        }
        f32x4 acc2[2][2];
#pragma unroll
        for (int m = 0; m < 2; ++m)
#pragma unroll
            for (int n = 0; n < 2; ++n) {
                float b = b2s[32 * ni + 16 * n + l15];
                acc2[m][n] = (f32x4){b, b, b, b};
            }
        const int sw = (l15 & 7) << 4;
#pragma unroll
        for (int ks = 0; ks < 2; ++ks) {
            int kb = ks * 64 + l4 * 16;
            bf16x8 af[2], bfr[2];
#pragma unroll
            for (int m = 0; m < 2; ++m)
                af[m] = *(const bf16x8*)(m1s + (32 * mi + 16 * m + l15) * 128 + (kb ^ sw));
#pragma unroll
            for (int n = 0; n < 2; ++n)
                bfr[n] = *(const bf16x8*)(wt2s + (32 * ni + 16 * n + l15) * 128 + (kb ^ sw));
#pragma unroll
            for (int m = 0; m < 2; ++m)
#pragma unroll
                for (int n = 0; n < 2; ++n)
                    acc2[m][n] = mfma16(af[m], bfr[n], acc2[m][n]);
        }
        // m2 = silu -> direct bf16 global store (proven 60us path)
        unsigned short* mg = m2g + (size_t)(tile * 128) * 64;
#pragma unroll
        for (int m = 0; m < 2; ++m)
#pragma unroll
            for (int n = 0; n < 2; ++n)
#pragma unroll
                for (int r = 0; r < 4; ++r) {
                    int row = 32 * mi + 16 * m + l4 * 4 + r;
                    int col = 32 * ni + 16 * n + l15;
                    mg[row * 64 + col] = bf16_rne(silu_f(acc2[m][n][r]));
                }
        barrier_lgkm();                           // B2: m1s reads done before next write
    }
}

// ===========================================================================
// agg_kernel: agg[n] = sum of contiguous m2g rows (CSR). Thread = (node, 4 cols).
// ===========================================================================
__global__ __launch_bounds__(256) void agg_kernel(
    const unsigned short* __restrict__ m2g, const int* __restrict__ rowptr,
    float* __restrict__ agg)
{
    int idx = blockIdx.x * 256 + threadIdx.x;
    if (idx >= NN * 16) return;
    int n = idx >> 4, c = idx & 15;
    int e0 = rowptr[n], e1 = rowptr[n + 1];
    float a0 = 0.f, a1 = 0.f, a2 = 0.f, a3 = 0.f;
    int e = e0;
    for (; e + 4 <= e1; e += 4) {
        uint2 u0 = *(const uint2*)(m2g + (size_t)(e + 0) * 64 + 4 * c);
        uint2 u1 = *(const uint2*)(m2g + (size_t)(e + 1) * 64 + 4 * c);
        uint2 u2 = *(const uint2*)(m2g + (size_t)(e + 2) * 64 + 4 * c);
        uint2 u3 = *(const uint2*)(m2g + (size_t)(e + 3) * 64 + 4 * c);
        a0 += (bflo(u0.x) + bflo(u1.x)) + (bflo(u2.x) + bflo(u3.x));
        a1 += (bfhi(u0.x) + bfhi(u1.x)) + (bfhi(u2.x) + bfhi(u3.x));
        a2 += (bflo(u0.y) + bflo(u1.y)) + (bflo(u2.y) + bflo(u3.y));
        a3 += (bfhi(u0.y) + bfhi(u1.y)) + (bfhi(u2.y) + bfhi(u3.y));
    }
    for (; e < e1; ++e) {
        uint2 u = *(const uint2*)(m2g + (size_t)e * 64 + 4 * c);
        a0 += bflo(u.x); a1 += bfhi(u.x);
        a2 += bflo(u.y); a3 += bfhi(u.y);
    }
    *(float4*)(agg + (size_t)64 * n + 4 * c) = make_float4(a0, a1, a2, a3);
}

// ===========================================================================
// Node row-MLP: cats=[h|agg], u=silu(cats@W1+b1), h = u@W2 + b2 + h.
// ===========================================================================
__global__ __launch_bounds__(512, 1) void node_mlp_kernel(
    const float* __restrict__ A, const float* __restrict__ A2,
    const float* __restrict__ w1g, const float* __restrict__ b1g,
    const float* __restrict__ w2g, const float* __restrict__ b2g,
    float* __restrict__ outp, int nrows, int ntiles)
{
    extern __shared__ float lds[];
    float* ws1  = lds;
    float* ws2  = ws1 + 8192;
    float* wb1  = ws2 + 4096;
    float* wb2  = wb1 + 64;
    float* cats = wb2 + 64;
    float* m1s  = cats + 128 * 132;

    const int tid = threadIdx.x;
    const int tr  = tid & 31;
    const int tc  = tid >> 5;

    for (int i = tid; i < 2048; i += 512)
        *(float4*)&ws1[4 * i] = *(const float4*)&w1g[4 * i];
    for (int i = tid; i < 1024; i += 512)
        *(float4*)&ws2[4 * i] = *(const float4*)&w2g[4 * i];
    if (tid < 64) { wb1[tid] = b1g[tid]; wb2[tid] = b2g[tid]; }

    for (int tile = blockIdx.x; tile < ntiles; tile += gridDim.x) {
        const int base = tile * 128;
        __syncthreads();
#pragma unroll
        for (int rep = 0; rep < 8; ++rep) {
            int idx = rep * 512 + tid;
            int r = idx >> 5, q = idx & 31;
            int n = base + r;
            float4 v = make_float4(0.f, 0.f, 0.f, 0.f);
            if (n < nrows)
                v = (q < 16) ? *(const float4*)(A + 64 * n + 4 * q)
                             : *(const float4*)(A2 + 64 * n + 4 * (q - 16));
            *(float4*)&cats[r * 132 + 4 * q] = v;
        }
        __syncthreads();
        float acc[4][4];
#pragma unroll
        for (int jj = 0; jj < 4; ++jj)
#pragma unroll
            for (int ii = 0; ii < 4; ++ii) acc[jj][ii] = wb1[4 * tc + ii];
#pragma unroll 4
        for (int k16 = 0; k16 < 32; ++k16) {
            float4 bv0 = *(const float4*)&ws1[(4 * k16 + 0) * 64 + 4 * tc];
            float4 bv1 = *(const float4*)&ws1[(4 * k16 + 1) * 64 + 4 * tc];
            float4 bv2 = *(const float4*)&ws1[(4 * k16 + 2) * 64 + 4 * tc];
            float4 bv3 = *(const float4*)&ws1[(4 * k16 + 3) * 64 + 4 * tc];
#pragma unroll
            for (int jj = 0; jj < 4; ++jj) {
                float4 av = *(const float4*)&cats[(tr + 32 * jj) * 132 + 4 * k16];
                acc[jj][0] = fmaf(av.x, bv0.x, fmaf(av.y, bv1.x, fmaf(av.z, bv2.x, fmaf(av.w, bv3.x, acc[jj][0]))));
                acc[jj][1] = fmaf(av.x, bv0.y, fmaf(av.y, bv1.y, fmaf(av.z, bv2.y, fmaf(av.w, bv3.y, acc[jj][1]))));
                acc[jj][2] = fmaf(av.x, bv0.z, fmaf(av.y, bv1.z, fmaf(av.z, bv2.z, fmaf(av.w, bv3.z, acc[jj][2]))));
                acc[jj][3] = fmaf(av.x, bv0.w, fmaf(av.y, bv1.w, fmaf(av.z, bv2.w, fmaf(av.w, bv3.w, acc[jj][3]))));
            }
        }
#pragma unroll
        for (int jj = 0; jj < 4; ++jj) {
            float4 v;
            v.x = silu_f(acc[jj][0]); v.y = silu_f(acc[jj][1]);
            v.z = silu_f(acc[jj][2]); v.w = silu_f(acc[jj][3]);
            *(float4*)&m1s[(tr + 32 * jj) * 68 + 4 * tc] = v;
        }
        __syncthreads();
        float acc2[4][4];
#pragma unroll
        for (int jj = 0; jj < 4; ++jj)
#pragma unroll
            for (int ii = 0; ii < 4; ++ii) acc2[jj][ii] = wb2[4 * tc + ii];
#pragma unroll 4
        for (int k16 = 0; k16 < 16; ++k16) {
            float4 bv0 = *(const float4*)&ws2[(4 * k16 + 0) * 64 + 4 * tc];
            float4 bv1 = *(const float4*)&ws2[(4 * k16 + 1) * 64 + 4 * tc];
            float4 bv2 = *(const float4*)&ws2[(4 * k16 + 2) * 64 + 4 * tc];
            float4 bv3 = *(const float4*)&ws2[(4 * k16 + 3) * 64 + 4 * tc];
#pragma unroll
            for (int jj = 0; jj < 4; ++jj) {
                float4 av = *(const float4*)&m1s[(tr + 32 * jj) * 68 + 4 * k16];
                acc2[jj][0] = fmaf(av.x, bv0.x, fmaf(av.y, bv1.x, fmaf(av.z, bv2.x, fmaf(av.w, bv3.x, acc2[jj][0]))));
                acc2[jj][1] = fmaf(av.x, bv0.y, fmaf(av.y, bv1.y, fmaf(av.z, bv2.y, fmaf(av.w, bv3.y, acc2[jj][1]))));
                acc2[jj][2] = fmaf(av.x, bv0.z, fmaf(av.y, bv1.z, fmaf(av.z, bv2.z, fmaf(av.w, bv3.z, acc2[jj][2]))));
                acc2[jj][3] = fmaf(av.x, bv0.w, fmaf(av.y, bv1.w, fmaf(av.z, bv2.w, fmaf(av.w, bv3.w, acc2[jj][3]))));
            }
        }
#pragma unroll
        for (int jj = 0; jj < 4; ++jj) {
            int r = tr + 32 * jj;
            int n = base + r;
            if (n < nrows) {
                float4 hold = *(const float4*)&cats[r * 132 + 4 * tc];
                *(float4*)&outp[64 * n + 4 * tc] = make_float4(
                    acc2[jj][0] + hold.x, acc2[jj][1] + hold.y,
                    acc2[jj][2] + hold.z, acc2[jj][3] + hold.w);
            }
        }
    }
}

// ===========================================================================
// Readout row-MLP (K1=64, segmented scatter into gsum)
// ===========================================================================
__global__ __launch_bounds__(512, 1) void rowmlp_ro_kernel(
    const float* __restrict__ A,
    const float* __restrict__ w1g, const float* __restrict__ b1g,
    const float* __restrict__ w2g, const float* __restrict__ b2g,
    const int* __restrict__ seg, float* __restrict__ outp,
    int nrows, int ntiles)
{
    extern __shared__ float lds[];
    float* ws1  = lds;
    float* ws2  = ws1 + 4096;
    float* wb1  = ws2 + 4096;
    float* wb2  = wb1 + 64;
    float* cats = wb2 + 64;
    float* m1s  = cats + 128 * 68;
    int*   segs = (int*)(m1s + 128 * 68);

    const int tid = threadIdx.x;
    const int tr  = tid & 31;
    const int tc  = tid >> 5;

    for (int i = tid; i < 1024; i += 512) {
        *(float4*)&ws1[4 * i] = *(const float4*)&w1g[4 * i];
        *(float4*)&ws2[4 * i] = *(const float4*)&w2g[4 * i];
    }
    if (tid < 64) { wb1[tid] = b1g[tid]; wb2[tid] = b2g[tid]; }

    for (int tile = blockIdx.x; tile < ntiles; tile += gridDim.x) {
        const int base = tile * 128;
        __syncthreads();
        if (tid < 128) segs[tid] = (base + tid < nrows) ? seg[base + tid] : -1;
#pragma unroll
        for (int rep = 0; rep < 4; ++rep) {
            int idx = rep * 512 + tid;
            int r = idx >> 4, q = idx & 15;
            int n = base + r;
            float4 v = make_float4(0.f, 0.f, 0.f, 0.f);
            if (n < nrows) v = *(const float4*)(A + 64 * n + 4 * q);
            *(float4*)&cats[r * 68 + 4 * q] = v;
        }
        __syncthreads();
        float acc[4][4];
#pragma unroll
        for (int jj = 0; jj < 4; ++jj)
#pragma unroll
            for (int ii = 0; ii < 4; ++ii) acc[jj][ii] = wb1[4 * tc + ii];
#pragma unroll 4
        for (int k16 = 0; k16 < 16; ++k16) {
            float4 bv0 = *(const float4*)&ws1[(4 * k16 + 0) * 64 + 4 * tc];
            float4 bv1 = *(const float4*)&ws1[(4 * k16 + 1) * 64 + 4 * tc];
            float4 bv2 = *(const float4*)&ws1[(4 * k16 + 2) * 64 + 4 * tc];
            float4 bv3 = *(const float4*)&ws1[(4 * k16 + 3) * 64 + 4 * tc];
#pragma unroll
            for (int jj = 0; jj < 4; ++jj) {
                float4 av = *(const float4*)&cats[(tr + 32 * jj) * 68 + 4 * k16];
                acc[jj][0] = fmaf(av.x, bv0.x, fmaf(av.y, bv1.x, fmaf(av.z, bv2.x, fmaf(av.w, bv3.x, acc[jj][0]))));
                acc[jj][1] = fmaf(av.x, bv0.y, fmaf(av.y, bv1.y, fmaf(av.z, bv2.y, fmaf(av.w, bv3.y, acc[jj][1]))));
                acc[jj][2] = fmaf(av.x, bv0.z, fmaf(av.y, bv1.z, fmaf(av.z, bv2.z, fmaf(av.w, bv3.z, acc[jj][2]))));
                acc[jj][3] = fmaf(av.x, bv0.w, fmaf(av.y, bv1.w, fmaf(av.z, bv2.w, fmaf(av.w, bv3.w, acc[jj][3]))));
            }
        }
#pragma unroll
        for (int jj = 0; jj < 4; ++jj) {
            float4 v;
            v.x = silu_f(acc[jj][0]); v.y = silu_f(acc[jj][1]);
            v.z = silu_f(acc[jj][2]); v.w = silu_f(acc[jj][3]);
            *(float4*)&m1s[(tr + 32 * jj) * 68 + 4 * tc] = v;
        }
        __syncthreads();
        float acc2[4][4];
#pragma unroll
        for (int jj = 0; jj < 4; ++jj)
#pragma unroll
            for (int ii = 0; ii < 4; ++ii) acc2[jj][ii] = wb2[4 * tc + ii];
#pragma unroll 4
        for (int k16 = 0; k16 < 16; ++k16) {
            float4 bv0 = *(const float4*)&ws2[(4 * k16 + 0) * 64 + 4 * tc];
            float4 bv1 = *(const float4*)&ws2[(4 * k16 + 1) * 64 + 4 * tc];
            float4 bv2 = *(const float4*)&ws2[(4 * k16 + 2) * 64 + 4 * tc];
            float4 bv3 = *(const float4*)&ws2[(4 * k16 + 3) * 64 + 4 * tc];
#pragma unroll
            for (int jj = 0; jj < 4; ++jj) {
                float4 av = *(const float4*)&m1s[(tr + 32 * jj) * 68 + 4 * k16];
                acc2[jj][0] = fmaf(av.x, bv0.x, fmaf(av.y, bv1.x, fmaf(av.z, bv2.x, fmaf(av.w, bv3.x, acc2[jj][0]))));
                acc2[jj][1] = fmaf(av.x, bv0.y, fmaf(av.y, bv1.y, fmaf(av.z, bv2.y, fmaf(av.w, bv3.y, acc2[jj][1]))));
                acc2[jj][2] = fmaf(av.x, bv0.z, fmaf(av.y, bv1.z, fmaf(av.z, bv2.z, fmaf(av.w, bv3.z, acc2[jj][2]))));
                acc2[jj][3] = fmaf(av.x, bv0.w, fmaf(av.y, bv1.w, fmaf(av.z, bv2.w, fmaf(av.w, bv3.w, acc2[jj][3]))));
            }
        }
#pragma unroll
        for (int jj = 0; jj < 4; ++jj) {
            int r = tr + 32 * jj;
            int n = base + r;
            int gid = segs[r];
            float4 vv = (n < nrows) ? make_float4(acc2[jj][0], acc2[jj][1], acc2[jj][2], acc2[jj][3])
                                    : make_float4(0.f, 0.f, 0.f, 0.f);
            unsigned f = (tr == 0 || segs[(r > 0) ? r - 1 : 0] != gid) ? 1u : 0u;
#pragma unroll
            for (int s = 1; s < 32; s <<= 1) {
                float ux = __shfl_up(vv.x, s, 32);
                float uy = __shfl_up(vv.y, s, 32);
                float uz = __shfl_up(vv.z, s, 32);
                float uw = __shfl_up(vv.w, s, 32);
                unsigned uf = __shfl_up(f, s, 32);
                if (tr >= s) {
                    if (!f) { vv.x += ux; vv.y += uy; vv.z += uz; vv.w += uw; }
                    f |= uf;
                }
            }
            bool tail = (tr == 31) || (segs[r + 1] != gid);
            if (tail && gid >= 0) {
                float* bp = outp + 64 * gid + 4 * tc;
                atomicAdd(bp + 0, vv.x); atomicAdd(bp + 1, vv.y);
                atomicAdd(bp + 2, vv.z); atomicAdd(bp + 3, vv.w);
            }
        }
    }
}

__global__ __launch_bounds__(256) void proj_kernel(
    const float* __restrict__ x, const float* __restrict__ w,
    const float* __restrict__ b, float* __restrict__ h, int n)
{
    int i = blockIdx.x * 256 + threadIdx.x;
    if (i >= n * 64) return;
    int node = i >> 6, j = i & 63;
    const float* xr = x + node * 14;
    float acc = b[j];
#pragma unroll
    for (int k = 0; k < 14; ++k) acc = fmaf(xr[k], w[k * 64 + j], acc);
    h[i] = acc;
}

__global__ __launch_bounds__(256) void head_kernel(
    const float* __restrict__ gsum,
    const float* __restrict__ w3, const float* __restrict__ b3,
    const float* __restrict__ w4, const float* __restrict__ b4,
    float* __restrict__ out, int g_count)
{
    int wid  = (blockIdx.x * 256 + threadIdx.x) >> 6;
    int lane = threadIdx.x & 63;
    if (wid >= g_count) return;
    float v = gsum[wid * 64 + lane];
    float t = b3[lane];
#pragma unroll
    for (int k = 0; k < 64; ++k) {
        float a = __shfl(v, k, 64);
        t = fmaf(a, w3[k * 64 + lane], t);
    }
    t = silu_f(t);
    float r = t * w4[lane];
#pragma unroll
    for (int off = 32; off; off >>= 1) r += __shfl_down(r, off, 64);
    if (lane == 0) out[wid] = r + b4[0];
}

extern "C" void kernel_launch(void* const* d_in, const int* in_sizes, int n_in,
                              void* d_out, int out_size, void* d_ws, size_t ws_size,
                              hipStream_t stream)
{
    const float* x      = (const float*)d_in[0];
    const int*   ei     = (const int*)d_in[2];
    const int*   batch  = (const int*)d_in[3];
    const float* proj_w = (const float*)d_in[4];
    const float* proj_b = (const float*)d_in[5];
    const float* ew1 = (const float*)d_in[6];
    const float* eb1 = (const float*)d_in[7];
    const float* ew2 = (const float*)d_in[8];
    const float* eb2 = (const float*)d_in[9];
    const float* nw1 = (const float*)d_in[10];
    const float* nb1 = (const float*)d_in[11];
    const float* nw2 = (const float*)d_in[12];
    const float* nb2 = (const float*)d_in[13];
    const float* l1w = (const float*)d_in[14]; const float* l1b = (const float*)d_in[15];
    const float* l2w = (const float*)d_in[16]; const float* l2b = (const float*)d_in[17];
    const float* l3w = (const float*)d_in[18]; const float* l3b = (const float*)d_in[19];
    const float* l4w = (const float*)d_in[20]; const float* l4b = (const float*)d_in[21];

    float* out  = (float*)d_out;
    float* h    = out + GG;                      // per_atom_out doubles as h

    unsigned short* m2g = (unsigned short*)d_ws;             // [E,64] bf16 = 102.4MB
    float* gsum = (float*)(m2g + (size_t)EE * 64);           // [G,64]
    float* Pt   = gsum + (size_t)GG * 64;                    // [N,64] f32
    unsigned short* Pbu = (unsigned short*)(Pt + (size_t)NN * 64);  // [N,64] bf16
    int* deg    = (int*)(Pbu + (size_t)NN * 64);
    int* rowptr = deg + NN;                                  // N+1
    int* cursor = rowptr + NN + 1;
    int* srcsS  = cursor + NN;                               // [E]
    int* dstsS  = srcsS + EE;                                // [E]
    int* bsum   = dstsS + EE;                                // [98]
    float* agg  = Pt;   // alias: Pt dead after edge_kernel, rebuilt next layer

    const size_t edge_lds = 8192 + 16384 + 256 + 256;                 // 25088
    const size_t pk_lds   = (size_t)(8192 + 8704) * 4;                // 67584
    const size_t node_lds = (size_t)(8192 + 4096 + 128 + 128 * 132 + 128 * 68) * 4;
    const size_t ro_lds   = (size_t)(4096 + 4096 + 128 + 128 * 68 + 128 * 68) * 4 + 128 * 4;

    (void)hipFuncSetAttribute((const void*)edge_kernel,
                              hipFuncAttributeMaxDynamicSharedMemorySize, (int)edge_lds);
    (void)hipFuncSetAttribute((const void*)pk_kernel,
                              hipFuncAttributeMaxDynamicSharedMemorySize, (int)pk_lds);
    (void)hipFuncSetAttribute((const void*)node_mlp_kernel,
                              hipFuncAttributeMaxDynamicSharedMemorySize, (int)node_lds);
    (void)hipFuncSetAttribute((const void*)rowmlp_ro_kernel,
                              hipFuncAttributeMaxDynamicSharedMemorySize, (int)ro_lds);

    // --- CSR build (dst-sorted edge arrays) ---
    const int nb = (NN + 511) / 512;           // 98
    hipMemsetAsync(deg, 0, (size_t)NN * sizeof(int), stream);
    hipMemsetAsync(gsum, 0, (size_t)GG * 64 * sizeof(float), stream);
    hist_kernel<<<(EE + 255) / 256, 256, 0, stream>>>(ei, deg);
    scanA_kernel<<<nb, 512, 0, stream>>>(deg, rowptr, bsum);
    scanB_kernel<<<1, 128, 0, stream>>>(bsum, nb);
    scanC_kernel<<<nb, 512, 0, stream>>>(rowptr, cursor, bsum);
    scatter_kernel<<<(EE + 255) / 256, 256, 0, stream>>>(ei, cursor, srcsS, dstsS);

    proj_kernel<<<(NN * 64 + 255) / 256, 256, 0, stream>>>(x, proj_w, proj_b, h, NN);

    const int etiles = EE / 128;               // 6250 (exact)
    const int ntiles = (NN + 127) / 128;       // 391
    for (int l = 0; l < LL; ++l) {
        pk_kernel<<<ntiles, 512, pk_lds, stream>>>(h, ew1 + l * 8192, Pt, Pbu, ntiles);
        edge_kernel<<<1024, 512, edge_lds, stream>>>(
            Pt, Pbu, srcsS, dstsS, eb1 + l * 64, ew2 + l * 4096, eb2 + l * 64,
            m2g, etiles);
        agg_kernel<<<(NN * 16 + 255) / 256, 256, 0, stream>>>(m2g, rowptr, agg);
        node_mlp_kernel<<<196, 512, node_lds, stream>>>(
            h, agg, nw1 + l * 8192, nb1 + l * 64, nw2 + l * 4096, nb2 + l * 64,
            h, NN, ntiles);
    }
    rowmlp_ro_kernel<<<196, 512, ro_lds, stream>>>(
        h, l1w, l1b, l2w, l2b, batch, gsum, NN, ntiles);
    head_kernel<<<GG / 4, 256, 0, stream>>>(gsum, l3w, l3b, l4w, l4b, out, GG);
}

// Round 19
// 485.937 us; speedup vs baseline: 1.4803x; 1.0415x over previous
//
#include <hip/hip_runtime.h>

#define NN 50000
#define EE 800000
#define GG 512
#define LL 3

typedef short bf16x8 __attribute__((ext_vector_type(8)));
typedef float f32x4  __attribute__((ext_vector_type(4)));

__device__ __forceinline__ float silu_f(float x) {
    return x * __builtin_amdgcn_rcpf(1.0f + __expf(-x));
}
__device__ __forceinline__ unsigned short bf16_rne(float x) {
    unsigned u = __float_as_uint(x);
    u += 0x7fffu + ((u >> 16) & 1u);
    return (unsigned short)(u >> 16);
}
__device__ __forceinline__ float bflo(unsigned u) { return __uint_as_float(u << 16); }
__device__ __forceinline__ float bfhi(unsigned u) { return __uint_as_float(u & 0xffff0000u); }
__device__ __forceinline__ f32x4 mfma16(bf16x8 a, bf16x8 b, f32x4 c) {
    return __builtin_amdgcn_mfma_f32_16x16x32_bf16(a, b, c, 0, 0, 0);
}
// lgkm-only barrier: drains LDS ops, leaves global loads/stores in flight.
__device__ __forceinline__ void barrier_lgkm() {
    asm volatile("s_waitcnt lgkmcnt(0)" ::: "memory");
    __builtin_amdgcn_s_barrier();
}

// ===========================================================================
// CSR build: histogram -> hierarchical scan (3 small kernels) -> scatter
// ===========================================================================
__global__ __launch_bounds__(256) void hist_kernel(const int* __restrict__ ei,
                                                   int* __restrict__ deg) {
    int e = blockIdx.x * 256 + threadIdx.x;
    if (e < EE) atomicAdd(&deg[ei[EE + e]], 1);
}

__global__ __launch_bounds__(512) void scanA_kernel(const int* __restrict__ deg,
                                                    int* __restrict__ rowptr,
                                                    int* __restrict__ bsum) {
    __shared__ int wsum[8];
    const int tid = threadIdx.x, b = blockIdx.x;
    int i = b * 512 + tid;
    int v = (i < NN) ? deg[i] : 0;
    int lane = tid & 63, wid = tid >> 6;
    int x = v;
#pragma unroll
    for (int s = 1; s < 64; s <<= 1) {
        int u = __shfl_up(x, s, 64);
        if (lane >= s) x += u;
    }
    if (lane == 63) wsum[wid] = x;
    __syncthreads();
    int woff = 0;
    for (int w = 0; w < wid; ++w) woff += wsum[w];
    if (i < NN) rowptr[i] = woff + x - v;
    if (tid == 511) bsum[b] = woff + x;
}

__global__ __launch_bounds__(128) void scanB_kernel(int* __restrict__ bsum, int nb) {
    __shared__ int wsum[2];
    const int tid = threadIdx.x;
    int v = (tid < nb) ? bsum[tid] : 0;
    int lane = tid & 63, wid = tid >> 6;
    int x = v;
#pragma unroll
    for (int s = 1; s < 64; s <<= 1) {
        int u = __shfl_up(x, s, 64);
        if (lane >= s) x += u;
    }
    if (lane == 63) wsum[wid] = x;
    __syncthreads();
    int woff = (wid == 1) ? wsum[0] : 0;
    if (tid < nb) bsum[tid] = woff + x - v;
}

__global__ __launch_bounds__(512) void scanC_kernel(int* __restrict__ rowptr,
                                                    int* __restrict__ cursor,
                                                    const int* __restrict__ bsum) {
    const int tid = threadIdx.x, b = blockIdx.x;
    int i = b * 512 + tid;
    if (i < NN) {
        int r = rowptr[i] + bsum[b];
        rowptr[i] = r;
        cursor[i] = r;
    }
    if (i == 0) rowptr[NN] = EE;
}

__global__ __launch_bounds__(256) void scatter_kernel(const int* __restrict__ ei,
                                                      int* __restrict__ cursor,
                                                      int* __restrict__ srcsS,
                                                      int* __restrict__ dstsS) {
    int e = blockIdx.x * 256 + threadIdx.x;
    if (e < EE) {
        int d = ei[EE + e];
        int pos = atomicAdd(&cursor[d], 1);
        srcsS[pos] = ei[e];
        dstsS[pos] = d;
    }
}

// ===========================================================================
// pk_kernel (MFMA): out[128r][128c] = h_bf16[128r][64k] @ Wcat_bf16[64k][128c]
// Wcat[k][c] = W1[(c<64?k:64+k)][c&63]; cols 0-63 -> Pt (f32), 64-127 -> Pb.
// FIX vs round 18: wt staging covers ALL 8 k-chunks per column (was 4 ->
// uninitialized LDS -> NaN). Each thread stages 2 chunks.
// ===========================================================================
__global__ __launch_bounds__(512, 2) void pk_kernel(
    const float* __restrict__ h, const float* __restrict__ w1g,
    float* __restrict__ Pt, unsigned short* __restrict__ Pbu, int ntiles)
{
    extern __shared__ __align__(16) char smem[];
    char*  hb = smem;                    // [128r][128B] swz : 16384
    char*  wt = hb + 16384;              // [128c][128B] swz : 16384
    float* tp = (float*)(wt + 16384);    // [128][68] f32   : 34816
    // total 67584 B

    const int tid = threadIdx.x;
    const int l   = tid & 63;
    const int w   = tid >> 6;
    const int mi  = w >> 1;              // 0..3 : row block 32*mi
    const int ni  = w & 1;               // 0..1 : col half 64*ni
    const int l15 = l & 15;
    const int l4  = l >> 4;
    const int sw  = (l15 & 7) << 4;

    // ---- stage Wcat^T bf16 once (col-major rows, swizzled); 2 chunks/thread ----
    {
        int c = tid >> 2, kq0 = tid & 3;
#pragma unroll
        for (int hf = 0; hf < 2; ++hf) {
            int kq = kq0 + 4 * hf;       // 0..7 : 8-k chunk
            const float* wp = w1g + (size_t)((c >> 6) * 64 + kq * 8) * 64 + (c & 63);
            bf16x8 bv;
#pragma unroll
            for (int j = 0; j < 8; ++j) bv[j] = (short)bf16_rne(wp[j * 64]);
            *(bf16x8*)(wt + c * 128 + ((kq * 16) ^ ((c & 7) << 4))) = bv;
        }
    }

    for (int tile = blockIdx.x; tile < ntiles; tile += gridDim.x) {
        const int base = tile * 128;
        __syncthreads();                 // prev tp reads done; wt ready (1st iter)
        // ---- stage h tile -> bf16 swizzled LDS ----
        {
            int r = tid >> 2, q = tid & 3;   // q: 16-float chunk of the row
            int n = base + r;
            float v[16];
#pragma unroll
            for (int j = 0; j < 16; ++j) v[j] = 0.f;
            if (n < NN) {
                const float* hp = h + (size_t)64 * n + q * 16;
#pragma unroll
                for (int j = 0; j < 4; ++j) {
                    float4 t = *(const float4*)(hp + 4 * j);
                    v[4 * j] = t.x; v[4 * j + 1] = t.y;
                    v[4 * j + 2] = t.z; v[4 * j + 3] = t.w;
                }
            }
            bf16x8 b0, b1;
#pragma unroll
            for (int j = 0; j < 8; ++j) {
                b0[j] = (short)bf16_rne(v[j]);
                b1[j] = (short)bf16_rne(v[8 + j]);
            }
            int swr = (r & 7) << 4;
            *(bf16x8*)(hb + r * 128 + ((q * 32) ^ swr))      = b0;
            *(bf16x8*)(hb + r * 128 + ((q * 32 + 16) ^ swr)) = b1;
        }
        __syncthreads();
        // ---- MFMA: acc[m][n] covers rows 32mi+16m, cols 64ni+16n ----
        f32x4 acc[2][4];
#pragma unroll
        for (int m = 0; m < 2; ++m)
#pragma unroll
            for (int n = 0; n < 4; ++n) acc[m][n] = (f32x4){0.f, 0.f, 0.f, 0.f};
#pragma unroll
        for (int ks = 0; ks < 2; ++ks) {
            int kb = ks * 64 + l4 * 16;
            bf16x8 af[2], bf[4];
#pragma unroll
            for (int m = 0; m < 2; ++m)
                af[m] = *(const bf16x8*)(hb + (32 * mi + 16 * m + l15) * 128 + (kb ^ sw));
#pragma unroll
            for (int n = 0; n < 4; ++n)
                bf[n] = *(const bf16x8*)(wt + (64 * ni + 16 * n + l15) * 128 + (kb ^ sw));
#pragma unroll
            for (int m = 0; m < 2; ++m)
#pragma unroll
                for (int n = 0; n < 4; ++n)
                    acc[m][n] = mfma16(af[m], bf[n], acc[m][n]);
        }
        // ---- phase A: Pt (ni==0 waves) -> tp -> coalesced f32 store ----
        __syncthreads();                 // MFMA hb/wt reads done
        if (ni == 0) {
#pragma unroll
            for (int m = 0; m < 2; ++m)
#pragma unroll
                for (int n = 0; n < 4; ++n)
#pragma unroll
                    for (int r = 0; r < 4; ++r)
                        tp[(32 * mi + 16 * m + l4 * 4 + r) * 68 + 16 * n + l15] =
                            acc[m][n][r];
        }
        __syncthreads();
        {
            int r = tid >> 2, q = tid & 3;
            int n = base + r;
            if (n < NN) {
                float* op = Pt + (size_t)64 * n + q * 16;
#pragma unroll
                for (int j = 0; j < 4; ++j)
                    *(float4*)(op + 4 * j) = *(const float4*)&tp[r * 68 + q * 16 + 4 * j];
            }
        }
        __syncthreads();
        // ---- phase B: Pb (ni==1 waves) -> tp -> coalesced bf16 store ----
        if (ni == 1) {
#pragma unroll
            for (int m = 0; m < 2; ++m)
#pragma unroll
                for (int n = 0; n < 4; ++n)
#pragma unroll
                    for (int r = 0; r < 4; ++r)
                        tp[(32 * mi + 16 * m + l4 * 4 + r) * 68 + 16 * n + l15] =
                            acc[m][n][r];
        }
        __syncthreads();
        {
            int r = tid >> 2, q = tid & 3;
            int n = base + r;
            if (n < NN) {
                unsigned uu[8];
#pragma unroll
                for (int j = 0; j < 8; ++j) {
                    float lo = tp[r * 68 + q * 16 + 2 * j];
                    float hi = tp[r * 68 + q * 16 + 2 * j + 1];
                    uu[j] = ((unsigned)bf16_rne(hi) << 16) | bf16_rne(lo);
                }
                uint4* op = (uint4*)(Pbu + (size_t)64 * n + q * 16);
                op[0] = make_uint4(uu[0], uu[1], uu[2], uu[3]);
                op[1] = make_uint4(uu[4], uu[5], uu[6], uu[7]);
            }
        }
    }
}

// ===========================================================================
// Edge kernel — BYTE-EXACT round-14/17 version (61 us, FETCH 66 / WRITE 112).
// Do NOT perturb this kernel's store timing (rounds 13/16 regressions).
// ===========================================================================
__global__ __launch_bounds__(512, 6) void edge_kernel(
    const float* __restrict__ Pt, const unsigned short* __restrict__ Pbu,
    const int* __restrict__ srcsS, const int* __restrict__ dstsS,
    const float* __restrict__ b1g,
    const float* __restrict__ w2g, const float* __restrict__ b2g,
    unsigned short* __restrict__ m2g, int ntiles)
{
    extern __shared__ __align__(16) char smem[];
    char*  wt2s = smem;                       // [64c][128B] swz   8192
    char*  m1s  = wt2s + 8192;                // [128r][128B] swz 16384
    float* b1s  = (float*)(m1s + 16384);      // 64 f32
    float* b2s  = b1s + 64;                   // 64 f32

    const int tid = threadIdx.x;
    const int l   = tid & 63;
    const int w   = tid >> 6;
    const int mi  = w >> 1;
    const int ni  = w & 1;
    const int l15 = l & 15;
    const int l4  = l >> 4;
    const int g7  = tid & 7;

    {
        int c = tid >> 3, kc = tid & 7;
        const float* wp = w2g + (kc * 8) * 64 + c;
        bf16x8 bv;
#pragma unroll
        for (int j = 0; j < 8; ++j) bv[j] = (short)bf16_rne(wp[j * 64]);
        *(bf16x8*)(wt2s + c * 128 + ((kc * 16) ^ ((c & 7) << 4))) = bv;
    }
    if (tid < 64) { b1s[tid] = b1g[tid]; b2s[tid] = b2g[tid]; }

    int    ix_d[2], ix_s[2];
    float4 pf_a0[2], pf_a1[2];
    uint4  pf_pb[2];

    auto IDX = [&](int tt) {
        int eb = tt * 128;
#pragma unroll
        for (int it = 0; it < 2; ++it) {
            int e = (it * 512 + tid) >> 3;
            ix_d[it] = dstsS[eb + e];
            ix_s[it] = srcsS[eb + e];
        }
    };
    auto DATA = [&]() {
#pragma unroll
        for (int it = 0; it < 2; ++it) {
            const float* pt = Pt + (size_t)64 * ix_d[it] + 8 * g7;
            pf_a0[it] = *(const float4*)pt;
            pf_a1[it] = *(const float4*)(pt + 4);
            pf_pb[it] = *(const uint4*)(Pbu + (size_t)64 * ix_s[it] + 8 * g7);
        }
    };

    int tile = blockIdx.x;
    if (tile < ntiles) { IDX(tile); DATA(); }
    if (tile + gridDim.x < ntiles) IDX(tile + gridDim.x);
    barrier_lgkm();

    for (; tile < ntiles; tile += gridDim.x) {
#pragma unroll
        for (int it = 0; it < 2; ++it) {
            int e = (it * 512 + tid) >> 3;
            float4 b0  = *(const float4*)(b1s + 8 * g7);
            float4 b1v = *(const float4*)(b1s + 8 * g7 + 4);
            float v0 = silu_f(pf_a0[it].x + bflo(pf_pb[it].x) + b0.x);
            float v1 = silu_f(pf_a0[it].y + bfhi(pf_pb[it].x) + b0.y);
            float v2 = silu_f(pf_a0[it].z + bflo(pf_pb[it].y) + b0.z);
            float v3 = silu_f(pf_a0[it].w + bfhi(pf_pb[it].y) + b0.w);
            float v4 = silu_f(pf_a1[it].x + bflo(pf_pb[it].z) + b1v.x);
            float v5 = silu_f(pf_a1[it].y + bfhi(pf_pb[it].z) + b1v.y);
            float v6 = silu_f(pf_a1[it].z + bflo(pf_pb[it].w) + b1v.z);
            float v7 = silu_f(pf_a1[it].w + bfhi(pf_pb[it].w) + b1v.w);
            uint4 o;
            o.x = ((unsigned)bf16_rne(v1) << 16) | bf16_rne(v0);
            o.y = ((unsigned)bf16_rne(v3) << 16) | bf16_rne(v2);
            o.z = ((unsigned)bf16_rne(v5) << 16) | bf16_rne(v4);
            o.w = ((unsigned)bf16_rne(v7) << 16) | bf16_rne(v6);
            *(uint4*)(m1s + e * 128 + ((g7 * 16) ^ ((e & 7) << 4))) = o;
        }
        barrier_lgkm();                           // B1: m1s ready
        int nxt = tile + gridDim.x;
        if (nxt < ntiles) {
            DATA();                               // idx regs completed 1 iter ago
            if (nxt + gridDim.x < ntiles) IDX(nxt + gridDim.x);
        }
        f32x4 acc2[2][2];
#pragma unroll
        for (int m = 0; m < 2; ++m)
#pragma unroll
            for (int n = 0; n < 2; ++n) {
                float b = b2s[32 * ni + 16 * n + l15];
                acc2[m][n] = (f32x4){b, b, b, b};
            }
        const int sw = (l15 & 7) << 4;
#pragma unroll
        for (int ks = 0; ks < 2; ++ks) {
            int kb = ks * 64 + l4 * 16;
            bf16x8 af[2], bfr[2];
#pragma unroll
            for (int m = 0; m < 2; ++m)
                af[m] = *(const bf16x8*)(m1s + (32 * mi + 16 * m + l15) * 128 + (kb ^ sw));
#pragma unroll
            for (int n = 0; n < 2; ++n)
                bfr[n] = *(const bf16x8*)(wt2s + (32 * ni + 16 * n + l15) * 128 + (kb ^ sw));
#pragma unroll
            for (int m = 0; m < 2; ++m)
#pragma unroll
                for (int n = 0; n < 2; ++n)
                    acc2[m][n] = mfma16(af[m], bfr[n], acc2[m][n]);
        }
        // m2 = silu -> direct bf16 global store (proven 60us path)
        unsigned short* mg = m2g + (size_t)(tile * 128) * 64;
#pragma unroll
        for (int m = 0; m < 2; ++m)
#pragma unroll
            for (int n = 0; n < 2; ++n)
#pragma unroll
                for (int r = 0; r < 4; ++r) {
                    int row = 32 * mi + 16 * m + l4 * 4 + r;
                    int col = 32 * ni + 16 * n + l15;
                    mg[row * 64 + col] = bf16_rne(silu_f(acc2[m][n][r]));
                }
        barrier_lgkm();                           // B2: m1s reads done before next write
    }
}

// ===========================================================================
// agg_kernel: agg[n] = sum of contiguous m2g rows (CSR). Thread = (node, 4 cols).
// ===========================================================================
__global__ __launch_bounds__(256) void agg_kernel(
    const unsigned short* __restrict__ m2g, const int* __restrict__ rowptr,
    float* __restrict__ agg)
{
    int idx = blockIdx.x * 256 + threadIdx.x;
    if (idx >= NN * 16) return;
    int n = idx >> 4, c = idx & 15;
    int e0 = rowptr[n], e1 = rowptr[n + 1];
    float a0 = 0.f, a1 = 0.f, a2 = 0.f, a3 = 0.f;
    int e = e0;
    for (; e + 4 <= e1; e += 4) {
        uint2 u0 = *(const uint2*)(m2g + (size_t)(e + 0) * 64 + 4 * c);
        uint2 u1 = *(const uint2*)(m2g + (size_t)(e + 1) * 64 + 4 * c);
        uint2 u2 = *(const uint2*)(m2g + (size_t)(e + 2) * 64 + 4 * c);
        uint2 u3 = *(const uint2*)(m2g + (size_t)(e + 3) * 64 + 4 * c);
        a0 += (bflo(u0.x) + bflo(u1.x)) + (bflo(u2.x) + bflo(u3.x));
        a1 += (bfhi(u0.x) + bfhi(u1.x)) + (bfhi(u2.x) + bfhi(u3.x));
        a2 += (bflo(u0.y) + bflo(u1.y)) + (bflo(u2.y) + bflo(u3.y));
        a3 += (bfhi(u0.y) + bfhi(u1.y)) + (bfhi(u2.y) + bfhi(u3.y));
    }
    for (; e < e1; ++e) {
        uint2 u = *(const uint2*)(m2g + (size_t)e * 64 + 4 * c);
        a0 += bflo(u.x); a1 += bfhi(u.x);
        a2 += bflo(u.y); a3 += bfhi(u.y);
    }
    *(float4*)(agg + (size_t)64 * n + 4 * c) = make_float4(a0, a1, a2, a3);
}

// ===========================================================================
// Node row-MLP: cats=[h|agg], u=silu(cats@W1+b1), h = u@W2 + b2 + h.
// ===========================================================================
__global__ __launch_bounds__(512, 1) void node_mlp_kernel(
    const float* __restrict__ A, const float* __restrict__ A2,
    const float* __restrict__ w1g, const float* __restrict__ b1g,
    const float* __restrict__ w2g, const float* __restrict__ b2g,
    float* __restrict__ outp, int nrows, int ntiles)
{
    extern __shared__ float lds[];
    float* ws1  = lds;
    float* ws2  = ws1 + 8192;
    float* wb1  = ws2 + 4096;
    float* wb2  = wb1 + 64;
    float* cats = wb2 + 64;
    float* m1s  = cats + 128 * 132;

    const int tid = threadIdx.x;
    const int tr  = tid & 31;
    const int tc  = tid >> 5;

    for (int i = tid; i < 2048; i += 512)
        *(float4*)&ws1[4 * i] = *(const float4*)&w1g[4 * i];
    for (int i = tid; i < 1024; i += 512)
        *(float4*)&ws2[4 * i] = *(const float4*)&w2g[4 * i];
    if (tid < 64) { wb1[tid] = b1g[tid]; wb2[tid] = b2g[tid]; }

    for (int tile = blockIdx.x; tile < ntiles; tile += gridDim.x) {
        const int base = tile * 128;
        __syncthreads();
#pragma unroll
        for (int rep = 0; rep < 8; ++rep) {
            int idx = rep * 512 + tid;
            int r = idx >> 5, q = idx & 31;
            int n = base + r;
            float4 v = make_float4(0.f, 0.f, 0.f, 0.f);
            if (n < nrows)
                v = (q < 16) ? *(const float4*)(A + 64 * n + 4 * q)
                             : *(const float4*)(A2 + 64 * n + 4 * (q - 16));
            *(float4*)&cats[r * 132 + 4 * q] = v;
        }
        __syncthreads();
        float acc[4][4];
#pragma unroll
        for (int jj = 0; jj < 4; ++jj)
#pragma unroll
            for (int ii = 0; ii < 4; ++ii) acc[jj][ii] = wb1[4 * tc + ii];
#pragma unroll 4
        for (int k16 = 0; k16 < 32; ++k16) {
            float4 bv0 = *(const float4*)&ws1[(4 * k16 + 0) * 64 + 4 * tc];
            float4 bv1 = *(const float4*)&ws1[(4 * k16 + 1) * 64 + 4 * tc];
            float4 bv2 = *(const float4*)&ws1[(4 * k16 + 2) * 64 + 4 * tc];
            float4 bv3 = *(const float4*)&ws1[(4 * k16 + 3) * 64 + 4 * tc];
#pragma unroll
            for (int jj = 0; jj < 4; ++jj) {
                float4 av = *(const float4*)&cats[(tr + 32 * jj) * 132 + 4 * k16];
                acc[jj][0] = fmaf(av.x, bv0.x, fmaf(av.y, bv1.x, fmaf(av.z, bv2.x, fmaf(av.w, bv3.x, acc[jj][0]))));
                acc[jj][1] = fmaf(av.x, bv0.y, fmaf(av.y, bv1.y, fmaf(av.z, bv2.y, fmaf(av.w, bv3.y, acc[jj][1]))));
                acc[jj][2] = fmaf(av.x, bv0.z, fmaf(av.y, bv1.z, fmaf(av.z, bv2.z, fmaf(av.w, bv3.z, acc[jj][2]))));
                acc[jj][3] = fmaf(av.x, bv0.w, fmaf(av.y, bv1.w, fmaf(av.z, bv2.w, fmaf(av.w, bv3.w, acc[jj][3]))));
            }
        }
#pragma unroll
        for (int jj = 0; jj < 4; ++jj) {
            float4 v;
            v.x = silu_f(acc[jj][0]); v.y = silu_f(acc[jj][1]);
            v.z = silu_f(acc[jj][2]); v.w = silu_f(acc[jj][3]);
            *(float4*)&m1s[(tr + 32 * jj) * 68 + 4 * tc] = v;
        }
        __syncthreads();
        float acc2[4][4];
#pragma unroll
        for (int jj = 0; jj < 4; ++jj)
#pragma unroll
            for (int ii = 0; ii < 4; ++ii) acc2[jj][ii] = wb2[4 * tc + ii];
#pragma unroll 4
        for (int k16 = 0; k16 < 16; ++k16) {
            float4 bv0 = *(const float4*)&ws2[(4 * k16 + 0) * 64 + 4 * tc];
            float4 bv1 = *(const float4*)&ws2[(4 * k16 + 1) * 64 + 4 * tc];
            float4 bv2 = *(const float4*)&ws2[(4 * k16 + 2) * 64 + 4 * tc];
            float4 bv3 = *(const float4*)&ws2[(4 * k16 + 3) * 64 + 4 * tc];
#pragma unroll
            for (int jj = 0; jj < 4; ++jj) {
                float4 av = *(const float4*)&m1s[(tr + 32 * jj) * 68 + 4 * k16];
                acc2[jj][0] = fmaf(av.x, bv0.x, fmaf(av.y, bv1.x, fmaf(av.z, bv2.x, fmaf(av.w, bv3.x, acc2[jj][0]))));
                acc2[jj][1] = fmaf(av.x, bv0.y, fmaf(av.y, bv1.y, fmaf(av.z, bv2.y, fmaf(av.w, bv3.y, acc2[jj][1]))));
                acc2[jj][2] = fmaf(av.x, bv0.z, fmaf(av.y, bv1.z, fmaf(av.z, bv2.z, fmaf(av.w, bv3.z, acc2[jj][2]))));
                acc2[jj][3] = fmaf(av.x, bv0.w, fmaf(av.y, bv1.w, fmaf(av.z, bv2.w, fmaf(av.w, bv3.w, acc2[jj][3]))));
            }
        }
#pragma unroll
        for (int jj = 0; jj < 4; ++jj) {
            int r = tr + 32 * jj;
            int n = base + r;
            if (n < nrows) {
                float4 hold = *(const float4*)&cats[r * 132 + 4 * tc];
                *(float4*)&outp[64 * n + 4 * tc] = make_float4(
                    acc2[jj][0] + hold.x, acc2[jj][1] + hold.y,
                    acc2[jj][2] + hold.z, acc2[jj][3] + hold.w);
            }
        }
    }
}

// ===========================================================================
// Readout row-MLP (K1=64, segmented scatter into gsum)
// ===========================================================================
__global__ __launch_bounds__(512, 1) void rowmlp_ro_kernel(
    const float* __restrict__ A,
    const float* __restrict__ w1g, const float* __restrict__ b1g,
    const float* __restrict__ w2g, const float* __restrict__ b2g,
    const int* __restrict__ seg, float* __restrict__ outp,
    int nrows, int ntiles)
{
    extern __shared__ float lds[];
    float* ws1  = lds;
    float* ws2  = ws1 + 4096;
    float* wb1  = ws2 + 4096;
    float* wb2  = wb1 + 64;
    float* cats = wb2 + 64;
    float* m1s  = cats + 128 * 68;
    int*   segs = (int*)(m1s + 128 * 68);

    const int tid = threadIdx.x;
    const int tr  = tid & 31;
    const int tc  = tid >> 5;

    for (int i = tid; i < 1024; i += 512) {
        *(float4*)&ws1[4 * i] = *(const float4*)&w1g[4 * i];
        *(float4*)&ws2[4 * i] = *(const float4*)&w2g[4 * i];
    }
    if (tid < 64) { wb1[tid] = b1g[tid]; wb2[tid] = b2g[tid]; }

    for (int tile = blockIdx.x; tile < ntiles; tile += gridDim.x) {
        const int base = tile * 128;
        __syncthreads();
        if (tid < 128) segs[tid] = (base + tid < nrows) ? seg[base + tid] : -1;
#pragma unroll
        for (int rep = 0; rep < 4; ++rep) {
            int idx = rep * 512 + tid;
            int r = idx >> 4, q = idx & 15;
            int n = base + r;
            float4 v = make_float4(0.f, 0.f, 0.f, 0.f);
            if (n < nrows) v = *(const float4*)(A + 64 * n + 4 * q);
            *(float4*)&cats[r * 68 + 4 * q] = v;
        }
        __syncthreads();
        float acc[4][4];
#pragma unroll
        for (int jj = 0; jj < 4; ++jj)
#pragma unroll
            for (int ii = 0; ii < 4; ++ii) acc[jj][ii] = wb1[4 * tc + ii];
#pragma unroll 4
        for (int k16 = 0; k16 < 16; ++k16) {
            float4 bv0 = *(const float4*)&ws1[(4 * k16 + 0) * 64 + 4 * tc];
            float4 bv1 = *(const float4*)&ws1[(4 * k16 + 1) * 64 + 4 * tc];
            float4 bv2 = *(const float4*)&ws1[(4 * k16 + 2) * 64 + 4 * tc];
            float4 bv3 = *(const float4*)&ws1[(4 * k16 + 3) * 64 + 4 * tc];
#pragma unroll
            for (int jj = 0; jj < 4; ++jj) {
                float4 av = *(const float4*)&cats[(tr + 32 * jj) * 68 + 4 * k16];
                acc[jj][0] = fmaf(av.x, bv0.x, fmaf(av.y, bv1.x, fmaf(av.z, bv2.x, fmaf(av.w, bv3.x, acc[jj][0]))));
                acc[jj][1] = fmaf(av.x, bv0.y, fmaf(av.y, bv1.y, fmaf(av.z, bv2.y, fmaf(av.w, bv3.y, acc[jj][1]))));
                acc[jj][2] = fmaf(av.x, bv0.z, fmaf(av.y, bv1.z, fmaf(av.z, bv2.z, fmaf(av.w, bv3.z, acc[jj][2]))));
                acc[jj][3] = fmaf(av.x, bv0.w, fmaf(av.y, bv1.w, fmaf(av.z, bv2.w, fmaf(av.w, bv3.w, acc[jj][3]))));
            }
        }
#pragma unroll
        for (int jj = 0; jj < 4; ++jj) {
            float4 v;
            v.x = silu_f(acc[jj][0]); v.y = silu_f(acc[jj][1]);
            v.z = silu_f(acc[jj][2]); v.w = silu_f(acc[jj][3]);
            *(float4*)&m1s[(tr + 32 * jj) * 68 + 4 * tc] = v;
        }
        __syncthreads();
        float acc2[4][4];
#pragma unroll
        for (int jj = 0; jj < 4; ++jj)
#pragma unroll
            for (int ii = 0; ii < 4; ++ii) acc2[jj][ii] = wb2[4 * tc + ii];
#pragma unroll 4
        for (int k16 = 0; k16 < 16; ++k16) {
            float4 bv0 = *(const float4*)&ws2[(4 * k16 + 0) * 64 + 4 * tc];
            float4 bv1 = *(const float4*)&ws2[(4 * k16 + 1) * 64 + 4 * tc];
            float4 bv2 = *(const float4*)&ws2[(4 * k16 + 2) * 64 + 4 * tc];
            float4 bv3 = *(const float4*)&ws2[(4 * k16 + 3) * 64 + 4 * tc];
#pragma unroll
            for (int jj = 0; jj < 4; ++jj) {
                float4 av = *(const float4*)&m1s[(tr + 32 * jj) * 68 + 4 * k16];
                acc2[jj][0] = fmaf(av.x, bv0.x, fmaf(av.y, bv1.x, fmaf(av.z, bv2.x, fmaf(av.w, bv3.x, acc2[jj][0]))));
                acc2[jj][1] = fmaf(av.x, bv0.y, fmaf(av.y, bv1.y, fmaf(av.z, bv2.y, fmaf(av.w, bv3.y, acc2[jj][1]))));
                acc2[jj][2] = fmaf(av.x, bv0.z, fmaf(av.y, bv1.z, fmaf(av.z, bv2.z, fmaf(av.w, bv3.z, acc2[jj][2]))));
                acc2[jj][3] = fmaf(av.x, bv0.w, fmaf(av.y, bv1.w, fmaf(av.z, bv2.w, fmaf(av.w, bv3.w, acc2[jj][3]))));
            }
        }
#pragma unroll
        for (int jj = 0; jj < 4; ++jj) {
            int r = tr + 32 * jj;
            int n = base + r;
            int gid = segs[r];
            float4 vv = (n < nrows) ? make_float4(acc2[jj][0], acc2[jj][1], acc2[jj][2], acc2[jj][3])
                                    : make_float4(0.f, 0.f, 0.f, 0.f);
            unsigned f = (tr == 0 || segs[(r > 0) ? r - 1 : 0] != gid) ? 1u : 0u;
#pragma unroll
            for (int s = 1; s < 32; s <<= 1) {
                float ux = __shfl_up(vv.x, s, 32);
                float uy = __shfl_up(vv.y, s, 32);
                float uz = __shfl_up(vv.z, s, 32);
                float uw = __shfl_up(vv.w, s, 32);
                unsigned uf = __shfl_up(f, s, 32);
                if (tr >= s) {
                    if (!f) { vv.x += ux; vv.y += uy; vv.z += uz; vv.w += uw; }
                    f |= uf;
                }
            }
            bool tail = (tr == 31) || (segs[r + 1] != gid);
            if (tail && gid >= 0) {
                float* bp = outp + 64 * gid + 4 * tc;
                atomicAdd(bp + 0, vv.x); atomicAdd(bp + 1, vv.y);
                atomicAdd(bp + 2, vv.z); atomicAdd(bp + 3, vv.w);
            }
        }
    }
}

__global__ __launch_bounds__(256) void proj_kernel(
    const float* __restrict__ x, const float* __restrict__ w,
    const float* __restrict__ b, float* __restrict__ h, int n)
{
    int i = blockIdx.x * 256 + threadIdx.x;
    if (i >= n * 64) return;
    int node = i >> 6, j = i & 63;
    const float* xr = x + node * 14;
    float acc = b[j];
#pragma unroll
    for (int k = 0; k < 14; ++k) acc = fmaf(xr[k], w[k * 64 + j], acc);
    h[i] = acc;
}

__global__ __launch_bounds__(256) void head_kernel(
    const float* __restrict__ gsum,
    const float* __restrict__ w3, const float* __restrict__ b3,
    const float* __restrict__ w4, const float* __restrict__ b4,
    float* __restrict__ out, int g_count)
{
    int wid  = (blockIdx.x * 256 + threadIdx.x) >> 6;
    int lane = threadIdx.x & 63;
    if (wid >= g_count) return;
    float v = gsum[wid * 64 + lane];
    float t = b3[lane];
#pragma unroll
    for (int k = 0; k < 64; ++k) {
        float a = __shfl(v, k, 64);
        t = fmaf(a, w3[k * 64 + lane], t);
    }
    t = silu_f(t);
    float r = t * w4[lane];
#pragma unroll
    for (int off = 32; off; off >>= 1) r += __shfl_down(r, off, 64);
    if (lane == 0) out[wid] = r + b4[0];
}

extern "C" void kernel_launch(void* const* d_in, const int* in_sizes, int n_in,
                              void* d_out, int out_size, void* d_ws, size_t ws_size,
                              hipStream_t stream)
{
    const float* x      = (const float*)d_in[0];
    const int*   ei     = (const int*)d_in[2];
    const int*   batch  = (const int*)d_in[3];
    const float* proj_w = (const float*)d_in[4];
    const float* proj_b = (const float*)d_in[5];
    const float* ew1 = (const float*)d_in[6];
    const float* eb1 = (const float*)d_in[7];
    const float* ew2 = (const float*)d_in[8];
    const float* eb2 = (const float*)d_in[9];
    const float* nw1 = (const float*)d_in[10];
    const float* nb1 = (const float*)d_in[11];
    const float* nw2 = (const float*)d_in[12];
    const float* nb2 = (const float*)d_in[13];
    const float* l1w = (const float*)d_in[14]; const float* l1b = (const float*)d_in[15];
    const float* l2w = (const float*)d_in[16]; const float* l2b = (const float*)d_in[17];
    const float* l3w = (const float*)d_in[18]; const float* l3b = (const float*)d_in[19];
    const float* l4w = (const float*)d_in[20]; const float* l4b = (const float*)d_in[21];

    float* out  = (float*)d_out;
    float* h    = out + GG;                      // per_atom_out doubles as h

    unsigned short* m2g = (unsigned short*)d_ws;             // [E,64] bf16 = 102.4MB
    float* gsum = (float*)(m2g + (size_t)EE * 64);           // [G,64]
    float* Pt   = gsum + (size_t)GG * 64;                    // [N,64] f32
    unsigned short* Pbu = (unsigned short*)(Pt + (size_t)NN * 64);  // [N,64] bf16
    int* deg    = (int*)(Pbu + (size_t)NN * 64);
    int* rowptr = deg + NN;                                  // N+1
    int* cursor = rowptr + NN + 1;
    int* srcsS  = cursor + NN;                               // [E]
    int* dstsS  = srcsS + EE;                                // [E]
    int* bsum   = dstsS + EE;                                // [98]
    float* agg  = Pt;   // alias: Pt dead after edge_kernel, rebuilt next layer

    const size_t edge_lds = 8192 + 16384 + 256 + 256;                 // 25088
    const size_t pk_lds   = 16384 + 16384 + 34816;                    // 67584
    const size_t node_lds = (size_t)(8192 + 4096 + 128 + 128 * 132 + 128 * 68) * 4;
    const size_t ro_lds   = (size_t)(4096 + 4096 + 128 + 128 * 68 + 128 * 68) * 4 + 128 * 4;

    (void)hipFuncSetAttribute((const void*)edge_kernel,
                              hipFuncAttributeMaxDynamicSharedMemorySize, (int)edge_lds);
    (void)hipFuncSetAttribute((const void*)pk_kernel,
                              hipFuncAttributeMaxDynamicSharedMemorySize, (int)pk_lds);
    (void)hipFuncSetAttribute((const void*)node_mlp_kernel,
                              hipFuncAttributeMaxDynamicSharedMemorySize, (int)node_lds);
    (void)hipFuncSetAttribute((const void*)rowmlp_ro_kernel,
                              hipFuncAttributeMaxDynamicSharedMemorySize, (int)ro_lds);

    // --- CSR build (dst-sorted edge arrays) ---
    const int nb = (NN + 511) / 512;           // 98
    hipMemsetAsync(deg, 0, (size_t)NN * sizeof(int), stream);
    hipMemsetAsync(gsum, 0, (size_t)GG * 64 * sizeof(float), stream);
    hist_kernel<<<(EE + 255) / 256, 256, 0, stream>>>(ei, deg);
    scanA_kernel<<<nb, 512, 0, stream>>>(deg, rowptr, bsum);
    scanB_kernel<<<1, 128, 0, stream>>>(bsum, nb);
    scanC_kernel<<<nb, 512, 0, stream>>>(rowptr, cursor, bsum);
    scatter_kernel<<<(EE + 255) / 256, 256, 0, stream>>>(ei, cursor, srcsS, dstsS);

    proj_kernel<<<(NN * 64 + 255) / 256, 256, 0, stream>>>(x, proj_w, proj_b, h, NN);

    const int etiles = EE / 128;               // 6250 (exact)
    const int ntiles = (NN + 127) / 128;       // 391
    for (int l = 0; l < LL; ++l) {
        pk_kernel<<<ntiles, 512, pk_lds, stream>>>(h, ew1 + l * 8192, Pt, Pbu, ntiles);
        edge_kernel<<<1024, 512, edge_lds, stream>>>(
            Pt, Pbu, srcsS, dstsS, eb1 + l * 64, ew2 + l * 4096, eb2 + l * 64,
            m2g, etiles);
        agg_kernel<<<(NN * 16 + 255) / 256, 256, 0, stream>>>(m2g, rowptr, agg);
        node_mlp_kernel<<<196, 512, node_lds, stream>>>(
            h, agg, nw1 + l * 8192, nb1 + l * 64, nw2 + l * 4096, nb2 + l * 64,
            h, NN, ntiles);
    }
    rowmlp_ro_kernel<<<196, 512, ro_lds, stream>>>(
        h, l1w, l1b, l2w, l2b, batch, gsum, NN, ntiles);
    head_kernel<<<GG / 4, 256, 0, stream>>>(gsum, l3w, l3b, l4w, l4b, out, GG);
}

// Round 20
// 478.292 us; speedup vs baseline: 1.5039x; 1.0160x over previous
//
#include <hip/hip_runtime.h>

#define NN 50000
#define EE 800000
#define GG 512
#define LL 3

typedef short bf16x8 __attribute__((ext_vector_type(8)));
typedef float f32x4  __attribute__((ext_vector_type(4)));

__device__ __forceinline__ float silu_f(float x) {
    return x * __builtin_amdgcn_rcpf(1.0f + __expf(-x));
}
__device__ __forceinline__ unsigned short bf16_rne(float x) {
    unsigned u = __float_as_uint(x);
    u += 0x7fffu + ((u >> 16) & 1u);
    return (unsigned short)(u >> 16);
}
__device__ __forceinline__ float bflo(unsigned u) { return __uint_as_float(u << 16); }
__device__ __forceinline__ float bfhi(unsigned u) { return __uint_as_float(u & 0xffff0000u); }
__device__ __forceinline__ f32x4 mfma16(bf16x8 a, bf16x8 b, f32x4 c) {
    return __builtin_amdgcn_mfma_f32_16x16x32_bf16(a, b, c, 0, 0, 0);
}
// lgkm-only barrier: drains LDS ops, leaves global loads/stores in flight.
__device__ __forceinline__ void barrier_lgkm() {
    asm volatile("s_waitcnt lgkmcnt(0)" ::: "memory");
    __builtin_amdgcn_s_barrier();
}

// ===========================================================================
// CSR build: histogram -> hierarchical scan -> scatter (packed int2 epair)
// ===========================================================================
__global__ __launch_bounds__(256) void hist_kernel(const int* __restrict__ ei,
                                                   int* __restrict__ deg) {
    int e = blockIdx.x * 256 + threadIdx.x;
    if (e < EE) atomicAdd(&deg[ei[EE + e]], 1);
}

__global__ __launch_bounds__(512) void scanA_kernel(const int* __restrict__ deg,
                                                    int* __restrict__ rowptr,
                                                    int* __restrict__ bsum) {
    __shared__ int wsum[8];
    const int tid = threadIdx.x, b = blockIdx.x;
    int i = b * 512 + tid;
    int v = (i < NN) ? deg[i] : 0;
    int lane = tid & 63, wid = tid >> 6;
    int x = v;
#pragma unroll
    for (int s = 1; s < 64; s <<= 1) {
        int u = __shfl_up(x, s, 64);
        if (lane >= s) x += u;
    }
    if (lane == 63) wsum[wid] = x;
    __syncthreads();
    int woff = 0;
    for (int w = 0; w < wid; ++w) woff += wsum[w];
    if (i < NN) rowptr[i] = woff + x - v;
    if (tid == 511) bsum[b] = woff + x;
}

__global__ __launch_bounds__(128) void scanB_kernel(int* __restrict__ bsum, int nb) {
    __shared__ int wsum[2];
    const int tid = threadIdx.x;
    int v = (tid < nb) ? bsum[tid] : 0;
    int lane = tid & 63, wid = tid >> 6;
    int x = v;
#pragma unroll
    for (int s = 1; s < 64; s <<= 1) {
        int u = __shfl_up(x, s, 64);
        if (lane >= s) x += u;
    }
    if (lane == 63) wsum[wid] = x;
    __syncthreads();
    int woff = (wid == 1) ? wsum[0] : 0;
    if (tid < nb) bsum[tid] = woff + x - v;
}

__global__ __launch_bounds__(512) void scanC_kernel(int* __restrict__ rowptr,
                                                    int* __restrict__ cursor,
                                                    const int* __restrict__ bsum) {
    const int tid = threadIdx.x, b = blockIdx.x;
    int i = b * 512 + tid;
    if (i < NN) {
        int r = rowptr[i] + bsum[b];
        rowptr[i] = r;
        cursor[i] = r;
    }
    if (i == 0) rowptr[NN] = EE;
}

// Packed scatter: one 8B store per edge (src,dst) -> halves RMW line traffic
__global__ __launch_bounds__(256) void scatter_kernel(const int* __restrict__ ei,
                                                      int* __restrict__ cursor,
                                                      int2* __restrict__ epair) {
    int e = blockIdx.x * 256 + threadIdx.x;
    if (e < EE) {
        int d = ei[EE + e];
        int pos = atomicAdd(&cursor[d], 1);
        epair[pos] = make_int2(ei[e], d);   // (src, dst)
    }
}

// ===========================================================================
// pk_kernel (MFMA) — round-19 proven (cols 0-63 -> Pt f32, 64-127 -> Pb bf16)
// ===========================================================================
__global__ __launch_bounds__(512, 2) void pk_kernel(
    const float* __restrict__ h, const float* __restrict__ w1g,
    float* __restrict__ Pt, unsigned short* __restrict__ Pbu, int ntiles)
{
    extern __shared__ __align__(16) char smem[];
    char*  hb = smem;                    // [128r][128B] swz : 16384
    char*  wt = hb + 16384;              // [128c][128B] swz : 16384
    float* tp = (float*)(wt + 16384);    // [128][68] f32   : 34816

    const int tid = threadIdx.x;
    const int l   = tid & 63;
    const int w   = tid >> 6;
    const int mi  = w >> 1;
    const int ni  = w & 1;
    const int l15 = l & 15;
    const int l4  = l >> 4;
    const int sw  = (l15 & 7) << 4;

    {
        int c = tid >> 2, kq0 = tid & 3;
#pragma unroll
        for (int hf = 0; hf < 2; ++hf) {
            int kq = kq0 + 4 * hf;
            const float* wp = w1g + (size_t)((c >> 6) * 64 + kq * 8) * 64 + (c & 63);
            bf16x8 bv;
#pragma unroll
            for (int j = 0; j < 8; ++j) bv[j] = (short)bf16_rne(wp[j * 64]);
            *(bf16x8*)(wt + c * 128 + ((kq * 16) ^ ((c & 7) << 4))) = bv;
        }
    }

    for (int tile = blockIdx.x; tile < ntiles; tile += gridDim.x) {
        const int base = tile * 128;
        __syncthreads();
        {
            int r = tid >> 2, q = tid & 3;
            int n = base + r;
            float v[16];
#pragma unroll
            for (int j = 0; j < 16; ++j) v[j] = 0.f;
            if (n < NN) {
                const float* hp = h + (size_t)64 * n + q * 16;
#pragma unroll
                for (int j = 0; j < 4; ++j) {
                    float4 t = *(const float4*)(hp + 4 * j);
                    v[4 * j] = t.x; v[4 * j + 1] = t.y;
                    v[4 * j + 2] = t.z; v[4 * j + 3] = t.w;
                }
            }
            bf16x8 b0, b1;
#pragma unroll
            for (int j = 0; j < 8; ++j) {
                b0[j] = (short)bf16_rne(v[j]);
                b1[j] = (short)bf16_rne(v[8 + j]);
            }
            int swr = (r & 7) << 4;
            *(bf16x8*)(hb + r * 128 + ((q * 32) ^ swr))      = b0;
            *(bf16x8*)(hb + r * 128 + ((q * 32 + 16) ^ swr)) = b1;
        }
        __syncthreads();
        f32x4 acc[2][4];
#pragma unroll
        for (int m = 0; m < 2; ++m)
#pragma unroll
            for (int n = 0; n < 4; ++n) acc[m][n] = (f32x4){0.f, 0.f, 0.f, 0.f};
#pragma unroll
        for (int ks = 0; ks < 2; ++ks) {
            int kb = ks * 64 + l4 * 16;
            bf16x8 af[2], bf[4];
#pragma unroll
            for (int m = 0; m < 2; ++m)
                af[m] = *(const bf16x8*)(hb + (32 * mi + 16 * m + l15) * 128 + (kb ^ sw));
#pragma unroll
            for (int n = 0; n < 4; ++n)
                bf[n] = *(const bf16x8*)(wt + (64 * ni + 16 * n + l15) * 128 + (kb ^ sw));
#pragma unroll
            for (int m = 0; m < 2; ++m)
#pragma unroll
                for (int n = 0; n < 4; ++n)
                    acc[m][n] = mfma16(af[m], bf[n], acc[m][n]);
        }
        __syncthreads();
        if (ni == 0) {
#pragma unroll
            for (int m = 0; m < 2; ++m)
#pragma unroll
                for (int n = 0; n < 4; ++n)
#pragma unroll
                    for (int r = 0; r < 4; ++r)
                        tp[(32 * mi + 16 * m + l4 * 4 + r) * 68 + 16 * n + l15] =
                            acc[m][n][r];
        }
        __syncthreads();
        {
            int r = tid >> 2, q = tid & 3;
            int n = base + r;
            if (n < NN) {
                float* op = Pt + (size_t)64 * n + q * 16;
#pragma unroll
                for (int j = 0; j < 4; ++j)
                    *(float4*)(op + 4 * j) = *(const float4*)&tp[r * 68 + q * 16 + 4 * j];
            }
        }
        __syncthreads();
        if (ni == 1) {
#pragma unroll
            for (int m = 0; m < 2; ++m)
#pragma unroll
                for (int n = 0; n < 4; ++n)
#pragma unroll
                    for (int r = 0; r < 4; ++r)
                        tp[(32 * mi + 16 * m + l4 * 4 + r) * 68 + 16 * n + l15] =
                            acc[m][n][r];
        }
        __syncthreads();
        {
            int r = tid >> 2, q = tid & 3;
            int n = base + r;
            if (n < NN) {
                unsigned uu[8];
#pragma unroll
                for (int j = 0; j < 8; ++j) {
                    float lo = tp[r * 68 + q * 16 + 2 * j];
                    float hi = tp[r * 68 + q * 16 + 2 * j + 1];
                    uu[j] = ((unsigned)bf16_rne(hi) << 16) | bf16_rne(lo);
                }
                uint4* op = (uint4*)(Pbu + (size_t)64 * n + q * 16);
                op[0] = make_uint4(uu[0], uu[1], uu[2], uu[3]);
                op[1] = make_uint4(uu[4], uu[5], uu[6], uu[7]);
            }
        }
    }
}

// ===========================================================================
// Edge kernel — round-14/17 structure; IDX now reads packed int2 epair
// (read-side only; store path byte-identical — rounds 13/16 lesson).
// ===========================================================================
__global__ __launch_bounds__(512, 6) void edge_kernel(
    const float* __restrict__ Pt, const unsigned short* __restrict__ Pbu,
    const int2* __restrict__ epair,
    const float* __restrict__ b1g,
    const float* __restrict__ w2g, const float* __restrict__ b2g,
    unsigned short* __restrict__ m2g, int ntiles)
{
    extern __shared__ __align__(16) char smem[];
    char*  wt2s = smem;                       // [64c][128B] swz   8192
    char*  m1s  = wt2s + 8192;                // [128r][128B] swz 16384
    float* b1s  = (float*)(m1s + 16384);      // 64 f32
    float* b2s  = b1s + 64;                   // 64 f32

    const int tid = threadIdx.x;
    const int l   = tid & 63;
    const int w   = tid >> 6;
    const int mi  = w >> 1;
    const int ni  = w & 1;
    const int l15 = l & 15;
    const int l4  = l >> 4;
    const int g7  = tid & 7;

    {
        int c = tid >> 3, kc = tid & 7;
        const float* wp = w2g + (kc * 8) * 64 + c;
        bf16x8 bv;
#pragma unroll
        for (int j = 0; j < 8; ++j) bv[j] = (short)bf16_rne(wp[j * 64]);
        *(bf16x8*)(wt2s + c * 128 + ((kc * 16) ^ ((c & 7) << 4))) = bv;
    }
    if (tid < 64) { b1s[tid] = b1g[tid]; b2s[tid] = b2g[tid]; }

    int    ix_d[2], ix_s[2];
    float4 pf_a0[2], pf_a1[2];
    uint4  pf_pb[2];

    auto IDX = [&](int tt) {
        int eb = tt * 128;
#pragma unroll
        for (int it = 0; it < 2; ++it) {
            int e = (it * 512 + tid) >> 3;
            int2 p = epair[eb + e];
            ix_s[it] = p.x;
            ix_d[it] = p.y;
        }
    };
    auto DATA = [&]() {
#pragma unroll
        for (int it = 0; it < 2; ++it) {
            const float* pt = Pt + (size_t)64 * ix_d[it] + 8 * g7;
            pf_a0[it] = *(const float4*)pt;
            pf_a1[it] = *(const float4*)(pt + 4);
            pf_pb[it] = *(const uint4*)(Pbu + (size_t)64 * ix_s[it] + 8 * g7);
        }
    };

    int tile = blockIdx.x;
    if (tile < ntiles) { IDX(tile); DATA(); }
    if (tile + gridDim.x < ntiles) IDX(tile + gridDim.x);
    barrier_lgkm();

    for (; tile < ntiles; tile += gridDim.x) {
#pragma unroll
        for (int it = 0; it < 2; ++it) {
            int e = (it * 512 + tid) >> 3;
            float4 b0  = *(const float4*)(b1s + 8 * g7);
            float4 b1v = *(const float4*)(b1s + 8 * g7 + 4);
            float v0 = silu_f(pf_a0[it].x + bflo(pf_pb[it].x) + b0.x);
            float v1 = silu_f(pf_a0[it].y + bfhi(pf_pb[it].x) + b0.y);
            float v2 = silu_f(pf_a0[it].z + bflo(pf_pb[it].y) + b0.z);
            float v3 = silu_f(pf_a0[it].w + bfhi(pf_pb[it].y) + b0.w);
            float v4 = silu_f(pf_a1[it].x + bflo(pf_pb[it].z) + b1v.x);
            float v5 = silu_f(pf_a1[it].y + bfhi(pf_pb[it].z) + b1v.y);
            float v6 = silu_f(pf_a1[it].z + bflo(pf_pb[it].w) + b1v.z);
            float v7 = silu_f(pf_a1[it].w + bfhi(pf_pb[it].w) + b1v.w);
            uint4 o;
            o.x = ((unsigned)bf16_rne(v1) << 16) | bf16_rne(v0);
            o.y = ((unsigned)bf16_rne(v3) << 16) | bf16_rne(v2);
            o.z = ((unsigned)bf16_rne(v5) << 16) | bf16_rne(v4);
            o.w = ((unsigned)bf16_rne(v7) << 16) | bf16_rne(v6);
            *(uint4*)(m1s + e * 128 + ((g7 * 16) ^ ((e & 7) << 4))) = o;
        }
        barrier_lgkm();                           // B1: m1s ready
        int nxt = tile + gridDim.x;
        if (nxt < ntiles) {
            DATA();                               // idx regs completed 1 iter ago
            if (nxt + gridDim.x < ntiles) IDX(nxt + gridDim.x);
        }
        f32x4 acc2[2][2];
#pragma unroll
        for (int m = 0; m < 2; ++m)
#pragma unroll
            for (int n = 0; n < 2; ++n) {
                float b = b2s[32 * ni + 16 * n + l15];
                acc2[m][n] = (f32x4){b, b, b, b};
            }
        const int sw = (l15 & 7) << 4;
#pragma unroll
        for (int ks = 0; ks < 2; ++ks) {
            int kb = ks * 64 + l4 * 16;
            bf16x8 af[2], bfr[2];
#pragma unroll
            for (int m = 0; m < 2; ++m)
                af[m] = *(const bf16x8*)(m1s + (32 * mi + 16 * m + l15) * 128 + (kb ^ sw));
#pragma unroll
            for (int n = 0; n < 2; ++n)
                bfr[n] = *(const bf16x8*)(wt2s + (32 * ni + 16 * n + l15) * 128 + (kb ^ sw));
#pragma unroll
            for (int m = 0; m < 2; ++m)
#pragma unroll
                for (int n = 0; n < 2; ++n)
                    acc2[m][n] = mfma16(af[m], bfr[n], acc2[m][n]);
        }
        // m2 = silu -> direct bf16 global store (proven 60us path)
        unsigned short* mg = m2g + (size_t)(tile * 128) * 64;
#pragma unroll
        for (int m = 0; m < 2; ++m)
#pragma unroll
            for (int n = 0; n < 2; ++n)
#pragma unroll
                for (int r = 0; r < 4; ++r) {
                    int row = 32 * mi + 16 * m + l4 * 4 + r;
                    int col = 32 * ni + 16 * n + l15;
                    mg[row * 64 + col] = bf16_rne(silu_f(acc2[m][n][r]));
                }
        barrier_lgkm();                           // B2: m1s reads done before next write
    }
}

// ===========================================================================
// agg_kernel: agg[n] = sum of contiguous m2g rows (CSR). Thread = (node, 4 cols).
// ===========================================================================
__global__ __launch_bounds__(256) void agg_kernel(
    const unsigned short* __restrict__ m2g, const int* __restrict__ rowptr,
    float* __restrict__ agg)
{
    int idx = blockIdx.x * 256 + threadIdx.x;
    if (idx >= NN * 16) return;
    int n = idx >> 4, c = idx & 15;
    int e0 = rowptr[n], e1 = rowptr[n + 1];
    float a0 = 0.f, a1 = 0.f, a2 = 0.f, a3 = 0.f;
    int e = e0;
    for (; e + 4 <= e1; e += 4) {
        uint2 u0 = *(const uint2*)(m2g + (size_t)(e + 0) * 64 + 4 * c);
        uint2 u1 = *(const uint2*)(m2g + (size_t)(e + 1) * 64 + 4 * c);
        uint2 u2 = *(const uint2*)(m2g + (size_t)(e + 2) * 64 + 4 * c);
        uint2 u3 = *(const uint2*)(m2g + (size_t)(e + 3) * 64 + 4 * c);
        a0 += (bflo(u0.x) + bflo(u1.x)) + (bflo(u2.x) + bflo(u3.x));
        a1 += (bfhi(u0.x) + bfhi(u1.x)) + (bfhi(u2.x) + bfhi(u3.x));
        a2 += (bflo(u0.y) + bflo(u1.y)) + (bflo(u2.y) + bflo(u3.y));
        a3 += (bfhi(u0.y) + bfhi(u1.y)) + (bfhi(u2.y) + bfhi(u3.y));
    }
    for (; e < e1; ++e) {
        uint2 u = *(const uint2*)(m2g + (size_t)e * 64 + 4 * c);
        a0 += bflo(u.x); a1 += bfhi(u.x);
        a2 += bflo(u.y); a3 += bfhi(u.y);
    }
    *(float4*)(agg + (size_t)64 * n + 4 * c) = make_float4(a0, a1, a2, a3);
}

// ===========================================================================
// Node row-MLP: cats=[h|agg], u=silu(cats@W1+b1), h = u@W2 + b2 + h.
// ===========================================================================
__global__ __launch_bounds__(512, 1) void node_mlp_kernel(
    const float* __restrict__ A, const float* __restrict__ A2,
    const float* __restrict__ w1g, const float* __restrict__ b1g,
    const float* __restrict__ w2g, const float* __restrict__ b2g,
    float* __restrict__ outp, int nrows, int ntiles)
{
    extern __shared__ float lds[];
    float* ws1  = lds;
    float* ws2  = ws1 + 8192;
    float* wb1  = ws2 + 4096;
    float* wb2  = wb1 + 64;
    float* cats = wb2 + 64;
    float* m1s  = cats + 128 * 132;

    const int tid = threadIdx.x;
    const int tr  = tid & 31;
    const int tc  = tid >> 5;

    for (int i = tid; i < 2048; i += 512)
        *(float4*)&ws1[4 * i] = *(const float4*)&w1g[4 * i];
    for (int i = tid; i < 1024; i += 512)
        *(float4*)&ws2[4 * i] = *(const float4*)&w2g[4 * i];
    if (tid < 64) { wb1[tid] = b1g[tid]; wb2[tid] = b2g[tid]; }

    for (int tile = blockIdx.x; tile < ntiles; tile += gridDim.x) {
        const int base = tile * 128;
        __syncthreads();
#pragma unroll
        for (int rep = 0; rep < 8; ++rep) {
            int idx = rep * 512 + tid;
            int r = idx >> 5, q = idx & 31;
            int n = base + r;
            float4 v = make_float4(0.f, 0.f, 0.f, 0.f);
            if (n < nrows)
                v = (q < 16) ? *(const float4*)(A + 64 * n + 4 * q)
                             : *(const float4*)(A2 + 64 * n + 4 * (q - 16));
            *(float4*)&cats[r * 132 + 4 * q] = v;
        }
        __syncthreads();
        float acc[4][4];
#pragma unroll
        for (int jj = 0; jj < 4; ++jj)
#pragma unroll
            for (int ii = 0; ii < 4; ++ii) acc[jj][ii] = wb1[4 * tc + ii];
#pragma unroll 4
        for (int k16 = 0; k16 < 32; ++k16) {
            float4 bv0 = *(const float4*)&ws1[(4 * k16 + 0) * 64 + 4 * tc];
            float4 bv1 = *(const float4*)&ws1[(4 * k16 + 1) * 64 + 4 * tc];
            float4 bv2 = *(const float4*)&ws1[(4 * k16 + 2) * 64 + 4 * tc];
            float4 bv3 = *(const float4*)&ws1[(4 * k16 + 3) * 64 + 4 * tc];
#pragma unroll
            for (int jj = 0; jj < 4; ++jj) {
                float4 av = *(const float4*)&cats[(tr + 32 * jj) * 132 + 4 * k16];
                acc[jj][0] = fmaf(av.x, bv0.x, fmaf(av.y, bv1.x, fmaf(av.z, bv2.x, fmaf(av.w, bv3.x, acc[jj][0]))));
                acc[jj][1] = fmaf(av.x, bv0.y, fmaf(av.y, bv1.y, fmaf(av.z, bv2.y, fmaf(av.w, bv3.y, acc[jj][1]))));
                acc[jj][2] = fmaf(av.x, bv0.z, fmaf(av.y, bv1.z, fmaf(av.z, bv2.z, fmaf(av.w, bv3.z, acc[jj][2]))));
                acc[jj][3] = fmaf(av.x, bv0.w, fmaf(av.y, bv1.w, fmaf(av.z, bv2.w, fmaf(av.w, bv3.w, acc[jj][3]))));
            }
        }
#pragma unroll
        for (int jj = 0; jj < 4; ++jj) {
            float4 v;
            v.x = silu_f(acc[jj][0]); v.y = silu_f(acc[jj][1]);
            v.z = silu_f(acc[jj][2]); v.w = silu_f(acc[jj][3]);
            *(float4*)&m1s[(tr + 32 * jj) * 68 + 4 * tc] = v;
        }
        __syncthreads();
        float acc2[4][4];
#pragma unroll
        for (int jj = 0; jj < 4; ++jj)
#pragma unroll
            for (int ii = 0; ii < 4; ++ii) acc2[jj][ii] = wb2[4 * tc + ii];
#pragma unroll 4
        for (int k16 = 0; k16 < 16; ++k16) {
            float4 bv0 = *(const float4*)&ws2[(4 * k16 + 0) * 64 + 4 * tc];
            float4 bv1 = *(const float4*)&ws2[(4 * k16 + 1) * 64 + 4 * tc];
            float4 bv2 = *(const float4*)&ws2[(4 * k16 + 2) * 64 + 4 * tc];
            float4 bv3 = *(const float4*)&ws2[(4 * k16 + 3) * 64 + 4 * tc];
#pragma unroll
            for (int jj = 0; jj < 4; ++jj) {
                float4 av = *(const float4*)&m1s[(tr + 32 * jj) * 68 + 4 * k16];
                acc2[jj][0] = fmaf(av.x, bv0.x, fmaf(av.y, bv1.x, fmaf(av.z, bv2.x, fmaf(av.w, bv3.x, acc2[jj][0]))));
                acc2[jj][1] = fmaf(av.x, bv0.y, fmaf(av.y, bv1.y, fmaf(av.z, bv2.y, fmaf(av.w, bv3.y, acc2[jj][1]))));
                acc2[jj][2] = fmaf(av.x, bv0.z, fmaf(av.y, bv1.z, fmaf(av.z, bv2.z, fmaf(av.w, bv3.z, acc2[jj][2]))));
                acc2[jj][3] = fmaf(av.x, bv0.w, fmaf(av.y, bv1.w, fmaf(av.z, bv2.w, fmaf(av.w, bv3.w, acc2[jj][3]))));
            }
        }
#pragma unroll
        for (int jj = 0; jj < 4; ++jj) {
            int r = tr + 32 * jj;
            int n = base + r;
            if (n < nrows) {
                float4 hold = *(const float4*)&cats[r * 132 + 4 * tc];
                *(float4*)&outp[64 * n + 4 * tc] = make_float4(
                    acc2[jj][0] + hold.x, acc2[jj][1] + hold.y,
                    acc2[jj][2] + hold.z, acc2[jj][3] + hold.w);
            }
        }
    }
}

// ===========================================================================
// Readout row-MLP (K1=64, segmented scatter into gsum)
// ===========================================================================
__global__ __launch_bounds__(512, 1) void rowmlp_ro_kernel(
    const float* __restrict__ A,
    const float* __restrict__ w1g, const float* __restrict__ b1g,
    const float* __restrict__ w2g, const float* __restrict__ b2g,
    const int* __restrict__ seg, float* __restrict__ outp,
    int nrows, int ntiles)
{
    extern __shared__ float lds[];
    float* ws1  = lds;
    float* ws2  = ws1 + 4096;
    float* wb1  = ws2 + 4096;
    float* wb2  = wb1 + 64;
    float* cats = wb2 + 64;
    float* m1s  = cats + 128 * 68;
    int*   segs = (int*)(m1s + 128 * 68);

    const int tid = threadIdx.x;
    const int tr  = tid & 31;
    const int tc  = tid >> 5;

    for (int i = tid; i < 1024; i += 512) {
        *(float4*)&ws1[4 * i] = *(const float4*)&w1g[4 * i];
        *(float4*)&ws2[4 * i] = *(const float4*)&w2g[4 * i];
    }
    if (tid < 64) { wb1[tid] = b1g[tid]; wb2[tid] = b2g[tid]; }

    for (int tile = blockIdx.x; tile < ntiles; tile += gridDim.x) {
        const int base = tile * 128;
        __syncthreads();
        if (tid < 128) segs[tid] = (base + tid < nrows) ? seg[base + tid] : -1;
#pragma unroll
        for (int rep = 0; rep < 4; ++rep) {
            int idx = rep * 512 + tid;
            int r = idx >> 4, q = idx & 15;
            int n = base + r;
            float4 v = make_float4(0.f, 0.f, 0.f, 0.f);
            if (n < nrows) v = *(const float4*)(A + 64 * n + 4 * q);
            *(float4*)&cats[r * 68 + 4 * q] = v;
        }
        __syncthreads();
        float acc[4][4];
#pragma unroll
        for (int jj = 0; jj < 4; ++jj)
#pragma unroll
            for (int ii = 0; ii < 4; ++ii) acc[jj][ii] = wb1[4 * tc + ii];
#pragma unroll 4
        for (int k16 = 0; k16 < 16; ++k16) {
            float4 bv0 = *(const float4*)&ws1[(4 * k16 + 0) * 64 + 4 * tc];
            float4 bv1 = *(const float4*)&ws1[(4 * k16 + 1) * 64 + 4 * tc];
            float4 bv2 = *(const float4*)&ws1[(4 * k16 + 2) * 64 + 4 * tc];
            float4 bv3 = *(const float4*)&ws1[(4 * k16 + 3) * 64 + 4 * tc];
#pragma unroll
            for (int jj = 0; jj < 4; ++jj) {
                float4 av = *(const float4*)&cats[(tr + 32 * jj) * 68 + 4 * k16];
                acc[jj][0] = fmaf(av.x, bv0.x, fmaf(av.y, bv1.x, fmaf(av.z, bv2.x, fmaf(av.w, bv3.x, acc[jj][0]))));
                acc[jj][1] = fmaf(av.x, bv0.y, fmaf(av.y, bv1.y, fmaf(av.z, bv2.y, fmaf(av.w, bv3.y, acc[jj][1]))));
                acc[jj][2] = fmaf(av.x, bv0.z, fmaf(av.y, bv1.z, fmaf(av.z, bv2.z, fmaf(av.w, bv3.z, acc[jj][2]))));
                acc[jj][3] = fmaf(av.x, bv0.w, fmaf(av.y, bv1.w, fmaf(av.z, bv2.w, fmaf(av.w, bv3.w, acc[jj][3]))));
            }
        }
#pragma unroll
        for (int jj = 0; jj < 4; ++jj) {
            float4 v;
            v.x = silu_f(acc[jj][0]); v.y = silu_f(acc[jj][1]);
            v.z = silu_f(acc[jj][2]); v.w = silu_f(acc[jj][3]);
            *(float4*)&m1s[(tr + 32 * jj) * 68 + 4 * tc] = v;
        }
        __syncthreads();
        float acc2[4][4];
#pragma unroll
        for (int jj = 0; jj < 4; ++jj)
#pragma unroll
            for (int ii = 0; ii < 4; ++ii) acc2[jj][ii] = wb2[4 * tc + ii];
#pragma unroll 4
        for (int k16 = 0; k16 < 16; ++k16) {
            float4 bv0 = *(const float4*)&ws2[(4 * k16 + 0) * 64 + 4 * tc];
            float4 bv1 = *(const float4*)&ws2[(4 * k16 + 1) * 64 + 4 * tc];
            float4 bv2 = *(const float4*)&ws2[(4 * k16 + 2) * 64 + 4 * tc];
            float4 bv3 = *(const float4*)&ws2[(4 * k16 + 3) * 64 + 4 * tc];
#pragma unroll
            for (int jj = 0; jj < 4; ++jj) {
                float4 av = *(const float4*)&m1s[(tr + 32 * jj) * 68 + 4 * k16];
                acc2[jj][0] = fmaf(av.x, bv0.x, fmaf(av.y, bv1.x, fmaf(av.z, bv2.x, fmaf(av.w, bv3.x, acc2[jj][0]))));
                acc2[jj][1] = fmaf(av.x, bv0.y, fmaf(av.y, bv1.y, fmaf(av.z, bv2.y, fmaf(av.w, bv3.y, acc2[jj][1]))));
                acc2[jj][2] = fmaf(av.x, bv0.z, fmaf(av.y, bv1.z, fmaf(av.z, bv2.z, fmaf(av.w, bv3.z, acc2[jj][2]))));
                acc2[jj][3] = fmaf(av.x, bv0.w, fmaf(av.y, bv1.w, fmaf(av.z, bv2.w, fmaf(av.w, bv3.w, acc2[jj][3]))));
            }
        }
#pragma unroll
        for (int jj = 0; jj < 4; ++jj) {
            int r = tr + 32 * jj;
            int n = base + r;
            int gid = segs[r];
            float4 vv = (n < nrows) ? make_float4(acc2[jj][0], acc2[jj][1], acc2[jj][2], acc2[jj][3])
                                    : make_float4(0.f, 0.f, 0.f, 0.f);
            unsigned f = (tr == 0 || segs[(r > 0) ? r - 1 : 0] != gid) ? 1u : 0u;
#pragma unroll
            for (int s = 1; s < 32; s <<= 1) {
                float ux = __shfl_up(vv.x, s, 32);
                float uy = __shfl_up(vv.y, s, 32);
                float uz = __shfl_up(vv.z, s, 32);
                float uw = __shfl_up(vv.w, s, 32);
                unsigned uf = __shfl_up(f, s, 32);
                if (tr >= s) {
                    if (!f) { vv.x += ux; vv.y += uy; vv.z += uz; vv.w += uw; }
                    f |= uf;
                }
            }
            bool tail = (tr == 31) || (segs[r + 1] != gid);
            if (tail && gid >= 0) {
                float* bp = outp + 64 * gid + 4 * tc;
                atomicAdd(bp + 0, vv.x); atomicAdd(bp + 1, vv.y);
                atomicAdd(bp + 2, vv.z); atomicAdd(bp + 3, vv.w);
            }
        }
    }
}

__global__ __launch_bounds__(256) void proj_kernel(
    const float* __restrict__ x, const float* __restrict__ w,
    const float* __restrict__ b, float* __restrict__ h, int n)
{
    int i = blockIdx.x * 256 + threadIdx.x;
    if (i >= n * 64) return;
    int node = i >> 6, j = i & 63;
    const float* xr = x + node * 14;
    float acc = b[j];
#pragma unroll
    for (int k = 0; k < 14; ++k) acc = fmaf(xr[k], w[k * 64 + j], acc);
    h[i] = acc;
}

__global__ __launch_bounds__(256) void head_kernel(
    const float* __restrict__ gsum,
    const float* __restrict__ w3, const float* __restrict__ b3,
    const float* __restrict__ w4, const float* __restrict__ b4,
    float* __restrict__ out, int g_count)
{
    int wid  = (blockIdx.x * 256 + threadIdx.x) >> 6;
    int lane = threadIdx.x & 63;
    if (wid >= g_count) return;
    float v = gsum[wid * 64 + lane];
    float t = b3[lane];
#pragma unroll
    for (int k = 0; k < 64; ++k) {
        float a = __shfl(v, k, 64);
        t = fmaf(a, w3[k * 64 + lane], t);
    }
    t = silu_f(t);
    float r = t * w4[lane];
#pragma unroll
    for (int off = 32; off; off >>= 1) r += __shfl_down(r, off, 64);
    if (lane == 0) out[wid] = r + b4[0];
}

extern "C" void kernel_launch(void* const* d_in, const int* in_sizes, int n_in,
                              void* d_out, int out_size, void* d_ws, size_t ws_size,
                              hipStream_t stream)
{
    const float* x      = (const float*)d_in[0];
    const int*   ei     = (const int*)d_in[2];
    const int*   batch  = (const int*)d_in[3];
    const float* proj_w = (const float*)d_in[4];
    const float* proj_b = (const float*)d_in[5];
    const float* ew1 = (const float*)d_in[6];
    const float* eb1 = (const float*)d_in[7];
    const float* ew2 = (const float*)d_in[8];
    const float* eb2 = (const float*)d_in[9];
    const float* nw1 = (const float*)d_in[10];
    const float* nb1 = (const float*)d_in[11];
    const float* nw2 = (const float*)d_in[12];
    const float* nb2 = (const float*)d_in[13];
    const float* l1w = (const float*)d_in[14]; const float* l1b = (const float*)d_in[15];
    const float* l2w = (const float*)d_in[16]; const float* l2b = (const float*)d_in[17];
    const float* l3w = (const float*)d_in[18]; const float* l3b = (const float*)d_in[19];
    const float* l4w = (const float*)d_in[20]; const float* l4b = (const float*)d_in[21];

    float* out  = (float*)d_out;
    float* h    = out + GG;                      // per_atom_out doubles as h

    unsigned short* m2g = (unsigned short*)d_ws;             // [E,64] bf16 = 102.4MB
    float* gsum = (float*)(m2g + (size_t)EE * 64);           // [G,64]
    float* Pt   = gsum + (size_t)GG * 64;                    // [N,64] f32
    unsigned short* Pbu = (unsigned short*)(Pt + (size_t)NN * 64);  // [N,64] bf16
    int* deg    = (int*)(Pbu + (size_t)NN * 64);
    int* rowptr = deg + NN;                                  // N+1
    int* cursor = rowptr + NN + 1;
    int2* epair = (int2*)(((uintptr_t)(cursor + NN) + 15) & ~(uintptr_t)15);  // [E] packed (src,dst)
    int* bsum   = (int*)(epair + EE);                        // [98]
    float* agg  = Pt;   // alias: Pt dead after edge_kernel, rebuilt next layer

    const size_t edge_lds = 8192 + 16384 + 256 + 256;                 // 25088
    const size_t pk_lds   = 16384 + 16384 + 34816;                    // 67584
    const size_t node_lds = (size_t)(8192 + 4096 + 128 + 128 * 132 + 128 * 68) * 4;
    const size_t ro_lds   = (size_t)(4096 + 4096 + 128 + 128 * 68 + 128 * 68) * 4 + 128 * 4;

    (void)hipFuncSetAttribute((const void*)edge_kernel,
                              hipFuncAttributeMaxDynamicSharedMemorySize, (int)edge_lds);
    (void)hipFuncSetAttribute((const void*)pk_kernel,
                              hipFuncAttributeMaxDynamicSharedMemorySize, (int)pk_lds);
    (void)hipFuncSetAttribute((const void*)node_mlp_kernel,
                              hipFuncAttributeMaxDynamicSharedMemorySize, (int)node_lds);
    (void)hipFuncSetAttribute((const void*)rowmlp_ro_kernel,
                              hipFuncAttributeMaxDynamicSharedMemorySize, (int)ro_lds);

    // --- CSR build (dst-sorted packed edge list) ---
    const int nb = (NN + 511) / 512;           // 98
    hipMemsetAsync(deg, 0, (size_t)NN * sizeof(int), stream);
    hipMemsetAsync(gsum, 0, (size_t)GG * 64 * sizeof(float), stream);
    hist_kernel<<<(EE + 255) / 256, 256, 0, stream>>>(ei, deg);
    scanA_kernel<<<nb, 512, 0, stream>>>(deg, rowptr, bsum);
    scanB_kernel<<<1, 128, 0, stream>>>(bsum, nb);
    scanC_kernel<<<nb, 512, 0, stream>>>(rowptr, cursor, bsum);
    scatter_kernel<<<(EE + 255) / 256, 256, 0, stream>>>(ei, cursor, epair);

    proj_kernel<<<(NN * 64 + 255) / 256, 256, 0, stream>>>(x, proj_w, proj_b, h, NN);

    const int etiles = EE / 128;               // 6250 (exact)
    const int ntiles = (NN + 127) / 128;       // 391
    for (int l = 0; l < LL; ++l) {
        pk_kernel<<<ntiles, 512, pk_lds, stream>>>(h, ew1 + l * 8192, Pt, Pbu, ntiles);
        edge_kernel<<<1024, 512, edge_lds, stream>>>(
            Pt, Pbu, epair, eb1 + l * 64, ew2 + l * 4096, eb2 + l * 64,
            m2g, etiles);
        agg_kernel<<<(NN * 16 + 255) / 256, 256, 0, stream>>>(m2g, rowptr, agg);
        node_mlp_kernel<<<196, 512, node_lds, stream>>>(
            h, agg, nw1 + l * 8192, nb1 + l * 64, nw2 + l * 4096, nb2 + l * 64,
            h, NN, ntiles);
    }
    rowmlp_ro_kernel<<<196, 512, ro_lds, stream>>>(
        h, l1w, l1b, l2w, l2b, batch, gsum, NN, ntiles);
    head_kernel<<<GG / 4, 256, 0, stream>>>(gsum, l3w, l3b, l4w, l4b, out, GG);
}

// Round 21
// 464.595 us; speedup vs baseline: 1.5483x; 1.0295x over previous
//
#include <hip/hip_runtime.h>

#define NN 50000
#define EE 800000
#define GG 512
#define LL 3

typedef short bf16x8 __attribute__((ext_vector_type(8)));
typedef float f32x4  __attribute__((ext_vector_type(4)));

__device__ __forceinline__ float silu_f(float x) {
    return x * __builtin_amdgcn_rcpf(1.0f + __expf(-x));
}
__device__ __forceinline__ unsigned short bf16_rne(float x) {
    unsigned u = __float_as_uint(x);
    u += 0x7fffu + ((u >> 16) & 1u);
    return (unsigned short)(u >> 16);
}
__device__ __forceinline__ float bflo(unsigned u) { return __uint_as_float(u << 16); }
__device__ __forceinline__ float bfhi(unsigned u) { return __uint_as_float(u & 0xffff0000u); }
__device__ __forceinline__ f32x4 mfma16(bf16x8 a, bf16x8 b, f32x4 c) {
    return __builtin_amdgcn_mfma_f32_16x16x32_bf16(a, b, c, 0, 0, 0);
}
// lgkm-only barrier: drains LDS ops, leaves global loads/stores in flight.
__device__ __forceinline__ void barrier_lgkm() {
    asm volatile("s_waitcnt lgkmcnt(0)" ::: "memory");
    __builtin_amdgcn_s_barrier();
}

// ===========================================================================
// CSR build: 8-way sharded histogram -> hierarchical scan -> sharded scatter.
// Shard s = e&7 cuts same-address atomic contention 8x (hist AND scatter).
// Node n's edges stay exactly contiguous in [rowptr[n], rowptr[n+1]).
// ===========================================================================
__global__ __launch_bounds__(256) void hist_kernel(const int* __restrict__ ei,
                                                   int* __restrict__ deg8) {
    int e = blockIdx.x * 256 + threadIdx.x;
    if (e < EE) atomicAdd(&deg8[(e & 7) * NN + ei[EE + e]], 1);
}

// Phase A: per-block (512 nodes) local exclusive scan of total degree
__global__ __launch_bounds__(512) void scanA_kernel(const int* __restrict__ deg8,
                                                    int* __restrict__ rowptr,
                                                    int* __restrict__ bsum) {
    __shared__ int wsum[8];
    const int tid = threadIdx.x, b = blockIdx.x;
    int i = b * 512 + tid;
    int v = 0;
    if (i < NN) {
#pragma unroll
        for (int s = 0; s < 8; ++s) v += deg8[s * NN + i];
    }
    int lane = tid & 63, wid = tid >> 6;
    int x = v;
#pragma unroll
    for (int s = 1; s < 64; s <<= 1) {
        int u = __shfl_up(x, s, 64);
        if (lane >= s) x += u;
    }
    if (lane == 63) wsum[wid] = x;
    __syncthreads();
    int woff = 0;
    for (int w = 0; w < wid; ++w) woff += wsum[w];
    if (i < NN) rowptr[i] = woff + x - v;
    if (tid == 511) bsum[b] = woff + x;
}

__global__ __launch_bounds__(128) void scanB_kernel(int* __restrict__ bsum, int nb) {
    __shared__ int wsum[2];
    const int tid = threadIdx.x;
    int v = (tid < nb) ? bsum[tid] : 0;
    int lane = tid & 63, wid = tid >> 6;
    int x = v;
#pragma unroll
    for (int s = 1; s < 64; s <<= 1) {
        int u = __shfl_up(x, s, 64);
        if (lane >= s) x += u;
    }
    if (lane == 63) wsum[wid] = x;
    __syncthreads();
    int woff = (wid == 1) ? wsum[0] : 0;
    if (tid < nb) bsum[tid] = woff + x - v;
}

// Phase C: finalize rowptr, emit per-shard cursors
__global__ __launch_bounds__(512) void scanC_kernel(int* __restrict__ rowptr,
                                                    int* __restrict__ cursor8,
                                                    const int* __restrict__ deg8,
                                                    const int* __restrict__ bsum) {
    const int tid = threadIdx.x, b = blockIdx.x;
    int i = b * 512 + tid;
    if (i < NN) {
        int r = rowptr[i] + bsum[b];
        rowptr[i] = r;
        int running = r;
#pragma unroll
        for (int s = 0; s < 8; ++s) {
            cursor8[s * NN + i] = running;
            running += deg8[s * NN + i];
        }
    }
    if (i == 0) rowptr[NN] = EE;
}

// Sharded packed scatter: contention /8, one 8B store per edge
__global__ __launch_bounds__(256) void scatter_kernel(const int* __restrict__ ei,
                                                      int* __restrict__ cursor8,
                                                      int2* __restrict__ epair) {
    int e = blockIdx.x * 256 + threadIdx.x;
    if (e < EE) {
        int d = ei[EE + e];
        int pos = atomicAdd(&cursor8[(e & 7) * NN + d], 1);
        epair[pos] = make_int2(ei[e], d);   // (src, dst)
    }
}

// ===========================================================================
// pk_kernel (MFMA) — round-19 proven (cols 0-63 -> Pt f32, 64-127 -> Pb bf16)
// ===========================================================================
__global__ __launch_bounds__(512, 2) void pk_kernel(
    const float* __restrict__ h, const float* __restrict__ w1g,
    float* __restrict__ Pt, unsigned short* __restrict__ Pbu, int ntiles)
{
    extern __shared__ __align__(16) char smem[];
    char*  hb = smem;                    // [128r][128B] swz : 16384
    char*  wt = hb + 16384;              // [128c][128B] swz : 16384
    float* tp = (float*)(wt + 16384);    // [128][68] f32   : 34816

    const int tid = threadIdx.x;
    const int l   = tid & 63;
    const int w   = tid >> 6;
    const int mi  = w >> 1;
    const int ni  = w & 1;
    const int l15 = l & 15;
    const int l4  = l >> 4;
    const int sw  = (l15 & 7) << 4;

    {
        int c = tid >> 2, kq0 = tid & 3;
#pragma unroll
        for (int hf = 0; hf < 2; ++hf) {
            int kq = kq0 + 4 * hf;
            const float* wp = w1g + (size_t)((c >> 6) * 64 + kq * 8) * 64 + (c & 63);
            bf16x8 bv;
#pragma unroll
            for (int j = 0; j < 8; ++j) bv[j] = (short)bf16_rne(wp[j * 64]);
            *(bf16x8*)(wt + c * 128 + ((kq * 16) ^ ((c & 7) << 4))) = bv;
        }
    }

    for (int tile = blockIdx.x; tile < ntiles; tile += gridDim.x) {
        const int base = tile * 128;
        __syncthreads();
        {
            int r = tid >> 2, q = tid & 3;
            int n = base + r;
            float v[16];
#pragma unroll
            for (int j = 0; j < 16; ++j) v[j] = 0.f;
            if (n < NN) {
                const float* hp = h + (size_t)64 * n + q * 16;
#pragma unroll
                for (int j = 0; j < 4; ++j) {
                    float4 t = *(const float4*)(hp + 4 * j);
                    v[4 * j] = t.x; v[4 * j + 1] = t.y;
                    v[4 * j + 2] = t.z; v[4 * j + 3] = t.w;
                }
            }
            bf16x8 b0, b1;
#pragma unroll
            for (int j = 0; j < 8; ++j) {
                b0[j] = (short)bf16_rne(v[j]);
                b1[j] = (short)bf16_rne(v[8 + j]);
            }
            int swr = (r & 7) << 4;
            *(bf16x8*)(hb + r * 128 + ((q * 32) ^ swr))      = b0;
            *(bf16x8*)(hb + r * 128 + ((q * 32 + 16) ^ swr)) = b1;
        }
        __syncthreads();
        f32x4 acc[2][4];
#pragma unroll
        for (int m = 0; m < 2; ++m)
#pragma unroll
            for (int n = 0; n < 4; ++n) acc[m][n] = (f32x4){0.f, 0.f, 0.f, 0.f};
#pragma unroll
        for (int ks = 0; ks < 2; ++ks) {
            int kb = ks * 64 + l4 * 16;
            bf16x8 af[2], bf[4];
#pragma unroll
            for (int m = 0; m < 2; ++m)
                af[m] = *(const bf16x8*)(hb + (32 * mi + 16 * m + l15) * 128 + (kb ^ sw));
#pragma unroll
            for (int n = 0; n < 4; ++n)
                bf[n] = *(const bf16x8*)(wt + (64 * ni + 16 * n + l15) * 128 + (kb ^ sw));
#pragma unroll
            for (int m = 0; m < 2; ++m)
#pragma unroll
                for (int n = 0; n < 4; ++n)
                    acc[m][n] = mfma16(af[m], bf[n], acc[m][n]);
        }
        __syncthreads();
        if (ni == 0) {
#pragma unroll
            for (int m = 0; m < 2; ++m)
#pragma unroll
                for (int n = 0; n < 4; ++n)
#pragma unroll
                    for (int r = 0; r < 4; ++r)
                        tp[(32 * mi + 16 * m + l4 * 4 + r) * 68 + 16 * n + l15] =
                            acc[m][n][r];
        }
        __syncthreads();
        {
            int r = tid >> 2, q = tid & 3;
            int n = base + r;
            if (n < NN) {
                float* op = Pt + (size_t)64 * n + q * 16;
#pragma unroll
                for (int j = 0; j < 4; ++j)
                    *(float4*)(op + 4 * j) = *(const float4*)&tp[r * 68 + q * 16 + 4 * j];
            }
        }
        __syncthreads();
        if (ni == 1) {
#pragma unroll
            for (int m = 0; m < 2; ++m)
#pragma unroll
                for (int n = 0; n < 4; ++n)
#pragma unroll
                    for (int r = 0; r < 4; ++r)
                        tp[(32 * mi + 16 * m + l4 * 4 + r) * 68 + 16 * n + l15] =
                            acc[m][n][r];
        }
        __syncthreads();
        {
            int r = tid >> 2, q = tid & 3;
            int n = base + r;
            if (n < NN) {
                unsigned uu[8];
#pragma unroll
                for (int j = 0; j < 8; ++j) {
                    float lo = tp[r * 68 + q * 16 + 2 * j];
                    float hi = tp[r * 68 + q * 16 + 2 * j + 1];
                    uu[j] = ((unsigned)bf16_rne(hi) << 16) | bf16_rne(lo);
                }
                uint4* op = (uint4*)(Pbu + (size_t)64 * n + q * 16);
                op[0] = make_uint4(uu[0], uu[1], uu[2], uu[3]);
                op[1] = make_uint4(uu[4], uu[5], uu[6], uu[7]);
            }
        }
    }
}

// ===========================================================================
// Edge kernel — round-14/17 structure; packed int2 IDX (round-20 proven).
// Store path byte-identical — rounds 13/16 lesson.
// ===========================================================================
__global__ __launch_bounds__(512, 6) void edge_kernel(
    const float* __restrict__ Pt, const unsigned short* __restrict__ Pbu,
    const int2* __restrict__ epair,
    const float* __restrict__ b1g,
    const float* __restrict__ w2g, const float* __restrict__ b2g,
    unsigned short* __restrict__ m2g, int ntiles)
{
    extern __shared__ __align__(16) char smem[];
    char*  wt2s = smem;                       // [64c][128B] swz   8192
    char*  m1s  = wt2s + 8192;                // [128r][128B] swz 16384
    float* b1s  = (float*)(m1s + 16384);      // 64 f32
    float* b2s  = b1s + 64;                   // 64 f32

    const int tid = threadIdx.x;
    const int l   = tid & 63;
    const int w   = tid >> 6;
    const int mi  = w >> 1;
    const int ni  = w & 1;
    const int l15 = l & 15;
    const int l4  = l >> 4;
    const int g7  = tid & 7;

    {
        int c = tid >> 3, kc = tid & 7;
        const float* wp = w2g + (kc * 8) * 64 + c;
        bf16x8 bv;
#pragma unroll
        for (int j = 0; j < 8; ++j) bv[j] = (short)bf16_rne(wp[j * 64]);
        *(bf16x8*)(wt2s + c * 128 + ((kc * 16) ^ ((c & 7) << 4))) = bv;
    }
    if (tid < 64) { b1s[tid] = b1g[tid]; b2s[tid] = b2g[tid]; }

    int    ix_d[2], ix_s[2];
    float4 pf_a0[2], pf_a1[2];
    uint4  pf_pb[2];

    auto IDX = [&](int tt) {
        int eb = tt * 128;
#pragma unroll
        for (int it = 0; it < 2; ++it) {
            int e = (it * 512 + tid) >> 3;
            int2 p = epair[eb + e];
            ix_s[it] = p.x;
            ix_d[it] = p.y;
        }
    };
    auto DATA = [&]() {
#pragma unroll
        for (int it = 0; it < 2; ++it) {
            const float* pt = Pt + (size_t)64 * ix_d[it] + 8 * g7;
            pf_a0[it] = *(const float4*)pt;
            pf_a1[it] = *(const float4*)(pt + 4);
            pf_pb[it] = *(const uint4*)(Pbu + (size_t)64 * ix_s[it] + 8 * g7);
        }
    };

    int tile = blockIdx.x;
    if (tile < ntiles) { IDX(tile); DATA(); }
    if (tile + gridDim.x < ntiles) IDX(tile + gridDim.x);
    barrier_lgkm();

    for (; tile < ntiles; tile += gridDim.x) {
#pragma unroll
        for (int it = 0; it < 2; ++it) {
            int e = (it * 512 + tid) >> 3;
            float4 b0  = *(const float4*)(b1s + 8 * g7);
            float4 b1v = *(const float4*)(b1s + 8 * g7 + 4);
            float v0 = silu_f(pf_a0[it].x + bflo(pf_pb[it].x) + b0.x);
            float v1 = silu_f(pf_a0[it].y + bfhi(pf_pb[it].x) + b0.y);
            float v2 = silu_f(pf_a0[it].z + bflo(pf_pb[it].y) + b0.z);
            float v3 = silu_f(pf_a0[it].w + bfhi(pf_pb[it].y) + b0.w);
            float v4 = silu_f(pf_a1[it].x + bflo(pf_pb[it].z) + b1v.x);
            float v5 = silu_f(pf_a1[it].y + bfhi(pf_pb[it].z) + b1v.y);
            float v6 = silu_f(pf_a1[it].z + bflo(pf_pb[it].w) + b1v.z);
            float v7 = silu_f(pf_a1[it].w + bfhi(pf_pb[it].w) + b1v.w);
            uint4 o;
            o.x = ((unsigned)bf16_rne(v1) << 16) | bf16_rne(v0);
            o.y = ((unsigned)bf16_rne(v3) << 16) | bf16_rne(v2);
            o.z = ((unsigned)bf16_rne(v5) << 16) | bf16_rne(v4);
            o.w = ((unsigned)bf16_rne(v7) << 16) | bf16_rne(v6);
            *(uint4*)(m1s + e * 128 + ((g7 * 16) ^ ((e & 7) << 4))) = o;
        }
        barrier_lgkm();                           // B1: m1s ready
        int nxt = tile + gridDim.x;
        if (nxt < ntiles) {
            DATA();                               // idx regs completed 1 iter ago
            if (nxt + gridDim.x < ntiles) IDX(nxt + gridDim.x);
        }
        f32x4 acc2[2][2];
#pragma unroll
        for (int m = 0; m < 2; ++m)
#pragma unroll
            for (int n = 0; n < 2; ++n) {
                float b = b2s[32 * ni + 16 * n + l15];
                acc2[m][n] = (f32x4){b, b, b, b};
            }
        const int sw = (l15 & 7) << 4;
#pragma unroll
        for (int ks = 0; ks < 2; ++ks) {
            int kb = ks * 64 + l4 * 16;
            bf16x8 af[2], bfr[2];
#pragma unroll
            for (int m = 0; m < 2; ++m)
                af[m] = *(const bf16x8*)(m1s + (32 * mi + 16 * m + l15) * 128 + (kb ^ sw));
#pragma unroll
            for (int n = 0; n < 2; ++n)
                bfr[n] = *(const bf16x8*)(wt2s + (32 * ni + 16 * n + l15) * 128 + (kb ^ sw));
#pragma unroll
            for (int m = 0; m < 2; ++m)
#pragma unroll
                for (int n = 0; n < 2; ++n)
                    acc2[m][n] = mfma16(af[m], bfr[n], acc2[m][n]);
        }
        // m2 = silu -> direct bf16 global store (proven 60us path)
        unsigned short* mg = m2g + (size_t)(tile * 128) * 64;
#pragma unroll
        for (int m = 0; m < 2; ++m)
#pragma unroll
            for (int n = 0; n < 2; ++n)
#pragma unroll
                for (int r = 0; r < 4; ++r) {
                    int row = 32 * mi + 16 * m + l4 * 4 + r;
                    int col = 32 * ni + 16 * n + l15;
                    mg[row * 64 + col] = bf16_rne(silu_f(acc2[m][n][r]));
                }
        barrier_lgkm();                           // B2: m1s reads done before next write
    }
}

// ===========================================================================
// agg_kernel: agg[n] = sum of contiguous m2g rows (CSR). Thread = (node, 4 cols).
// ===========================================================================
__global__ __launch_bounds__(256) void agg_kernel(
    const unsigned short* __restrict__ m2g, const int* __restrict__ rowptr,
    float* __restrict__ agg)
{
    int idx = blockIdx.x * 256 + threadIdx.x;
    if (idx >= NN * 16) return;
    int n = idx >> 4, c = idx & 15;
    int e0 = rowptr[n], e1 = rowptr[n + 1];
    float a0 = 0.f, a1 = 0.f, a2 = 0.f, a3 = 0.f;
    int e = e0;
    for (; e + 4 <= e1; e += 4) {
        uint2 u0 = *(const uint2*)(m2g + (size_t)(e + 0) * 64 + 4 * c);
        uint2 u1 = *(const uint2*)(m2g + (size_t)(e + 1) * 64 + 4 * c);
        uint2 u2 = *(const uint2*)(m2g + (size_t)(e + 2) * 64 + 4 * c);
        uint2 u3 = *(const uint2*)(m2g + (size_t)(e + 3) * 64 + 4 * c);
        a0 += (bflo(u0.x) + bflo(u1.x)) + (bflo(u2.x) + bflo(u3.x));
        a1 += (bfhi(u0.x) + bfhi(u1.x)) + (bfhi(u2.x) + bfhi(u3.x));
        a2 += (bflo(u0.y) + bflo(u1.y)) + (bflo(u2.y) + bflo(u3.y));
        a3 += (bfhi(u0.y) + bfhi(u1.y)) + (bfhi(u2.y) + bfhi(u3.y));
    }
    for (; e < e1; ++e) {
        uint2 u = *(const uint2*)(m2g + (size_t)e * 64 + 4 * c);
        a0 += bflo(u.x); a1 += bfhi(u.x);
        a2 += bflo(u.y); a3 += bfhi(u.y);
    }
    *(float4*)(agg + (size_t)64 * n + 4 * c) = make_float4(a0, a1, a2, a3);
}

// ===========================================================================
// Node row-MLP: cats=[h|agg], u=silu(cats@W1+b1), h = u@W2 + b2 + h.
// ===========================================================================
__global__ __launch_bounds__(512, 1) void node_mlp_kernel(
    const float* __restrict__ A, const float* __restrict__ A2,
    const float* __restrict__ w1g, const float* __restrict__ b1g,
    const float* __restrict__ w2g, const float* __restrict__ b2g,
    float* __restrict__ outp, int nrows, int ntiles)
{
    extern __shared__ float lds[];
    float* ws1  = lds;
    float* ws2  = ws1 + 8192;
    float* wb1  = ws2 + 4096;
    float* wb2  = wb1 + 64;
    float* cats = wb2 + 64;
    float* m1s  = cats + 128 * 132;

    const int tid = threadIdx.x;
    const int tr  = tid & 31;
    const int tc  = tid >> 5;

    for (int i = tid; i < 2048; i += 512)
        *(float4*)&ws1[4 * i] = *(const float4*)&w1g[4 * i];
    for (int i = tid; i < 1024; i += 512)
        *(float4*)&ws2[4 * i] = *(const float4*)&w2g[4 * i];
    if (tid < 64) { wb1[tid] = b1g[tid]; wb2[tid] = b2g[tid]; }

    for (int tile = blockIdx.x; tile < ntiles; tile += gridDim.x) {
        const int base = tile * 128;
        __syncthreads();
#pragma unroll
        for (int rep = 0; rep < 8; ++rep) {
            int idx = rep * 512 + tid;
            int r = idx >> 5, q = idx & 31;
            int n = base + r;
            float4 v = make_float4(0.f, 0.f, 0.f, 0.f);
            if (n < nrows)
                v = (q < 16) ? *(const float4*)(A + 64 * n + 4 * q)
                             : *(const float4*)(A2 + 64 * n + 4 * (q - 16));
            *(float4*)&cats[r * 132 + 4 * q] = v;
        }
        __syncthreads();
        float acc[4][4];
#pragma unroll
        for (int jj = 0; jj < 4; ++jj)
#pragma unroll
            for (int ii = 0; ii < 4; ++ii) acc[jj][ii] = wb1[4 * tc + ii];
#pragma unroll 4
        for (int k16 = 0; k16 < 32; ++k16) {
            float4 bv0 = *(const float4*)&ws1[(4 * k16 + 0) * 64 + 4 * tc];
            float4 bv1 = *(const float4*)&ws1[(4 * k16 + 1) * 64 + 4 * tc];
            float4 bv2 = *(const float4*)&ws1[(4 * k16 + 2) * 64 + 4 * tc];
            float4 bv3 = *(const float4*)&ws1[(4 * k16 + 3) * 64 + 4 * tc];
#pragma unroll
            for (int jj = 0; jj < 4; ++jj) {
                float4 av = *(const float4*)&cats[(tr + 32 * jj) * 132 + 4 * k16];
                acc[jj][0] = fmaf(av.x, bv0.x, fmaf(av.y, bv1.x, fmaf(av.z, bv2.x, fmaf(av.w, bv3.x, acc[jj][0]))));
                acc[jj][1] = fmaf(av.x, bv0.y, fmaf(av.y, bv1.y, fmaf(av.z, bv2.y, fmaf(av.w, bv3.y, acc[jj][1]))));
                acc[jj][2] = fmaf(av.x, bv0.z, fmaf(av.y, bv1.z, fmaf(av.z, bv2.z, fmaf(av.w, bv3.z, acc[jj][2]))));
                acc[jj][3] = fmaf(av.x, bv0.w, fmaf(av.y, bv1.w, fmaf(av.z, bv2.w, fmaf(av.w, bv3.w, acc[jj][3]))));
            }
        }
#pragma unroll
        for (int jj = 0; jj < 4; ++jj) {
            float4 v;
            v.x = silu_f(acc[jj][0]); v.y = silu_f(acc[jj][1]);
            v.z = silu_f(acc[jj][2]); v.w = silu_f(acc[jj][3]);
            *(float4*)&m1s[(tr + 32 * jj) * 68 + 4 * tc] = v;
        }
        __syncthreads();
        float acc2[4][4];
#pragma unroll
        for (int jj = 0; jj < 4; ++jj)
#pragma unroll
            for (int ii = 0; ii < 4; ++ii) acc2[jj][ii] = wb2[4 * tc + ii];
#pragma unroll 4
        for (int k16 = 0; k16 < 16; ++k16) {
            float4 bv0 = *(const float4*)&ws2[(4 * k16 + 0) * 64 + 4 * tc];
            float4 bv1 = *(const float4*)&ws2[(4 * k16 + 1) * 64 + 4 * tc];
            float4 bv2 = *(const float4*)&ws2[(4 * k16 + 2) * 64 + 4 * tc];
            float4 bv3 = *(const float4*)&ws2[(4 * k16 + 3) * 64 + 4 * tc];
#pragma unroll
            for (int jj = 0; jj < 4; ++jj) {
                float4 av = *(const float4*)&m1s[(tr + 32 * jj) * 68 + 4 * k16];
                acc2[jj][0] = fmaf(av.x, bv0.x, fmaf(av.y, bv1.x, fmaf(av.z, bv2.x, fmaf(av.w, bv3.x, acc2[jj][0]))));
                acc2[jj][1] = fmaf(av.x, bv0.y, fmaf(av.y, bv1.y, fmaf(av.z, bv2.y, fmaf(av.w, bv3.y, acc2[jj][1]))));
                acc2[jj][2] = fmaf(av.x, bv0.z, fmaf(av.y, bv1.z, fmaf(av.z, bv2.z, fmaf(av.w, bv3.z, acc2[jj][2]))));
                acc2[jj][3] = fmaf(av.x, bv0.w, fmaf(av.y, bv1.w, fmaf(av.z, bv2.w, fmaf(av.w, bv3.w, acc2[jj][3]))));
            }
        }
#pragma unroll
        for (int jj = 0; jj < 4; ++jj) {
            int r = tr + 32 * jj;
            int n = base + r;
            if (n < nrows) {
                float4 hold = *(const float4*)&cats[r * 132 + 4 * tc];
                *(float4*)&outp[64 * n + 4 * tc] = make_float4(
                    acc2[jj][0] + hold.x, acc2[jj][1] + hold.y,
                    acc2[jj][2] + hold.z, acc2[jj][3] + hold.w);
            }
        }
    }
}

// ===========================================================================
// Readout row-MLP (K1=64, segmented scatter into gsum)
// ===========================================================================
__global__ __launch_bounds__(512, 1) void rowmlp_ro_kernel(
    const float* __restrict__ A,
    const float* __restrict__ w1g, const float* __restrict__ b1g,
    const float* __restrict__ w2g, const float* __restrict__ b2g,
    const int* __restrict__ seg, float* __restrict__ outp,
    int nrows, int ntiles)
{
    extern __shared__ float lds[];
    float* ws1  = lds;
    float* ws2  = ws1 + 4096;
    float* wb1  = ws2 + 4096;
    float* wb2  = wb1 + 64;
    float* cats = wb2 + 64;
    float* m1s  = cats + 128 * 68;
    int*   segs = (int*)(m1s + 128 * 68);

    const int tid = threadIdx.x;
    const int tr  = tid & 31;
    const int tc  = tid >> 5;

    for (int i = tid; i < 1024; i += 512) {
        *(float4*)&ws1[4 * i] = *(const float4*)&w1g[4 * i];
        *(float4*)&ws2[4 * i] = *(const float4*)&w2g[4 * i];
    }
    if (tid < 64) { wb1[tid] = b1g[tid]; wb2[tid] = b2g[tid]; }

    for (int tile = blockIdx.x; tile < ntiles; tile += gridDim.x) {
        const int base = tile * 128;
        __syncthreads();
        if (tid < 128) segs[tid] = (base + tid < nrows) ? seg[base + tid] : -1;
#pragma unroll
        for (int rep = 0; rep < 4; ++rep) {
            int idx = rep * 512 + tid;
            int r = idx >> 4, q = idx & 15;
            int n = base + r;
            float4 v = make_float4(0.f, 0.f, 0.f, 0.f);
            if (n < nrows) v = *(const float4*)(A + 64 * n + 4 * q);
            *(float4*)&cats[r * 68 + 4 * q] = v;
        }
        __syncthreads();
        float acc[4][4];
#pragma unroll
        for (int jj = 0; jj < 4; ++jj)
#pragma unroll
            for (int ii = 0; ii < 4; ++ii) acc[jj][ii] = wb1[4 * tc + ii];
#pragma unroll 4
        for (int k16 = 0; k16 < 16; ++k16) {
            float4 bv0 = *(const float4*)&ws1[(4 * k16 + 0) * 64 + 4 * tc];
            float4 bv1 = *(const float4*)&ws1[(4 * k16 + 1) * 64 + 4 * tc];
            float4 bv2 = *(const float4*)&ws1[(4 * k16 + 2) * 64 + 4 * tc];
            float4 bv3 = *(const float4*)&ws1[(4 * k16 + 3) * 64 + 4 * tc];
#pragma unroll
            for (int jj = 0; jj < 4; ++jj) {
                float4 av = *(const float4*)&cats[(tr + 32 * jj) * 68 + 4 * k16];
                acc[jj][0] = fmaf(av.x, bv0.x, fmaf(av.y, bv1.x, fmaf(av.z, bv2.x, fmaf(av.w, bv3.x, acc[jj][0]))));
                acc[jj][1] = fmaf(av.x, bv0.y, fmaf(av.y, bv1.y, fmaf(av.z, bv2.y, fmaf(av.w, bv3.y, acc[jj][1]))));
                acc[jj][2] = fmaf(av.x, bv0.z, fmaf(av.y, bv1.z, fmaf(av.z, bv2.z, fmaf(av.w, bv3.z, acc[jj][2]))));
                acc[jj][3] = fmaf(av.x, bv0.w, fmaf(av.y, bv1.w, fmaf(av.z, bv2.w, fmaf(av.w, bv3.w, acc[jj][3]))));
            }
        }
#pragma unroll
        for (int jj = 0; jj < 4; ++jj) {
            float4 v;
            v.x = silu_f(acc[jj][0]); v.y = silu_f(acc[jj][1]);
            v.z = silu_f(acc[jj][2]); v.w = silu_f(acc[jj][3]);
            *(float4*)&m1s[(tr + 32 * jj) * 68 + 4 * tc] = v;
        }
        __syncthreads();
        float acc2[4][4];
#pragma unroll
        for (int jj = 0; jj < 4; ++jj)
#pragma unroll
            for (int ii = 0; ii < 4; ++ii) acc2[jj][ii] = wb2[4 * tc + ii];
#pragma unroll 4
        for (int k16 = 0; k16 < 16; ++k16) {
            float4 bv0 = *(const float4*)&ws2[(4 * k16 + 0) * 64 + 4 * tc];
            float4 bv1 = *(const float4*)&ws2[(4 * k16 + 1) * 64 + 4 * tc];
            float4 bv2 = *(const float4*)&ws2[(4 * k16 + 2) * 64 + 4 * tc];
            float4 bv3 = *(const float4*)&ws2[(4 * k16 + 3) * 64 + 4 * tc];
#pragma unroll
            for (int jj = 0; jj < 4; ++jj) {
                float4 av = *(const float4*)&m1s[(tr + 32 * jj) * 68 + 4 * k16];
                acc2[jj][0] = fmaf(av.x, bv0.x, fmaf(av.y, bv1.x, fmaf(av.z, bv2.x, fmaf(av.w, bv3.x, acc2[jj][0]))));
                acc2[jj][1] = fmaf(av.x, bv0.y, fmaf(av.y, bv1.y, fmaf(av.z, bv2.y, fmaf(av.w, bv3.y, acc2[jj][1]))));
                acc2[jj][2] = fmaf(av.x, bv0.z, fmaf(av.y, bv1.z, fmaf(av.z, bv2.z, fmaf(av.w, bv3.z, acc2[jj][2]))));
                acc2[jj][3] = fmaf(av.x, bv0.w, fmaf(av.y, bv1.w, fmaf(av.z, bv2.w, fmaf(av.w, bv3.w, acc2[jj][3]))));
            }
        }
#pragma unroll
        for (int jj = 0; jj < 4; ++jj) {
            int r = tr + 32 * jj;
            int n = base + r;
            int gid = segs[r];
            float4 vv = (n < nrows) ? make_float4(acc2[jj][0], acc2[jj][1], acc2[jj][2], acc2[jj][3])
                                    : make_float4(0.f, 0.f, 0.f, 0.f);
            unsigned f = (tr == 0 || segs[(r > 0) ? r - 1 : 0] != gid) ? 1u : 0u;
#pragma unroll
            for (int s = 1; s < 32; s <<= 1) {
                float ux = __shfl_up(vv.x, s, 32);
                float uy = __shfl_up(vv.y, s, 32);
                float uz = __shfl_up(vv.z, s, 32);
                float uw = __shfl_up(vv.w, s, 32);
                unsigned uf = __shfl_up(f, s, 32);
                if (tr >= s) {
                    if (!f) { vv.x += ux; vv.y += uy; vv.z += uz; vv.w += uw; }
                    f |= uf;
                }
            }
            bool tail = (tr == 31) || (segs[r + 1] != gid);
            if (tail && gid >= 0) {
                float* bp = outp + 64 * gid + 4 * tc;
                atomicAdd(bp + 0, vv.x); atomicAdd(bp + 1, vv.y);
                atomicAdd(bp + 2, vv.z); atomicAdd(bp + 3, vv.w);
            }
        }
    }
}

__global__ __launch_bounds__(256) void proj_kernel(
    const float* __restrict__ x, const float* __restrict__ w,
    const float* __restrict__ b, float* __restrict__ h, int n)
{
    int i = blockIdx.x * 256 + threadIdx.x;
    if (i >= n * 64) return;
    int node = i >> 6, j = i & 63;
    const float* xr = x + node * 14;
    float acc = b[j];
#pragma unroll
    for (int k = 0; k < 14; ++k) acc = fmaf(xr[k], w[k * 64 + j], acc);
    h[i] = acc;
}

__global__ __launch_bounds__(256) void head_kernel(
    const float* __restrict__ gsum,
    const float* __restrict__ w3, const float* __restrict__ b3,
    const float* __restrict__ w4, const float* __restrict__ b4,
    float* __restrict__ out, int g_count)
{
    int wid  = (blockIdx.x * 256 + threadIdx.x) >> 6;
    int lane = threadIdx.x & 63;
    if (wid >= g_count) return;
    float v = gsum[wid * 64 + lane];
    float t = b3[lane];
#pragma unroll
    for (int k = 0; k < 64; ++k) {
        float a = __shfl(v, k, 64);
        t = fmaf(a, w3[k * 64 + lane], t);
    }
    t = silu_f(t);
    float r = t * w4[lane];
#pragma unroll
    for (int off = 32; off; off >>= 1) r += __shfl_down(r, off, 64);
    if (lane == 0) out[wid] = r + b4[0];
}

extern "C" void kernel_launch(void* const* d_in, const int* in_sizes, int n_in,
                              void* d_out, int out_size, void* d_ws, size_t ws_size,
                              hipStream_t stream)
{
    const float* x      = (const float*)d_in[0];
    const int*   ei     = (const int*)d_in[2];
    const int*   batch  = (const int*)d_in[3];
    const float* proj_w = (const float*)d_in[4];
    const float* proj_b = (const float*)d_in[5];
    const float* ew1 = (const float*)d_in[6];
    const float* eb1 = (const float*)d_in[7];
    const float* ew2 = (const float*)d_in[8];
    const float* eb2 = (const float*)d_in[9];
    const float* nw1 = (const float*)d_in[10];
    const float* nb1 = (const float*)d_in[11];
    const float* nw2 = (const float*)d_in[12];
    const float* nb2 = (const float*)d_in[13];
    const float* l1w = (const float*)d_in[14]; const float* l1b = (const float*)d_in[15];
    const float* l2w = (const float*)d_in[16]; const float* l2b = (const float*)d_in[17];
    const float* l3w = (const float*)d_in[18]; const float* l3b = (const float*)d_in[19];
    const float* l4w = (const float*)d_in[20]; const float* l4b = (const float*)d_in[21];

    float* out  = (float*)d_out;
    float* h    = out + GG;                      // per_atom_out doubles as h

    unsigned short* m2g = (unsigned short*)d_ws;             // [E,64] bf16 = 102.4MB
    float* gsum = (float*)(m2g + (size_t)EE * 64);           // [G,64]
    float* Pt   = gsum + (size_t)GG * 64;                    // [N,64] f32
    unsigned short* Pbu = (unsigned short*)(Pt + (size_t)NN * 64);  // [N,64] bf16
    int* deg8    = (int*)(Pbu + (size_t)NN * 64);            // [8][N]
    int* rowptr  = deg8 + 8 * NN;                            // N+1
    int* cursor8 = rowptr + NN + 1;                          // [8][N]
    int2* epair  = (int2*)(((uintptr_t)(cursor8 + 8 * NN) + 15) & ~(uintptr_t)15);  // [E]
    int* bsum    = (int*)(epair + EE);                       // [98]
    float* agg   = Pt;  // alias: Pt dead after edge_kernel, rebuilt next layer

    const size_t edge_lds = 8192 + 16384 + 256 + 256;                 // 25088
    const size_t pk_lds   = 16384 + 16384 + 34816;                    // 67584
    const size_t node_lds = (size_t)(8192 + 4096 + 128 + 128 * 132 + 128 * 68) * 4;
    const size_t ro_lds   = (size_t)(4096 + 4096 + 128 + 128 * 68 + 128 * 68) * 4 + 128 * 4;

    (void)hipFuncSetAttribute((const void*)edge_kernel,
                              hipFuncAttributeMaxDynamicSharedMemorySize, (int)edge_lds);
    (void)hipFuncSetAttribute((const void*)pk_kernel,
                              hipFuncAttributeMaxDynamicSharedMemorySize, (int)pk_lds);
    (void)hipFuncSetAttribute((const void*)node_mlp_kernel,
                              hipFuncAttributeMaxDynamicSharedMemorySize, (int)node_lds);
    (void)hipFuncSetAttribute((const void*)rowmlp_ro_kernel,
                              hipFuncAttributeMaxDynamicSharedMemorySize, (int)ro_lds);

    // --- CSR build (8-way sharded, dst-sorted packed edge list) ---
    const int nb = (NN + 511) / 512;           // 98
    hipMemsetAsync(deg8, 0, (size_t)8 * NN * sizeof(int), stream);
    hipMemsetAsync(gsum, 0, (size_t)GG * 64 * sizeof(float), stream);
    hist_kernel<<<(EE + 255) / 256, 256, 0, stream>>>(ei, deg8);
    scanA_kernel<<<nb, 512, 0, stream>>>(deg8, rowptr, bsum);
    scanB_kernel<<<1, 128, 0, stream>>>(bsum, nb);
    scanC_kernel<<<nb, 512, 0, stream>>>(rowptr, cursor8, deg8, bsum);
    scatter_kernel<<<(EE + 255) / 256, 256, 0, stream>>>(ei, cursor8, epair);

    proj_kernel<<<(NN * 64 + 255) / 256, 256, 0, stream>>>(x, proj_w, proj_b, h, NN);

    const int etiles = EE / 128;               // 6250 (exact)
    const int ntiles = (NN + 127) / 128;       // 391
    for (int l = 0; l < LL; ++l) {
        pk_kernel<<<ntiles, 512, pk_lds, stream>>>(h, ew1 + l * 8192, Pt, Pbu, ntiles);
        edge_kernel<<<1024, 512, edge_lds, stream>>>(
            Pt, Pbu, epair, eb1 + l * 64, ew2 + l * 4096, eb2 + l * 64,
            m2g, etiles);
        agg_kernel<<<(NN * 16 + 255) / 256, 256, 0, stream>>>(m2g, rowptr, agg);
        node_mlp_kernel<<<196, 512, node_lds, stream>>>(
            h, agg, nw1 + l * 8192, nb1 + l * 64, nw2 + l * 4096, nb2 + l * 64,
            h, NN, ntiles);
    }
    rowmlp_ro_kernel<<<196, 512, ro_lds, stream>>>(
        h, l1w, l1b, l2w, l2b, batch, gsum, NN, ntiles);
    head_kernel<<<GG / 4, 256, 0, stream>>>(gsum, l3w, l3b, l4w, l4b, out, GG);
}

// Round 22
// 425.403 us; speedup vs baseline: 1.6909x; 1.0921x over previous
//
#include <hip/hip_runtime.h>

#define NN 50000
#define EE 800000
#define GG 512
#define LL 3

typedef short bf16x8 __attribute__((ext_vector_type(8)));
typedef float f32x4  __attribute__((ext_vector_type(4)));

__device__ __forceinline__ float silu_f(float x) {
    return x * __builtin_amdgcn_rcpf(1.0f + __expf(-x));
}
__device__ __forceinline__ unsigned short bf16_rne(float x) {
    unsigned u = __float_as_uint(x);
    u += 0x7fffu + ((u >> 16) & 1u);
    return (unsigned short)(u >> 16);
}
__device__ __forceinline__ float bflo(unsigned u) { return __uint_as_float(u << 16); }
__device__ __forceinline__ float bfhi(unsigned u) { return __uint_as_float(u & 0xffff0000u); }
__device__ __forceinline__ f32x4 mfma16(bf16x8 a, bf16x8 b, f32x4 c) {
    return __builtin_amdgcn_mfma_f32_16x16x32_bf16(a, b, c, 0, 0, 0);
}
// lgkm-only barrier: drains LDS ops, leaves global loads/stores in flight.
__device__ __forceinline__ void barrier_lgkm() {
    asm volatile("s_waitcnt lgkmcnt(0)" ::: "memory");
    __builtin_amdgcn_s_barrier();
}

// ===========================================================================
// CSR build: 8-way sharded histogram -> hierarchical scan -> sharded scatter.
// ===========================================================================
__global__ __launch_bounds__(256) void hist_kernel(const int* __restrict__ ei,
                                                   int* __restrict__ deg8) {
    int e = blockIdx.x * 256 + threadIdx.x;
    if (e < EE) atomicAdd(&deg8[(e & 7) * NN + ei[EE + e]], 1);
}

__global__ __launch_bounds__(512) void scanA_kernel(const int* __restrict__ deg8,
                                                    int* __restrict__ rowptr,
                                                    int* __restrict__ bsum) {
    __shared__ int wsum[8];
    const int tid = threadIdx.x, b = blockIdx.x;
    int i = b * 512 + tid;
    int v = 0;
    if (i < NN) {
#pragma unroll
        for (int s = 0; s < 8; ++s) v += deg8[s * NN + i];
    }
    int lane = tid & 63, wid = tid >> 6;
    int x = v;
#pragma unroll
    for (int s = 1; s < 64; s <<= 1) {
        int u = __shfl_up(x, s, 64);
        if (lane >= s) x += u;
    }
    if (lane == 63) wsum[wid] = x;
    __syncthreads();
    int woff = 0;
    for (int w = 0; w < wid; ++w) woff += wsum[w];
    if (i < NN) rowptr[i] = woff + x - v;
    if (tid == 511) bsum[b] = woff + x;
}

__global__ __launch_bounds__(128) void scanB_kernel(int* __restrict__ bsum, int nb) {
    __shared__ int wsum[2];
    const int tid = threadIdx.x;
    int v = (tid < nb) ? bsum[tid] : 0;
    int lane = tid & 63, wid = tid >> 6;
    int x = v;
#pragma unroll
    for (int s = 1; s < 64; s <<= 1) {
        int u = __shfl_up(x, s, 64);
        if (lane >= s) x += u;
    }
    if (lane == 63) wsum[wid] = x;
    __syncthreads();
    int woff = (wid == 1) ? wsum[0] : 0;
    if (tid < nb) bsum[tid] = woff + x - v;
}

__global__ __launch_bounds__(512) void scanC_kernel(int* __restrict__ rowptr,
                                                    int* __restrict__ cursor8,
                                                    const int* __restrict__ deg8,
                                                    const int* __restrict__ bsum) {
    const int tid = threadIdx.x, b = blockIdx.x;
    int i = b * 512 + tid;
    if (i < NN) {
        int r = rowptr[i] + bsum[b];
        rowptr[i] = r;
        int running = r;
#pragma unroll
        for (int s = 0; s < 8; ++s) {
            cursor8[s * NN + i] = running;
            running += deg8[s * NN + i];
        }
    }
    if (i == 0) rowptr[NN] = EE;
}

__global__ __launch_bounds__(256) void scatter_kernel(const int* __restrict__ ei,
                                                      int* __restrict__ cursor8,
                                                      int2* __restrict__ epair) {
    int e = blockIdx.x * 256 + threadIdx.x;
    if (e < EE) {
        int d = ei[EE + e];
        int pos = atomicAdd(&cursor8[(e & 7) * NN + d], 1);
        epair[pos] = make_int2(ei[e], d);   // (src, dst)
    }
}

// ===========================================================================
// pk_kernel (MFMA) — round-19 proven (cols 0-63 -> Pt f32, 64-127 -> Pb bf16)
// ===========================================================================
__global__ __launch_bounds__(512, 2) void pk_kernel(
    const float* __restrict__ h, const float* __restrict__ w1g,
    float* __restrict__ Pt, unsigned short* __restrict__ Pbu, int ntiles)
{
    extern __shared__ __align__(16) char smem[];
    char*  hb = smem;                    // [128r][128B] swz : 16384
    char*  wt = hb + 16384;              // [128c][128B] swz : 16384
    float* tp = (float*)(wt + 16384);    // [128][68] f32   : 34816

    const int tid = threadIdx.x;
    const int l   = tid & 63;
    const int w   = tid >> 6;
    const int mi  = w >> 1;
    const int ni  = w & 1;
    const int l15 = l & 15;
    const int l4  = l >> 4;
    const int sw  = (l15 & 7) << 4;

    {
        int c = tid >> 2, kq0 = tid & 3;
#pragma unroll
        for (int hf = 0; hf < 2; ++hf) {
            int kq = kq0 + 4 * hf;
            const float* wp = w1g + (size_t)((c >> 6) * 64 + kq * 8) * 64 + (c & 63);
            bf16x8 bv;
#pragma unroll
            for (int j = 0; j < 8; ++j) bv[j] = (short)bf16_rne(wp[j * 64]);
            *(bf16x8*)(wt + c * 128 + ((kq * 16) ^ ((c & 7) << 4))) = bv;
        }
    }

    for (int tile = blockIdx.x; tile < ntiles; tile += gridDim.x) {
        const int base = tile * 128;
        __syncthreads();
        {
            int r = tid >> 2, q = tid & 3;
            int n = base + r;
            float v[16];
#pragma unroll
            for (int j = 0; j < 16; ++j) v[j] = 0.f;
            if (n < NN) {
                const float* hp = h + (size_t)64 * n + q * 16;
#pragma unroll
                for (int j = 0; j < 4; ++j) {
                    float4 t = *(const float4*)(hp + 4 * j);
                    v[4 * j] = t.x; v[4 * j + 1] = t.y;
                    v[4 * j + 2] = t.z; v[4 * j + 3] = t.w;
                }
            }
            bf16x8 b0, b1;
#pragma unroll
            for (int j = 0; j < 8; ++j) {
                b0[j] = (short)bf16_rne(v[j]);
                b1[j] = (short)bf16_rne(v[8 + j]);
            }
            int swr = (r & 7) << 4;
            *(bf16x8*)(hb + r * 128 + ((q * 32) ^ swr))      = b0;
            *(bf16x8*)(hb + r * 128 + ((q * 32 + 16) ^ swr)) = b1;
        }
        __syncthreads();
        f32x4 acc[2][4];
#pragma unroll
        for (int m = 0; m < 2; ++m)
#pragma unroll
            for (int n = 0; n < 4; ++n) acc[m][n] = (f32x4){0.f, 0.f, 0.f, 0.f};
#pragma unroll
        for (int ks = 0; ks < 2; ++ks) {
            int kb = ks * 64 + l4 * 16;
            bf16x8 af[2], bf[4];
#pragma unroll
            for (int m = 0; m < 2; ++m)
                af[m] = *(const bf16x8*)(hb + (32 * mi + 16 * m + l15) * 128 + (kb ^ sw));
#pragma unroll
            for (int n = 0; n < 4; ++n)
                bf[n] = *(const bf16x8*)(wt + (64 * ni + 16 * n + l15) * 128 + (kb ^ sw));
#pragma unroll
            for (int m = 0; m < 2; ++m)
#pragma unroll
                for (int n = 0; n < 4; ++n)
                    acc[m][n] = mfma16(af[m], bf[n], acc[m][n]);
        }
        __syncthreads();
        if (ni == 0) {
#pragma unroll
            for (int m = 0; m < 2; ++m)
#pragma unroll
                for (int n = 0; n < 4; ++n)
#pragma unroll
                    for (int r = 0; r < 4; ++r)
                        tp[(32 * mi + 16 * m + l4 * 4 + r) * 68 + 16 * n + l15] =
                            acc[m][n][r];
        }
        __syncthreads();
        {
            int r = tid >> 2, q = tid & 3;
            int n = base + r;
            if (n < NN) {
                float* op = Pt + (size_t)64 * n + q * 16;
#pragma unroll
                for (int j = 0; j < 4; ++j)
                    *(float4*)(op + 4 * j) = *(const float4*)&tp[r * 68 + q * 16 + 4 * j];
            }
        }
        __syncthreads();
        if (ni == 1) {
#pragma unroll
            for (int m = 0; m < 2; ++m)
#pragma unroll
                for (int n = 0; n < 4; ++n)
#pragma unroll
                    for (int r = 0; r < 4; ++r)
                        tp[(32 * mi + 16 * m + l4 * 4 + r) * 68 + 16 * n + l15] =
                            acc[m][n][r];
        }
        __syncthreads();
        {
            int r = tid >> 2, q = tid & 3;
            int n = base + r;
            if (n < NN) {
                unsigned uu[8];
#pragma unroll
                for (int j = 0; j < 8; ++j) {
                    float lo = tp[r * 68 + q * 16 + 2 * j];
                    float hi = tp[r * 68 + q * 16 + 2 * j + 1];
                    uu[j] = ((unsigned)bf16_rne(hi) << 16) | bf16_rne(lo);
                }
                uint4* op = (uint4*)(Pbu + (size_t)64 * n + q * 16);
                op[0] = make_uint4(uu[0], uu[1], uu[2], uu[3]);
                op[1] = make_uint4(uu[4], uu[5], uu[6], uu[7]);
            }
        }
    }
}

// ===========================================================================
// Edge kernel — round-14/17 structure; packed int2 IDX. UNCHANGED.
// ===========================================================================
__global__ __launch_bounds__(512, 6) void edge_kernel(
    const float* __restrict__ Pt, const unsigned short* __restrict__ Pbu,
    const int2* __restrict__ epair,
    const float* __restrict__ b1g,
    const float* __restrict__ w2g, const float* __restrict__ b2g,
    unsigned short* __restrict__ m2g, int ntiles)
{
    extern __shared__ __align__(16) char smem[];
    char*  wt2s = smem;                       // [64c][128B] swz   8192
    char*  m1s  = wt2s + 8192;                // [128r][128B] swz 16384
    float* b1s  = (float*)(m1s + 16384);      // 64 f32
    float* b2s  = b1s + 64;                   // 64 f32

    const int tid = threadIdx.x;
    const int l   = tid & 63;
    const int w   = tid >> 6;
    const int mi  = w >> 1;
    const int ni  = w & 1;
    const int l15 = l & 15;
    const int l4  = l >> 4;
    const int g7  = tid & 7;

    {
        int c = tid >> 3, kc = tid & 7;
        const float* wp = w2g + (kc * 8) * 64 + c;
        bf16x8 bv;
#pragma unroll
        for (int j = 0; j < 8; ++j) bv[j] = (short)bf16_rne(wp[j * 64]);
        *(bf16x8*)(wt2s + c * 128 + ((kc * 16) ^ ((c & 7) << 4))) = bv;
    }
    if (tid < 64) { b1s[tid] = b1g[tid]; b2s[tid] = b2g[tid]; }

    int    ix_d[2], ix_s[2];
    float4 pf_a0[2], pf_a1[2];
    uint4  pf_pb[2];

    auto IDX = [&](int tt) {
        int eb = tt * 128;
#pragma unroll
        for (int it = 0; it < 2; ++it) {
            int e = (it * 512 + tid) >> 3;
            int2 p = epair[eb + e];
            ix_s[it] = p.x;
            ix_d[it] = p.y;
        }
    };
    auto DATA = [&]() {
#pragma unroll
        for (int it = 0; it < 2; ++it) {
            const float* pt = Pt + (size_t)64 * ix_d[it] + 8 * g7;
            pf_a0[it] = *(const float4*)pt;
            pf_a1[it] = *(const float4*)(pt + 4);
            pf_pb[it] = *(const uint4*)(Pbu + (size_t)64 * ix_s[it] + 8 * g7);
        }
    };

    int tile = blockIdx.x;
    if (tile < ntiles) { IDX(tile); DATA(); }
    if (tile + gridDim.x < ntiles) IDX(tile + gridDim.x);
    barrier_lgkm();

    for (; tile < ntiles; tile += gridDim.x) {
#pragma unroll
        for (int it = 0; it < 2; ++it) {
            int e = (it * 512 + tid) >> 3;
            float4 b0  = *(const float4*)(b1s + 8 * g7);
            float4 b1v = *(const float4*)(b1s + 8 * g7 + 4);
            float v0 = silu_f(pf_a0[it].x + bflo(pf_pb[it].x) + b0.x);
            float v1 = silu_f(pf_a0[it].y + bfhi(pf_pb[it].x) + b0.y);
            float v2 = silu_f(pf_a0[it].z + bflo(pf_pb[it].y) + b0.z);
            float v3 = silu_f(pf_a0[it].w + bfhi(pf_pb[it].y) + b0.w);
            float v4 = silu_f(pf_a1[it].x + bflo(pf_pb[it].z) + b1v.x);
            float v5 = silu_f(pf_a1[it].y + bfhi(pf_pb[it].z) + b1v.y);
            float v6 = silu_f(pf_a1[it].z + bflo(pf_pb[it].w) + b1v.z);
            float v7 = silu_f(pf_a1[it].w + bfhi(pf_pb[it].w) + b1v.w);
            uint4 o;
            o.x = ((unsigned)bf16_rne(v1) << 16) | bf16_rne(v0);
            o.y = ((unsigned)bf16_rne(v3) << 16) | bf16_rne(v2);
            o.z = ((unsigned)bf16_rne(v5) << 16) | bf16_rne(v4);
            o.w = ((unsigned)bf16_rne(v7) << 16) | bf16_rne(v6);
            *(uint4*)(m1s + e * 128 + ((g7 * 16) ^ ((e & 7) << 4))) = o;
        }
        barrier_lgkm();                           // B1: m1s ready
        int nxt = tile + gridDim.x;
        if (nxt < ntiles) {
            DATA();
            if (nxt + gridDim.x < ntiles) IDX(nxt + gridDim.x);
        }
        f32x4 acc2[2][2];
#pragma unroll
        for (int m = 0; m < 2; ++m)
#pragma unroll
            for (int n = 0; n < 2; ++n) {
                float b = b2s[32 * ni + 16 * n + l15];
                acc2[m][n] = (f32x4){b, b, b, b};
            }
        const int sw = (l15 & 7) << 4;
#pragma unroll
        for (int ks = 0; ks < 2; ++ks) {
            int kb = ks * 64 + l4 * 16;
            bf16x8 af[2], bfr[2];
#pragma unroll
            for (int m = 0; m < 2; ++m)
                af[m] = *(const bf16x8*)(m1s + (32 * mi + 16 * m + l15) * 128 + (kb ^ sw));
#pragma unroll
            for (int n = 0; n < 2; ++n)
                bfr[n] = *(const bf16x8*)(wt2s + (32 * ni + 16 * n + l15) * 128 + (kb ^ sw));
#pragma unroll
            for (int m = 0; m < 2; ++m)
#pragma unroll
                for (int n = 0; n < 2; ++n)
                    acc2[m][n] = mfma16(af[m], bfr[n], acc2[m][n]);
        }
        unsigned short* mg = m2g + (size_t)(tile * 128) * 64;
#pragma unroll
        for (int m = 0; m < 2; ++m)
#pragma unroll
            for (int n = 0; n < 2; ++n)
#pragma unroll
                for (int r = 0; r < 4; ++r) {
                    int row = 32 * mi + 16 * m + l4 * 4 + r;
                    int col = 32 * ni + 16 * n + l15;
                    mg[row * 64 + col] = bf16_rne(silu_f(acc2[m][n][r]));
                }
        barrier_lgkm();                           // B2
    }
}

// ===========================================================================
// agg_kernel: agg[n] = sum of contiguous m2g rows (CSR). Thread = (node, 4 cols).
// ===========================================================================
__global__ __launch_bounds__(256) void agg_kernel(
    const unsigned short* __restrict__ m2g, const int* __restrict__ rowptr,
    float* __restrict__ agg)
{
    int idx = blockIdx.x * 256 + threadIdx.x;
    if (idx >= NN * 16) return;
    int n = idx >> 4, c = idx & 15;
    int e0 = rowptr[n], e1 = rowptr[n + 1];
    float a0 = 0.f, a1 = 0.f, a2 = 0.f, a3 = 0.f;
    int e = e0;
    for (; e + 4 <= e1; e += 4) {
        uint2 u0 = *(const uint2*)(m2g + (size_t)(e + 0) * 64 + 4 * c);
        uint2 u1 = *(const uint2*)(m2g + (size_t)(e + 1) * 64 + 4 * c);
        uint2 u2 = *(const uint2*)(m2g + (size_t)(e + 2) * 64 + 4 * c);
        uint2 u3 = *(const uint2*)(m2g + (size_t)(e + 3) * 64 + 4 * c);
        a0 += (bflo(u0.x) + bflo(u1.x)) + (bflo(u2.x) + bflo(u3.x));
        a1 += (bfhi(u0.x) + bfhi(u1.x)) + (bfhi(u2.x) + bfhi(u3.x));
        a2 += (bflo(u0.y) + bflo(u1.y)) + (bflo(u2.y) + bflo(u3.y));
        a3 += (bfhi(u0.y) + bfhi(u1.y)) + (bfhi(u2.y) + bfhi(u3.y));
    }
    for (; e < e1; ++e) {
        uint2 u = *(const uint2*)(m2g + (size_t)e * 64 + 4 * c);
        a0 += bflo(u.x); a1 += bfhi(u.x);
        a2 += bflo(u.y); a3 += bfhi(u.y);
    }
    *(float4*)(agg + (size_t)64 * n + 4 * c) = make_float4(a0, a1, a2, a3);
}

// ===========================================================================
// node_mfma_kernel: h = silu([h|agg] @ W1 + b1) @ W2 + b2 + h (residual f32).
// Stage1 K=128 split into two proven K=64 halves (hbA=h, hbB=agg; wtA/wtB).
// Stage2 = edge's exact m1s@wt2 MFMA block. Epilogue via tp f32 -> coalesced.
// LDS 109KB -> 1 block/CU, 8 waves.
// ===========================================================================
__global__ __launch_bounds__(512, 1) void node_mfma_kernel(
    const float* __restrict__ h, const float* __restrict__ agg,
    const float* __restrict__ w1g, const float* __restrict__ b1g,
    const float* __restrict__ w2g, const float* __restrict__ b2g,
    float* __restrict__ outp, int ntiles)
{
    extern __shared__ __align__(16) char smem[];
    char*  hbA = smem;                    // [128r][128B] swz : 16384 (k 0-63 = h)
    char*  hbB = hbA + 16384;             // [128r][128B] swz : 16384 (k 64-127 = agg)
    char*  wtA = hbB + 16384;             // [64c][128B] swz  :  8192 (W1 k 0-63)
    char*  wtB = wtA + 8192;              // [64c][128B] swz  :  8192 (W1 k 64-127)
    char*  wt2 = wtB + 8192;              // [64c][128B] swz  :  8192 (W2)
    char*  m1s = wt2 + 8192;              // [128r][128B] swz : 16384 (bf16 m1)
    float* tp  = (float*)(m1s + 16384);   // [128][68] f32    : 34816
    float* b1s = (float*)((char*)tp + 34816);  // 64
    float* b2s = b1s + 64;                     // 64

    const int tid = threadIdx.x;
    const int l   = tid & 63;
    const int w   = tid >> 6;
    const int mi  = w >> 1;               // row block 32*mi
    const int ni  = w & 1;                // col block 32*ni
    const int l15 = l & 15;
    const int l4  = l >> 4;
    const int sw  = (l15 & 7) << 4;

    // stage weights once: c = tid>>3 (0..63), kc = tid&7 (covers 512 chunks each)
    {
        int c = tid >> 3, kc = tid & 7;
        const float* wpA = w1g + (kc * 8) * 64 + c;          // W1[k][c], k=kc*8..+7
        const float* wpB = w1g + (64 + kc * 8) * 64 + c;     // k=64+...
        const float* wp2 = w2g + (kc * 8) * 64 + c;
        bf16x8 bA, bB, b2v;
#pragma unroll
        for (int j = 0; j < 8; ++j) {
            bA[j]  = (short)bf16_rne(wpA[j * 64]);
            bB[j]  = (short)bf16_rne(wpB[j * 64]);
            b2v[j] = (short)bf16_rne(wp2[j * 64]);
        }
        int off = c * 128 + ((kc * 16) ^ ((c & 7) << 4));
        *(bf16x8*)(wtA + off) = bA;
        *(bf16x8*)(wtB + off) = bB;
        *(bf16x8*)(wt2 + off) = b2v;
    }
    if (tid < 64) { b1s[tid] = b1g[tid]; b2s[tid] = b2g[tid]; }

    for (int tile = blockIdx.x; tile < ntiles; tile += gridDim.x) {
        const int base = tile * 128;
        __syncthreads();                  // B0: prev tp reads done; weights ready
        // ---- stage h -> hbA, agg -> hbB (pk-proven pattern x2) ----
        {
            int r = tid >> 2, q = tid & 3;
            int n = base + r;
            int swr = (r & 7) << 4;
#pragma unroll
            for (int srcsel = 0; srcsel < 2; ++srcsel) {
                const float* src = srcsel ? agg : h;
                char* dst = srcsel ? hbB : hbA;
                float v[16];
#pragma unroll
                for (int j = 0; j < 16; ++j) v[j] = 0.f;
                if (n < NN) {
                    const float* hp = src + (size_t)64 * n + q * 16;
#pragma unroll
                    for (int j = 0; j < 4; ++j) {
                        float4 t = *(const float4*)(hp + 4 * j);
                        v[4 * j] = t.x; v[4 * j + 1] = t.y;
                        v[4 * j + 2] = t.z; v[4 * j + 3] = t.w;
                    }
                }
                bf16x8 c0, c1;
#pragma unroll
                for (int j = 0; j < 8; ++j) {
                    c0[j] = (short)bf16_rne(v[j]);
                    c1[j] = (short)bf16_rne(v[8 + j]);
                }
                *(bf16x8*)(dst + r * 128 + ((q * 32) ^ swr))      = c0;
                *(bf16x8*)(dst + r * 128 + ((q * 32 + 16) ^ swr)) = c1;
            }
        }
        __syncthreads();                  // B1: hbA/hbB ready
        // ---- stage 1: [h|agg] @ W1 (K=128 as two K=64 halves) ----
        f32x4 acc[2][2];
#pragma unroll
        for (int m = 0; m < 2; ++m)
#pragma unroll
            for (int n = 0; n < 2; ++n) {
                float b = b1s[32 * ni + 16 * n + l15];
                acc[m][n] = (f32x4){b, b, b, b};
            }
#pragma unroll
        for (int half = 0; half < 2; ++half) {
            const char* hb = half ? hbB : hbA;
            const char* wt = half ? wtB : wtA;
#pragma unroll
            for (int ks = 0; ks < 2; ++ks) {
                int kb = ks * 64 + l4 * 16;
                bf16x8 af[2], bf[2];
#pragma unroll
                for (int m = 0; m < 2; ++m)
                    af[m] = *(const bf16x8*)(hb + (32 * mi + 16 * m + l15) * 128 + (kb ^ sw));
#pragma unroll
                for (int n = 0; n < 2; ++n)
                    bf[n] = *(const bf16x8*)(wt + (32 * ni + 16 * n + l15) * 128 + (kb ^ sw));
#pragma unroll
                for (int m = 0; m < 2; ++m)
#pragma unroll
                    for (int n = 0; n < 2; ++n)
                        acc[m][n] = mfma16(af[m], bf[n], acc[m][n]);
            }
        }
        // m1 = silu -> bf16 swizzled LDS (fragment scatter, 2B writes)
#pragma unroll
        for (int m = 0; m < 2; ++m)
#pragma unroll
            for (int n = 0; n < 2; ++n)
#pragma unroll
                for (int r = 0; r < 4; ++r) {
                    int row = 32 * mi + 16 * m + l4 * 4 + r;
                    int col = 32 * ni + 16 * n + l15;
                    *(unsigned short*)(m1s + row * 128 + ((col * 2) ^ ((row & 7) << 4))) =
                        bf16_rne(silu_f(acc[m][n][r]));
                }
        __syncthreads();                  // B2: m1s ready
        // ---- stage 2: m1 @ W2 (edge's exact block) ----
        f32x4 acc2[2][2];
#pragma unroll
        for (int m = 0; m < 2; ++m)
#pragma unroll
            for (int n = 0; n < 2; ++n) {
                float b = b2s[32 * ni + 16 * n + l15];
                acc2[m][n] = (f32x4){b, b, b, b};
            }
#pragma unroll
        for (int ks = 0; ks < 2; ++ks) {
            int kb = ks * 64 + l4 * 16;
            bf16x8 af[2], bfr[2];
#pragma unroll
            for (int m = 0; m < 2; ++m)
                af[m] = *(const bf16x8*)(m1s + (32 * mi + 16 * m + l15) * 128 + (kb ^ sw));
#pragma unroll
            for (int n = 0; n < 2; ++n)
                bfr[n] = *(const bf16x8*)(wt2 + (32 * ni + 16 * n + l15) * 128 + (kb ^ sw));
#pragma unroll
            for (int m = 0; m < 2; ++m)
#pragma unroll
                for (int n = 0; n < 2; ++n)
                    acc2[m][n] = mfma16(af[m], bfr[n], acc2[m][n]);
        }
        // fragments -> tp f32
#pragma unroll
        for (int m = 0; m < 2; ++m)
#pragma unroll
            for (int n = 0; n < 2; ++n)
#pragma unroll
                for (int r = 0; r < 4; ++r)
                    tp[(32 * mi + 16 * m + l4 * 4 + r) * 68 + 32 * ni + 16 * n + l15] =
                        acc2[m][n][r];
        __syncthreads();                  // B3: tp ready
        // epilogue: out = tp + h (residual f32-exact), coalesced
        {
            int r = tid >> 2, q = tid & 3;
            int n = base + r;
            if (n < NN) {
                const float* hp = h + (size_t)64 * n + q * 16;
                float* op = outp + (size_t)64 * n + q * 16;
#pragma unroll
                for (int j = 0; j < 4; ++j) {
                    float4 hv = *(const float4*)(hp + 4 * j);
                    const float* tv = &tp[r * 68 + q * 16 + 4 * j];
                    *(float4*)(op + 4 * j) = make_float4(
                        tv[0] + hv.x, tv[1] + hv.y, tv[2] + hv.z, tv[3] + hv.w);
                }
            }
        }
    }
}

// ===========================================================================
// Readout row-MLP (K1=64, segmented scatter into gsum) — unchanged.
// ===========================================================================
__global__ __launch_bounds__(512, 1) void rowmlp_ro_kernel(
    const float* __restrict__ A,
    const float* __restrict__ w1g, const float* __restrict__ b1g,
    const float* __restrict__ w2g, const float* __restrict__ b2g,
    const int* __restrict__ seg, float* __restrict__ outp,
    int nrows, int ntiles)
{
    extern __shared__ float lds[];
    float* ws1  = lds;
    float* ws2  = ws1 + 4096;
    float* wb1  = ws2 + 4096;
    float* wb2  = wb1 + 64;
    float* cats = wb2 + 64;
    float* m1s  = cats + 128 * 68;
    int*   segs = (int*)(m1s + 128 * 68);

    const int tid = threadIdx.x;
    const int tr  = tid & 31;
    const int tc  = tid >> 5;

    for (int i = tid; i < 1024; i += 512) {
        *(float4*)&ws1[4 * i] = *(const float4*)&w1g[4 * i];
        *(float4*)&ws2[4 * i] = *(const float4*)&w2g[4 * i];
    }
    if (tid < 64) { wb1[tid] = b1g[tid]; wb2[tid] = b2g[tid]; }

    for (int tile = blockIdx.x; tile < ntiles; tile += gridDim.x) {
        const int base = tile * 128;
        __syncthreads();
        if (tid < 128) segs[tid] = (base + tid < nrows) ? seg[base + tid] : -1;
#pragma unroll
        for (int rep = 0; rep < 4; ++rep) {
            int idx = rep * 512 + tid;
            int r = idx >> 4, q = idx & 15;
            int n = base + r;
            float4 v = make_float4(0.f, 0.f, 0.f, 0.f);
            if (n < nrows) v = *(const float4*)(A + 64 * n + 4 * q);
            *(float4*)&cats[r * 68 + 4 * q] = v;
        }
        __syncthreads();
        float acc[4][4];
#pragma unroll
        for (int jj = 0; jj < 4; ++jj)
#pragma unroll
            for (int ii = 0; ii < 4; ++ii) acc[jj][ii] = wb1[4 * tc + ii];
#pragma unroll 4
        for (int k16 = 0; k16 < 16; ++k16) {
            float4 bv0 = *(const float4*)&ws1[(4 * k16 + 0) * 64 + 4 * tc];
            float4 bv1 = *(const float4*)&ws1[(4 * k16 + 1) * 64 + 4 * tc];
            float4 bv2 = *(const float4*)&ws1[(4 * k16 + 2) * 64 + 4 * tc];
            float4 bv3 = *(const float4*)&ws1[(4 * k16 + 3) * 64 + 4 * tc];
#pragma unroll
            for (int jj = 0; jj < 4; ++jj) {
                float4 av = *(const float4*)&cats[(tr + 32 * jj) * 68 + 4 * k16];
                acc[jj][0] = fmaf(av.x, bv0.x, fmaf(av.y, bv1.x, fmaf(av.z, bv2.x, fmaf(av.w, bv3.x, acc[jj][0]))));
                acc[jj][1] = fmaf(av.x, bv0.y, fmaf(av.y, bv1.y, fmaf(av.z, bv2.y, fmaf(av.w, bv3.y, acc[jj][1]))));
                acc[jj][2] = fmaf(av.x, bv0.z, fmaf(av.y, bv1.z, fmaf(av.z, bv2.z, fmaf(av.w, bv3.z, acc[jj][2]))));
                acc[jj][3] = fmaf(av.x, bv0.w, fmaf(av.y, bv1.w, fmaf(av.z, bv2.w, fmaf(av.w, bv3.w, acc[jj][3]))));
            }
        }
#pragma unroll
        for (int jj = 0; jj < 4; ++jj) {
            float4 v;
            v.x = silu_f(acc[jj][0]); v.y = silu_f(acc[jj][1]);
            v.z = silu_f(acc[jj][2]); v.w = silu_f(acc[jj][3]);
            *(float4*)&m1s[(tr + 32 * jj) * 68 + 4 * tc] = v;
        }
        __syncthreads();
        float acc2[4][4];
#pragma unroll
        for (int jj = 0; jj < 4; ++jj)
#pragma unroll
            for (int ii = 0; ii < 4; ++ii) acc2[jj][ii] = wb2[4 * tc + ii];
#pragma unroll 4
        for (int k16 = 0; k16 < 16; ++k16) {
            float4 bv0 = *(const float4*)&ws2[(4 * k16 + 0) * 64 + 4 * tc];
            float4 bv1 = *(const float4*)&ws2[(4 * k16 + 1) * 64 + 4 * tc];
            float4 bv2 = *(const float4*)&ws2[(4 * k16 + 2) * 64 + 4 * tc];
            float4 bv3 = *(const float4*)&ws2[(4 * k16 + 3) * 64 + 4 * tc];
#pragma unroll
            for (int jj = 0; jj < 4; ++jj) {
                float4 av = *(const float4*)&m1s[(tr + 32 * jj) * 68 + 4 * k16];
                acc2[jj][0] = fmaf(av.x, bv0.x, fmaf(av.y, bv1.x, fmaf(av.z, bv2.x, fmaf(av.w, bv3.x, acc2[jj][0]))));
                acc2[jj][1] = fmaf(av.x, bv0.y, fmaf(av.y, bv1.y, fmaf(av.z, bv2.y, fmaf(av.w, bv3.y, acc2[jj][1]))));
                acc2[jj][2] = fmaf(av.x, bv0.z, fmaf(av.y, bv1.z, fmaf(av.z, bv2.z, fmaf(av.w, bv3.z, acc2[jj][2]))));
                acc2[jj][3] = fmaf(av.x, bv0.w, fmaf(av.y, bv1.w, fmaf(av.z, bv2.w, fmaf(av.w, bv3.w, acc2[jj][3]))));
            }
        }
#pragma unroll
        for (int jj = 0; jj < 4; ++jj) {
            int r = tr + 32 * jj;
            int n = base + r;
            int gid = segs[r];
            float4 vv = (n < nrows) ? make_float4(acc2[jj][0], acc2[jj][1], acc2[jj][2], acc2[jj][3])
                                    : make_float4(0.f, 0.f, 0.f, 0.f);
            unsigned f = (tr == 0 || segs[(r > 0) ? r - 1 : 0] != gid) ? 1u : 0u;
#pragma unroll
            for (int s = 1; s < 32; s <<= 1) {
                float ux = __shfl_up(vv.x, s, 32);
                float uy = __shfl_up(vv.y, s, 32);
                float uz = __shfl_up(vv.z, s, 32);
                float uw = __shfl_up(vv.w, s, 32);
                unsigned uf = __shfl_up(f, s, 32);
                if (tr >= s) {
                    if (!f) { vv.x += ux; vv.y += uy; vv.z += uz; vv.w += uw; }
                    f |= uf;
                }
            }
            bool tail = (tr == 31) || (segs[r + 1] != gid);
            if (tail && gid >= 0) {
                float* bp = outp + 64 * gid + 4 * tc;
                atomicAdd(bp + 0, vv.x); atomicAdd(bp + 1, vv.y);
                atomicAdd(bp + 2, vv.z); atomicAdd(bp + 3, vv.w);
            }
        }
    }
}

__global__ __launch_bounds__(256) void proj_kernel(
    const float* __restrict__ x, const float* __restrict__ w,
    const float* __restrict__ b, float* __restrict__ h, int n)
{
    int i = blockIdx.x * 256 + threadIdx.x;
    if (i >= n * 64) return;
    int node = i >> 6, j = i & 63;
    const float* xr = x + node * 14;
    float acc = b[j];
#pragma unroll
    for (int k = 0; k < 14; ++k) acc = fmaf(xr[k], w[k * 64 + j], acc);
    h[i] = acc;
}

__global__ __launch_bounds__(256) void head_kernel(
    const float* __restrict__ gsum,
    const float* __restrict__ w3, const float* __restrict__ b3,
    const float* __restrict__ w4, const float* __restrict__ b4,
    float* __restrict__ out, int g_count)
{
    int wid  = (blockIdx.x * 256 + threadIdx.x) >> 6;
    int lane = threadIdx.x & 63;
    if (wid >= g_count) return;
    float v = gsum[wid * 64 + lane];
    float t = b3[lane];
#pragma unroll
    for (int k = 0; k < 64; ++k) {
        float a = __shfl(v, k, 64);
        t = fmaf(a, w3[k * 64 + lane], t);
    }
    t = silu_f(t);
    float r = t * w4[lane];
#pragma unroll
    for (int off = 32; off; off >>= 1) r += __shfl_down(r, off, 64);
    if (lane == 0) out[wid] = r + b4[0];
}

extern "C" void kernel_launch(void* const* d_in, const int* in_sizes, int n_in,
                              void* d_out, int out_size, void* d_ws, size_t ws_size,
                              hipStream_t stream)
{
    const float* x      = (const float*)d_in[0];
    const int*   ei     = (const int*)d_in[2];
    const int*   batch  = (const int*)d_in[3];
    const float* proj_w = (const float*)d_in[4];
    const float* proj_b = (const float*)d_in[5];
    const float* ew1 = (const float*)d_in[6];
    const float* eb1 = (const float*)d_in[7];
    const float* ew2 = (const float*)d_in[8];
    const float* eb2 = (const float*)d_in[9];
    const float* nw1 = (const float*)d_in[10];
    const float* nb1 = (const float*)d_in[11];
    const float* nw2 = (const float*)d_in[12];
    const float* nb2 = (const float*)d_in[13];
    const float* l1w = (const float*)d_in[14]; const float* l1b = (const float*)d_in[15];
    const float* l2w = (const float*)d_in[16]; const float* l2b = (const float*)d_in[17];
    const float* l3w = (const float*)d_in[18]; const float* l3b = (const float*)d_in[19];
    const float* l4w = (const float*)d_in[20]; const float* l4b = (const float*)d_in[21];

    float* out  = (float*)d_out;
    float* h    = out + GG;                      // per_atom_out doubles as h

    unsigned short* m2g = (unsigned short*)d_ws;             // [E,64] bf16 = 102.4MB
    float* gsum = (float*)(m2g + (size_t)EE * 64);           // [G,64]
    float* Pt   = gsum + (size_t)GG * 64;                    // [N,64] f32
    unsigned short* Pbu = (unsigned short*)(Pt + (size_t)NN * 64);  // [N,64] bf16
    int* deg8    = (int*)(Pbu + (size_t)NN * 64);            // [8][N]
    int* rowptr  = deg8 + 8 * NN;                            // N+1
    int* cursor8 = rowptr + NN + 1;                          // [8][N]
    int2* epair  = (int2*)(((uintptr_t)(cursor8 + 8 * NN) + 15) & ~(uintptr_t)15);  // [E]
    int* bsum    = (int*)(epair + EE);                       // [98]
    float* agg   = Pt;  // alias: Pt dead after edge_kernel, rebuilt next layer

    const size_t edge_lds = 8192 + 16384 + 256 + 256;                 // 25088
    const size_t pk_lds   = 16384 + 16384 + 34816;                    // 67584
    const size_t node_lds = 16384 * 3 + 8192 * 3 + 34816 + 512;       // 109056
    const size_t ro_lds   = (size_t)(4096 + 4096 + 128 + 128 * 68 + 128 * 68) * 4 + 128 * 4;

    (void)hipFuncSetAttribute((const void*)edge_kernel,
                              hipFuncAttributeMaxDynamicSharedMemorySize, (int)edge_lds);
    (void)hipFuncSetAttribute((const void*)pk_kernel,
                              hipFuncAttributeMaxDynamicSharedMemorySize, (int)pk_lds);
    (void)hipFuncSetAttribute((const void*)node_mfma_kernel,
                              hipFuncAttributeMaxDynamicSharedMemorySize, (int)node_lds);
    (void)hipFuncSetAttribute((const void*)rowmlp_ro_kernel,
                              hipFuncAttributeMaxDynamicSharedMemorySize, (int)ro_lds);

    // --- CSR build (8-way sharded, dst-sorted packed edge list) ---
    const int nb = (NN + 511) / 512;           // 98
    hipMemsetAsync(deg8, 0, (size_t)8 * NN * sizeof(int), stream);
    hipMemsetAsync(gsum, 0, (size_t)GG * 64 * sizeof(float), stream);
    hist_kernel<<<(EE + 255) / 256, 256, 0, stream>>>(ei, deg8);
    scanA_kernel<<<nb, 512, 0, stream>>>(deg8, rowptr, bsum);
    scanB_kernel<<<1, 128, 0, stream>>>(bsum, nb);
    scanC_kernel<<<nb, 512, 0, stream>>>(rowptr, cursor8, deg8, bsum);
    scatter_kernel<<<(EE + 255) / 256, 256, 0, stream>>>(ei, cursor8, epair);

    proj_kernel<<<(NN * 64 + 255) / 256, 256, 0, stream>>>(x, proj_w, proj_b, h, NN);

    const int etiles = EE / 128;               // 6250 (exact)
    const int ntiles = (NN + 127) / 128;       // 391
    for (int l = 0; l < LL; ++l) {
        pk_kernel<<<ntiles, 512, pk_lds, stream>>>(h, ew1 + l * 8192, Pt, Pbu, ntiles);
        edge_kernel<<<1024, 512, edge_lds, stream>>>(
            Pt, Pbu, epair, eb1 + l * 64, ew2 + l * 4096, eb2 + l * 64,
            m2g, etiles);
        agg_kernel<<<(NN * 16 + 255) / 256, 256, 0, stream>>>(m2g, rowptr, agg);
        node_mfma_kernel<<<196, 512, node_lds, stream>>>(
            h, agg, nw1 + l * 8192, nb1 + l * 64, nw2 + l * 4096, nb2 + l * 64,
            h, ntiles);
    }
    rowmlp_ro_kernel<<<196, 512, ro_lds, stream>>>(
        h, l1w, l1b, l2w, l2b, batch, gsum, NN, ntiles);
    head_kernel<<<GG / 4, 256, 0, stream>>>(gsum, l3w, l3b, l4w, l4b, out, GG);
}